// Round 1
// baseline (923.640 us; speedup 1.0000x reference)
//
#include <hip/hip_runtime.h>
#include <math.h>

// Baseline correct implementation of the SKConv + RAL + CSA + fuse network.
// All intermediates fp32 in d_ws. 15 kernel launches, all on `stream`.

#define EPSN 1e-5f

// ---------------- block-wide reductions (blockDim.x == 256, 4 waves) --------
__device__ __forceinline__ void breduce2(float& a, float& b, float* lds) {
#pragma unroll
  for (int o = 32; o > 0; o >>= 1) {
    a += __shfl_down(a, o);
    b += __shfl_down(b, o);
  }
  int lane = threadIdx.x & 63, wid = threadIdx.x >> 6;
  __syncthreads();
  if (lane == 0) { lds[wid] = a; lds[4 + wid] = b; }
  __syncthreads();
  a = lds[0] + lds[1] + lds[2] + lds[3];
  b = lds[4] + lds[5] + lds[6] + lds[7];
}

__device__ __forceinline__ float breduce_sum(float v, float* lds) {
#pragma unroll
  for (int o = 32; o > 0; o >>= 1) v += __shfl_down(v, o);
  int lane = threadIdx.x & 63, wid = threadIdx.x >> 6;
  __syncthreads();
  if (lane == 0) lds[wid] = v;
  __syncthreads();
  return lds[0] + lds[1] + lds[2] + lds[3];
}

__device__ __forceinline__ float breduce_max(float v, float* lds) {
#pragma unroll
  for (int o = 32; o > 0; o >>= 1) v = fmaxf(v, __shfl_down(v, o));
  int lane = threadIdx.x & 63, wid = threadIdx.x >> 6;
  __syncthreads();
  if (lane == 0) lds[wid] = v;
  __syncthreads();
  return fmaxf(fmaxf(lds[0], lds[1]), fmaxf(lds[2], lds[3]));
}

// ---------------- SKConv branch: grouped conv + bias + InstanceNorm + ReLU --
// block = one output channel c; groups=32, 16 in-ch per group.
template <int KS>
__global__ __launch_bounds__(256) void sk_branch(
    const float* __restrict__ x, const float* __restrict__ w,
    const float* __restrict__ bias, float* __restrict__ feas,
    float* __restrict__ bmean, int m) {
  constexpr int PAD = KS / 2;
  constexpr int W2 = 32 + 2 * PAD;
  __shared__ float chanp[W2 * W2];
  __shared__ float ws[16 * KS * KS];
  __shared__ float red[8];
  int c = blockIdx.x, tid = threadIdx.x;
  int g = c >> 4;
  for (int i = tid; i < W2 * W2; i += 256) chanp[i] = 0.f;
  for (int i = tid; i < 16 * KS * KS; i += 256) ws[i] = w[c * 16 * KS * KS + i];
  float acc[4] = {0.f, 0.f, 0.f, 0.f};
  for (int ic = 0; ic < 16; ++ic) {
    __syncthreads();  // first iter: covers zero-fill + ws load
    for (int i = tid; i < 1024; i += 256)
      chanp[((i >> 5) + PAD) * W2 + (i & 31) + PAD] = x[(g * 16 + ic) * 1024 + i];
    __syncthreads();
#pragma unroll
    for (int r = 0; r < 4; ++r) {
      int px = tid + r * 256;
      int y = px >> 5, xx = px & 31;
      float a = acc[r];
#pragma unroll
      for (int ky = 0; ky < KS; ++ky)
#pragma unroll
        for (int kx = 0; kx < KS; ++kx)
          a += chanp[(y + ky) * W2 + xx + kx] * ws[ic * KS * KS + ky * KS + kx];
      acc[r] = a;
    }
  }
  float bv = bias[c];
  float s = 0.f, ss = 0.f;
#pragma unroll
  for (int r = 0; r < 4; ++r) { acc[r] += bv; s += acc[r]; ss += acc[r] * acc[r]; }
  breduce2(s, ss, red);
  float mean = s * (1.f / 1024.f);
  float var = ss * (1.f / 1024.f) - mean * mean;
  float inv = rsqrtf(var + EPSN);
  float rs = 0.f;
#pragma unroll
  for (int r = 0; r < 4; ++r) {
    float v = (acc[r] - mean) * inv;
    v = v > 0.f ? v : 0.f;
    feas[(m * 512 + c) * 1024 + tid + r * 256] = v;
    rs += v;
  }
  float tot = breduce_sum(rs, red);
  if (tid == 0) bmean[m * 512 + c] = tot * (1.f / 1024.f);
}

// ---------------- FC chain + branch softmax (one block) ---------------------
__global__ __launch_bounds__(256) void fc_att(
    const float* __restrict__ bmean, const float* __restrict__ w_fc,
    const float* __restrict__ b_fc, const float* __restrict__ w0,
    const float* __restrict__ b0, const float* __restrict__ w1,
    const float* __restrict__ b1, const float* __restrict__ w2,
    const float* __restrict__ b2, float* __restrict__ att) {
  __shared__ float sfea[512];
  __shared__ float zz[32];
  int tid = threadIdx.x;
  for (int c = tid; c < 512; c += 256)
    sfea[c] = bmean[c] + bmean[512 + c] + bmean[1024 + c];
  __syncthreads();
  if (tid < 32) {
    float d = b_fc[tid];
    for (int c = 0; c < 512; ++c) d += sfea[c] * w_fc[tid * 512 + c];
    zz[tid] = d;
  }
  __syncthreads();
  for (int c = tid; c < 512; c += 256) {
    float l0 = b0[c], l1 = b1[c], l2 = b2[c];
#pragma unroll
    for (int j = 0; j < 32; ++j) {
      float z = zz[j];
      l0 += z * w0[c * 32 + j];
      l1 += z * w1[c * 32 + j];
      l2 += z * w2[c * 32 + j];
    }
    float mx = fmaxf(l0, fmaxf(l1, l2));
    float e0 = expf(l0 - mx), e1 = expf(l1 - mx), e2 = expf(l2 - mx);
    float inv = 1.f / (e0 + e1 + e2);
    att[c] = e0 * inv;
    att[512 + c] = e1 * inv;
    att[1024 + c] = e2 * inv;
  }
}

// ---------------- attention blend -> out_res --------------------------------
__global__ void blend(const float* __restrict__ feas, const float* __restrict__ att,
                      float* __restrict__ res) {
  int idx = blockIdx.x * 256 + threadIdx.x;  // 524288 total
  int c = idx >> 10;
  res[idx] = feas[idx] * att[c] + feas[524288 + idx] * att[512 + c] +
             feas[1048576 + idx] * att[1024 + c];
}

// ---------------- 2x2 average pool -> fg_small (512,16,16) ------------------
__global__ void pool2(const float* __restrict__ res, float* __restrict__ fgs) {
  int idx = blockIdx.x * 256 + threadIdx.x;  // 131072
  int c = idx >> 8;
  int rem = idx & 255;
  int i = rem >> 4, j = rem & 15;
  const float* base = res + c * 1024 + (2 * i) * 32 + 2 * j;
  fgs[idx] = 0.25f * (base[0] + base[1] + base[32] + base[33]);
}

// ---------------- Gram matrix of 3x3x512 neighborhoods (256x256) ------------
// A[p,q] = sum_c sum_{3x3} fgs_pad[c,p-nbr] * fgs_pad[c,q-nbr]
__global__ __launch_bounds__(256) void gram(const float* __restrict__ fgs,
                                            float* __restrict__ A) {
  __shared__ float ch[8][324];  // 8 channels, 18x18 zero-padded
  int p = blockIdx.x, q = threadIdx.x;
  int pi = p >> 4, pj = p & 15, qi = q >> 4, qj = q & 15;
  for (int i = threadIdx.x; i < 8 * 324; i += 256) ((float*)ch)[i] = 0.f;
  float acc = 0.f;
  for (int c0 = 0; c0 < 512; c0 += 8) {
    __syncthreads();
#pragma unroll
    for (int cc = 0; cc < 8; ++cc)
      ch[cc][((q >> 4) + 1) * 18 + (q & 15) + 1] = fgs[(c0 + cc) * 256 + q];
    __syncthreads();
#pragma unroll
    for (int cc = 0; cc < 8; ++cc) {
#pragma unroll
      for (int u = 0; u < 3; ++u)
#pragma unroll
        for (int v = 0; v < 3; ++v)
          acc += ch[cc][(pi + u) * 18 + pj + v] * ch[cc][(qi + u) * 18 + qj + v];
    }
  }
  A[p * 256 + q] = acc;
}

// ---------------- RAL attention softmax over patch axis ---------------------
__global__ __launch_bounds__(256) void attn_softmax(const float* __restrict__ A,
                                                    float* __restrict__ attn) {
  __shared__ float red[8];
  int q = blockIdx.x, t = threadIdx.x;
  float nrm = sqrtf(fmaxf(A[t * 256 + t], 0.f));
  float v = A[t * 256 + q] / fmaxf(nrm, 1e-4f) * 10.f;
  float mx = breduce_max(v, red);
  float e = expf(v - mx);
  float sm = breduce_sum(e, red);
  attn[t * 256 + q] = e / sm;
}

// ---------------- transpose-conv (stride 2, pad 1, 4x4 patches) / 4 ---------
__global__ __launch_bounds__(256) void tconv(const float* __restrict__ res,
                                             const float* __restrict__ attn,
                                             float* __restrict__ out) {
  __shared__ float chanp[34 * 34];
  __shared__ float arow[8][256];
  int c = blockIdx.x, tid = threadIdx.x;
  for (int i = tid; i < 1156; i += 256) chanp[i] = 0.f;
  __syncthreads();
  for (int i = tid; i < 1024; i += 256)
    chanp[((i >> 5) + 1) * 34 + (i & 31) + 1] = res[c * 1024 + i];
  __syncthreads();
  float acc[4] = {0.f, 0.f, 0.f, 0.f};
  for (int p0 = 0; p0 < 256; p0 += 8) {
#pragma unroll
    for (int cc = 0; cc < 8; ++cc) arow[cc][tid] = attn[(p0 + cc) * 256 + tid];
    __syncthreads();
#pragma unroll
    for (int cc = 0; cc < 8; ++cc) {
      int p = p0 + cc;
      int pi = p >> 4, pj = p & 15;
#pragma unroll
      for (int r = 0; r < 4; ++r) {
        int px = tid + r * 256;
        int y = px >> 5, xx = px & 31;
        int ki0 = (y + 1) & 1, i0 = (y + 1 - ki0) >> 1;
        int kj0 = (xx + 1) & 1, j0 = (xx + 1 - kj0) >> 1;
        bool vy0 = i0 < 16, vy1 = i0 >= 1;
        bool vx0 = j0 < 16, vx1 = j0 >= 1;
        int ry0 = 2 * pi + ki0, ry1 = ry0 + 2;  // chanp row (pad +1 folded in)
        int rx0 = 2 * pj + kj0, rx1 = rx0 + 2;
        float a = 0.f;
        if (vy0 && vx0) a += arow[cc][i0 * 16 + j0] * chanp[ry0 * 34 + rx0];
        if (vy0 && vx1) a += arow[cc][i0 * 16 + j0 - 1] * chanp[ry0 * 34 + rx1];
        if (vy1 && vx0) a += arow[cc][(i0 - 1) * 16 + j0] * chanp[ry1 * 34 + rx0];
        if (vy1 && vx1) a += arow[cc][(i0 - 1) * 16 + j0 - 1] * chanp[ry1 * 34 + rx1];
        acc[r] += a;
      }
    }
    __syncthreads();
  }
#pragma unroll
  for (int r = 0; r < 4; ++r) out[c * 1024 + tid + r * 256] = acc[r] * 0.25f;
}

// ---------------- gus einsum: M(1024,512) = G(1024,1024) @ O(512,1024)^T ----
__global__ __launch_bounds__(256) void gus_gemm(const float* __restrict__ G,
                                                const float* __restrict__ O,
                                                float* __restrict__ M) {
  __shared__ float As[32][33];
  __shared__ float Bs[32][33];
  int bc = blockIdx.x, bp = blockIdx.y;
  int tid = threadIdx.x;
  int tx = tid & 31, ty = tid >> 5;
  float acc[4] = {0.f, 0.f, 0.f, 0.f};
  for (int k0 = 0; k0 < 1024; k0 += 32) {
    __syncthreads();
#pragma unroll
    for (int r0 = 0; r0 < 4; ++r0) {
      int r = ty + r0 * 8;
      As[r][tx] = G[(bp * 32 + r) * 1024 + k0 + tx];
      Bs[r][tx] = O[(bc * 32 + r) * 1024 + k0 + tx];
    }
    __syncthreads();
#pragma unroll
    for (int k = 0; k < 32; ++k) {
      float b = Bs[tx][k];
#pragma unroll
      for (int r = 0; r < 4; ++r) acc[r] += As[ty + r * 8][k] * b;
    }
  }
#pragma unroll
  for (int r = 0; r < 4; ++r)
    M[(bp * 32 + ty + r * 8) * 512 + bc * 32 + tx] = acc[r];
}

// ---------------- transpose out_ral to spatial-major + sigmoid --------------
__global__ __launch_bounds__(256) void transpose_sig(const float* __restrict__ orl,
                                                     float* __restrict__ orl_t,
                                                     float* __restrict__ sig_t) {
  __shared__ float t[32][33];
  int bc = blockIdx.x, bn = blockIdx.y;
  int tx = threadIdx.x & 31, ty = threadIdx.x >> 5;
#pragma unroll
  for (int r0 = 0; r0 < 4; ++r0) {
    int r = ty + r0 * 8;
    t[r][tx] = orl[(bc * 32 + r) * 1024 + bn * 32 + tx];
  }
  __syncthreads();
#pragma unroll
  for (int r0 = 0; r0 < 4; ++r0) {
    int r = ty + r0 * 8;
    float v = t[tx][r];
    int o = (bn * 32 + r) * 512 + bc * 32 + tx;
    orl_t[o] = v;
    sig_t[o] = 1.f / (1.f + expf(-v));
  }
}

// ---------------- CSA attention: 9-tap correlation + softmax ----------------
__global__ __launch_bounds__(256) void csa_attn(const float* __restrict__ sig_t,
                                                float* __restrict__ a9) {
  __shared__ float red[8];
  int n = blockIdx.x, tid = threadIdx.x;
  int ny = n >> 5, nx = n & 31;
  float part[9];
#pragma unroll
  for (int t = 0; t < 9; ++t) part[t] = 0.f;
  for (int c = tid; c < 512; c += 256) {
    float ctr = sig_t[n * 512 + c];
#pragma unroll
    for (int u = 0; u < 3; ++u) {
      int yy = ny + u - 1;
#pragma unroll
      for (int v = 0; v < 3; ++v) {
        int xx = nx + v - 1;
        float nb = ((unsigned)yy < 32u && (unsigned)xx < 32u)
                       ? sig_t[(yy * 32 + xx) * 512 + c] : 0.f;
        part[u * 3 + v] += ctr * nb;
      }
    }
  }
  float a[9];
#pragma unroll
  for (int t = 0; t < 9; ++t) a[t] = breduce_sum(part[t], red) * (1.f / 512.f);
  float mx = a[0];
#pragma unroll
  for (int t = 1; t < 9; ++t) mx = fmaxf(mx, a[t]);
  float sum = 0.f;
#pragma unroll
  for (int t = 0; t < 9; ++t) { a[t] = expf(a[t] - mx); sum += a[t]; }
  float inv = 1.f / sum;
  if (tid == 0) {
#pragma unroll
    for (int t = 0; t < 9; ++t) a9[n * 9 + t] = a[t] * inv;
  }
}

// ---------------- CSA output: weighted 3x3 gather (raw-reshape flat) --------
__global__ void csa_out(const float* __restrict__ a9, const float* __restrict__ orl_t,
                        float* __restrict__ outc) {
  int f = blockIdx.x * 256 + threadIdx.x;  // 524288
  int n = f >> 9, q = f & 511;
  int ny = n >> 5, nx = n & 31;
  float acc = 0.f;
#pragma unroll
  for (int u = 0; u < 3; ++u) {
    int yy = ny + u - 1;
#pragma unroll
    for (int v = 0; v < 3; ++v) {
      int xx = nx + v - 1;
      if ((unsigned)yy < 32u && (unsigned)xx < 32u)
        acc += a9[n * 9 + u * 3 + v] * orl_t[(yy * 32 + xx) * 512 + q];
    }
  }
  outc[f] = acc;
}

// ---------------- 1x1 conv (1024->512) + InstanceNorm + LeakyReLU(0.2) ------
// block computes 8 whole output channels; za = channels [0,512), zb = [512,1024)
__global__ __launch_bounds__(256) void conv1x1_in(const float* __restrict__ za,
                                                  const float* __restrict__ zb,
                                                  const float* __restrict__ w,
                                                  float* __restrict__ out) {
  __shared__ float red[8];
  int ob = blockIdx.x * 8, tid = threadIdx.x;
  float acc[8][4];
#pragma unroll
  for (int o = 0; o < 8; ++o)
#pragma unroll
    for (int r = 0; r < 4; ++r) acc[o][r] = 0.f;
  for (int i = 0; i < 1024; ++i) {
    const float* zr = (i < 512) ? (za + i * 1024) : (zb + (i - 512) * 1024);
    float zv[4];
#pragma unroll
    for (int r = 0; r < 4; ++r) zv[r] = zr[tid + r * 256];
#pragma unroll
    for (int o = 0; o < 8; ++o) {
      float wv = w[(ob + o) * 1024 + i];
#pragma unroll
      for (int r = 0; r < 4; ++r) acc[o][r] += wv * zv[r];
    }
  }
#pragma unroll
  for (int o = 0; o < 8; ++o) {
    float s = 0.f, ss = 0.f;
#pragma unroll
    for (int r = 0; r < 4; ++r) { s += acc[o][r]; ss += acc[o][r] * acc[o][r]; }
    breduce2(s, ss, red);
    float mean = s * (1.f / 1024.f);
    float var = ss * (1.f / 1024.f) - mean * mean;
    float inv = rsqrtf(var + EPSN);
#pragma unroll
    for (int r = 0; r < 4; ++r) {
      float v = (acc[o][r] - mean) * inv;
      out[(ob + o) * 1024 + tid + r * 256] = v >= 0.f ? v : 0.2f * v;
    }
  }
}

// ---------------- host launch ------------------------------------------------
extern "C" void kernel_launch(void* const* d_in, const int* in_sizes, int n_in,
                              void* d_out, int out_size, void* d_ws, size_t ws_size,
                              hipStream_t stream) {
  const float* x = (const float*)d_in[0];
  const float* gus = (const float*)d_in[1];
  const float* w3 = (const float*)d_in[2];
  const float* b3 = (const float*)d_in[3];
  const float* w5 = (const float*)d_in[4];
  const float* b5 = (const float*)d_in[5];
  const float* w7 = (const float*)d_in[6];
  const float* b7 = (const float*)d_in[7];
  const float* wfc = (const float*)d_in[8];
  const float* bfc = (const float*)d_in[9];
  const float* w0 = (const float*)d_in[10];
  const float* b0 = (const float*)d_in[11];
  const float* w1 = (const float*)d_in[12];
  const float* b1 = (const float*)d_in[13];
  const float* w2 = (const float*)d_in[14];
  const float* b2 = (const float*)d_in[15];
  const float* wdown = (const float*)d_in[16];
  const float* wfuse = (const float*)d_in[17];

  float* ws = (float*)d_ws;
  float* feas = ws;                   // 3*512*1024 = 1572864
  float* bmean = feas + 1572864;      // 1536
  float* att = bmean + 1536;          // 1536
  float* res = att + 1536;            // 524288  (out_res, pre-RAL blend)
  float* fgs = res + 524288;          // 131072  (fg_small 512x16x16)
  float* A = fgs + 131072;            // 65536   (Gram 256x256)
  float* attn = A + 65536;            // 65536
  float* orl = attn + 65536;          // 524288  (out_32 post-RAL)
  float* orlt = orl + 524288;         // 524288  (spatial-major)
  float* sigt = orlt + 524288;        // 524288  (sigmoid, spatial-major)
  float* gusout = sigt + 524288;      // 524288  (M flat == gus_out flat)
  float* a9 = gusout + 524288;        // 9216
  float* outcsa = a9 + 9216;          // 524288
  float* zdown = outcsa + 524288;     // 524288

  sk_branch<3><<<512, 256, 0, stream>>>(x, w3, b3, feas, bmean, 0);
  sk_branch<5><<<512, 256, 0, stream>>>(x, w5, b5, feas, bmean, 1);
  sk_branch<7><<<512, 256, 0, stream>>>(x, w7, b7, feas, bmean, 2);
  fc_att<<<1, 256, 0, stream>>>(bmean, wfc, bfc, w0, b0, w1, b1, w2, b2, att);
  blend<<<2048, 256, 0, stream>>>(feas, att, res);
  pool2<<<512, 256, 0, stream>>>(res, fgs);
  gram<<<256, 256, 0, stream>>>(fgs, A);
  attn_softmax<<<256, 256, 0, stream>>>(A, attn);
  tconv<<<512, 256, 0, stream>>>(res, attn, orl);
  gus_gemm<<<dim3(16, 32), 256, 0, stream>>>(gus, orl, gusout);
  transpose_sig<<<dim3(16, 32), 256, 0, stream>>>(orl, orlt, sigt);
  csa_attn<<<1024, 256, 0, stream>>>(sigt, a9);
  csa_out<<<2048, 256, 0, stream>>>(a9, orlt, outcsa);
  conv1x1_in<<<64, 256, 0, stream>>>(gusout, outcsa, wdown, zdown);
  conv1x1_in<<<64, 256, 0, stream>>>(zdown, res, wfuse, (float*)d_out);
}

// Round 2
// 634.537 us; speedup vs baseline: 1.4556x; 1.4556x over previous
//
#include <hip/hip_runtime.h>
#include <math.h>

#define EPSN 1e-5f

// ---------------- block-wide reductions (blockDim.x == 256, 4 waves) --------
__device__ __forceinline__ void breduce2(float& a, float& b, float* lds) {
#pragma unroll
  for (int o = 32; o > 0; o >>= 1) {
    a += __shfl_down(a, o);
    b += __shfl_down(b, o);
  }
  int lane = threadIdx.x & 63, wid = threadIdx.x >> 6;
  __syncthreads();
  if (lane == 0) { lds[wid] = a; lds[4 + wid] = b; }
  __syncthreads();
  a = lds[0] + lds[1] + lds[2] + lds[3];
  b = lds[4] + lds[5] + lds[6] + lds[7];
}

__device__ __forceinline__ float breduce_sum(float v, float* lds) {
#pragma unroll
  for (int o = 32; o > 0; o >>= 1) v += __shfl_down(v, o);
  int lane = threadIdx.x & 63, wid = threadIdx.x >> 6;
  __syncthreads();
  if (lane == 0) lds[wid] = v;
  __syncthreads();
  return lds[0] + lds[1] + lds[2] + lds[3];
}

__device__ __forceinline__ float breduce_max(float v, float* lds) {
#pragma unroll
  for (int o = 32; o > 0; o >>= 1) v = fmaxf(v, __shfl_down(v, o));
  int lane = threadIdx.x & 63, wid = threadIdx.x >> 6;
  __syncthreads();
  if (lane == 0) lds[wid] = v;
  __syncthreads();
  return fmaxf(fmaxf(lds[0], lds[1]), fmaxf(lds[2], lds[3]));
}

// ---------------- SKConv branch: grouped conv + bias + InstanceNorm + ReLU --
template <int KS>
__global__ __launch_bounds__(256) void sk_branch(
    const float* __restrict__ x, const float* __restrict__ w,
    const float* __restrict__ bias, float* __restrict__ feas,
    float* __restrict__ bmean, int m) {
  constexpr int PAD = KS / 2;
  constexpr int W2 = 32 + 2 * PAD;
  __shared__ float chanp[W2 * W2];
  __shared__ float ws[16 * KS * KS];
  __shared__ float red[8];
  int c = blockIdx.x, tid = threadIdx.x;
  int g = c >> 4;
  for (int i = tid; i < W2 * W2; i += 256) chanp[i] = 0.f;
  for (int i = tid; i < 16 * KS * KS; i += 256) ws[i] = w[c * 16 * KS * KS + i];
  float acc[4] = {0.f, 0.f, 0.f, 0.f};
  for (int ic = 0; ic < 16; ++ic) {
    __syncthreads();
    for (int i = tid; i < 1024; i += 256)
      chanp[((i >> 5) + PAD) * W2 + (i & 31) + PAD] = x[(g * 16 + ic) * 1024 + i];
    __syncthreads();
#pragma unroll
    for (int r = 0; r < 4; ++r) {
      int px = tid + r * 256;
      int y = px >> 5, xx = px & 31;
      float a = acc[r];
#pragma unroll
      for (int ky = 0; ky < KS; ++ky)
#pragma unroll
        for (int kx = 0; kx < KS; ++kx)
          a += chanp[(y + ky) * W2 + xx + kx] * ws[ic * KS * KS + ky * KS + kx];
      acc[r] = a;
    }
  }
  float bv = bias[c];
  float s = 0.f, ss = 0.f;
#pragma unroll
  for (int r = 0; r < 4; ++r) { acc[r] += bv; s += acc[r]; ss += acc[r] * acc[r]; }
  breduce2(s, ss, red);
  float mean = s * (1.f / 1024.f);
  float var = ss * (1.f / 1024.f) - mean * mean;
  float inv = rsqrtf(var + EPSN);
  float rs = 0.f;
#pragma unroll
  for (int r = 0; r < 4; ++r) {
    float v = (acc[r] - mean) * inv;
    v = v > 0.f ? v : 0.f;
    feas[(m * 512 + c) * 1024 + tid + r * 256] = v;
    rs += v;
  }
  float tot = breduce_sum(rs, red);
  if (tid == 0) bmean[m * 512 + c] = tot * (1.f / 1024.f);
}

// ---------------- FC chain + branch softmax (one block) ---------------------
__global__ __launch_bounds__(256) void fc_att(
    const float* __restrict__ bmean, const float* __restrict__ w_fc,
    const float* __restrict__ b_fc, const float* __restrict__ w0,
    const float* __restrict__ b0, const float* __restrict__ w1,
    const float* __restrict__ b1, const float* __restrict__ w2,
    const float* __restrict__ b2, float* __restrict__ att) {
  __shared__ float sfea[512];
  __shared__ float zz[32];
  int tid = threadIdx.x;
  for (int c = tid; c < 512; c += 256)
    sfea[c] = bmean[c] + bmean[512 + c] + bmean[1024 + c];
  __syncthreads();
  if (tid < 32) {
    float d = b_fc[tid];
    for (int c = 0; c < 512; ++c) d += sfea[c] * w_fc[tid * 512 + c];
    zz[tid] = d;
  }
  __syncthreads();
  for (int c = tid; c < 512; c += 256) {
    float l0 = b0[c], l1 = b1[c], l2 = b2[c];
#pragma unroll
    for (int j = 0; j < 32; ++j) {
      float z = zz[j];
      l0 += z * w0[c * 32 + j];
      l1 += z * w1[c * 32 + j];
      l2 += z * w2[c * 32 + j];
    }
    float mx = fmaxf(l0, fmaxf(l1, l2));
    float e0 = expf(l0 - mx), e1 = expf(l1 - mx), e2 = expf(l2 - mx);
    float inv = 1.f / (e0 + e1 + e2);
    att[c] = e0 * inv;
    att[512 + c] = e1 * inv;
    att[1024 + c] = e2 * inv;
  }
}

// ---------------- attention blend -> out_res --------------------------------
__global__ void blend(const float* __restrict__ feas, const float* __restrict__ att,
                      float* __restrict__ res) {
  int idx = blockIdx.x * 256 + threadIdx.x;
  int c = idx >> 10;
  res[idx] = feas[idx] * att[c] + feas[524288 + idx] * att[512 + c] +
             feas[1048576 + idx] * att[1024 + c];
}

// ---------------- 2x2 average pool -> fg_small (512,16,16) ------------------
__global__ void pool2(const float* __restrict__ res, float* __restrict__ fgs) {
  int idx = blockIdx.x * 256 + threadIdx.x;
  int c = idx >> 8;
  int rem = idx & 255;
  int i = rem >> 4, j = rem & 15;
  const float* base = res + c * 1024 + (2 * i) * 32 + 2 * j;
  fgs[idx] = 0.25f * (base[0] + base[1] + base[32] + base[33]);
}

// ---------------- Gram matrix of 3x3x512 neighborhoods (256x256) ------------
__global__ __launch_bounds__(256) void gram(const float* __restrict__ fgs,
                                            float* __restrict__ A) {
  __shared__ float ch[8][324];
  int p = blockIdx.x, q = threadIdx.x;
  int pi = p >> 4, pj = p & 15, qi = q >> 4, qj = q & 15;
  for (int i = threadIdx.x; i < 8 * 324; i += 256) ((float*)ch)[i] = 0.f;
  float acc = 0.f;
  for (int c0 = 0; c0 < 512; c0 += 8) {
    __syncthreads();
#pragma unroll
    for (int cc = 0; cc < 8; ++cc)
      ch[cc][((q >> 4) + 1) * 18 + (q & 15) + 1] = fgs[(c0 + cc) * 256 + q];
    __syncthreads();
#pragma unroll
    for (int cc = 0; cc < 8; ++cc) {
#pragma unroll
      for (int u = 0; u < 3; ++u)
#pragma unroll
        for (int v = 0; v < 3; ++v)
          acc += ch[cc][(pi + u) * 18 + pj + v] * ch[cc][(qi + u) * 18 + qj + v];
    }
  }
  A[p * 256 + q] = acc;
}

// ---------------- RAL attention softmax over patch axis ---------------------
__global__ __launch_bounds__(256) void attn_softmax(const float* __restrict__ A,
                                                    float* __restrict__ attn) {
  __shared__ float red[8];
  int q = blockIdx.x, t = threadIdx.x;
  float nrm = sqrtf(fmaxf(A[t * 256 + t], 0.f));
  float v = A[t * 256 + q] / fmaxf(nrm, 1e-4f) * 10.f;
  float mx = breduce_max(v, red);
  float e = expf(v - mx);
  float sm = breduce_sum(e, red);
  attn[t * 256 + q] = e / sm;
}

// ---------------- transpose-conv (stride 2, pad 1, 4x4 patches) / 4 ---------
__global__ __launch_bounds__(256) void tconv(const float* __restrict__ res,
                                             const float* __restrict__ attn,
                                             float* __restrict__ out) {
  __shared__ float chanp[34 * 34];
  __shared__ float arow[8][256];
  int c = blockIdx.x, tid = threadIdx.x;
  for (int i = tid; i < 1156; i += 256) chanp[i] = 0.f;
  __syncthreads();
  for (int i = tid; i < 1024; i += 256)
    chanp[((i >> 5) + 1) * 34 + (i & 31) + 1] = res[c * 1024 + i];
  __syncthreads();
  float acc[4] = {0.f, 0.f, 0.f, 0.f};
  for (int p0 = 0; p0 < 256; p0 += 8) {
#pragma unroll
    for (int cc = 0; cc < 8; ++cc) arow[cc][tid] = attn[(p0 + cc) * 256 + tid];
    __syncthreads();
#pragma unroll
    for (int cc = 0; cc < 8; ++cc) {
      int p = p0 + cc;
      int pi = p >> 4, pj = p & 15;
#pragma unroll
      for (int r = 0; r < 4; ++r) {
        int px = tid + r * 256;
        int y = px >> 5, xx = px & 31;
        int ki0 = (y + 1) & 1, i0 = (y + 1 - ki0) >> 1;
        int kj0 = (xx + 1) & 1, j0 = (xx + 1 - kj0) >> 1;
        bool vy0 = i0 < 16, vy1 = i0 >= 1;
        bool vx0 = j0 < 16, vx1 = j0 >= 1;
        int ry0 = 2 * pi + ki0, ry1 = ry0 + 2;
        int rx0 = 2 * pj + kj0, rx1 = rx0 + 2;
        float a = 0.f;
        if (vy0 && vx0) a += arow[cc][i0 * 16 + j0] * chanp[ry0 * 34 + rx0];
        if (vy0 && vx1) a += arow[cc][i0 * 16 + j0 - 1] * chanp[ry0 * 34 + rx1];
        if (vy1 && vx0) a += arow[cc][(i0 - 1) * 16 + j0] * chanp[ry1 * 34 + rx0];
        if (vy1 && vx1) a += arow[cc][(i0 - 1) * 16 + j0 - 1] * chanp[ry1 * 34 + rx1];
        acc[r] += a;
      }
    }
    __syncthreads();
  }
#pragma unroll
  for (int r = 0; r < 4; ++r) out[c * 1024 + tid + r * 256] = acc[r] * 0.25f;
}

// ---------------- 64x64-tile GEMM, BK=32, 4x4 micro-tile --------------------
// gemm_nn: raw[o,p] = sum_k w[o*1024+k] * Z[k,p], Z = concat(za,zb) channel-major.
// grid = dim3(N/64=16, M/64=8)
__global__ __launch_bounds__(256) void gemm_nn(const float* __restrict__ w,
                                               const float* __restrict__ za,
                                               const float* __restrict__ zb,
                                               float* __restrict__ raw) {
  __shared__ float As[32][68];
  __shared__ float Bs[32][68];
  int tid = threadIdx.x;
  int pb = blockIdx.x * 64, ob = blockIdx.y * 64;
  int tx = tid & 15, ty = tid >> 4;
  float acc[4][4] = {};
  for (int k0 = 0; k0 < 1024; k0 += 32) {
    const float* Bsrc =
        (k0 < 512) ? za + (size_t)k0 * 1024 : zb + (size_t)(k0 - 512) * 1024;
    __syncthreads();
#pragma unroll
    for (int r = 0; r < 2; ++r) {
      int v = r * 256 + tid;            // 0..511 float4 ids
      int mm = v >> 3, kq = (v & 7) * 4;
      float4 a = *(const float4*)&w[(ob + mm) * 1024 + k0 + kq];
      As[kq + 0][mm] = a.x; As[kq + 1][mm] = a.y;
      As[kq + 2][mm] = a.z; As[kq + 3][mm] = a.w;
      int kk = v >> 4, pq = (v & 15) * 4;
      *(float4*)&Bs[kk][pq] = *(const float4*)&Bsrc[kk * 1024 + pb + pq];
    }
    __syncthreads();
#pragma unroll
    for (int k = 0; k < 32; ++k) {
      float4 a = *(const float4*)&As[k][ty * 4];
      float4 b = *(const float4*)&Bs[k][tx * 4];
      float av[4] = {a.x, a.y, a.z, a.w};
      float bv[4] = {b.x, b.y, b.z, b.w};
#pragma unroll
      for (int i = 0; i < 4; ++i)
#pragma unroll
        for (int j = 0; j < 4; ++j) acc[i][j] += av[i] * bv[j];
    }
  }
#pragma unroll
  for (int i = 0; i < 4; ++i) {
    float4 o4 = {acc[i][0], acc[i][1], acc[i][2], acc[i][3]};
    *(float4*)&raw[(ob + ty * 4 + i) * 1024 + pb + tx * 4] = o4;
  }
}

// gemm_nt: Mo[p,c] = sum_k G[p*1024+k] * O[c*1024+k]. grid = dim3(512/64=8, 1024/64=16)
__global__ __launch_bounds__(256) void gemm_nt(const float* __restrict__ G,
                                               const float* __restrict__ O,
                                               float* __restrict__ Mo) {
  __shared__ float As[32][68];
  __shared__ float Bs[32][68];
  int tid = threadIdx.x;
  int cb = blockIdx.x * 64, pb = blockIdx.y * 64;
  int tx = tid & 15, ty = tid >> 4;
  float acc[4][4] = {};
  for (int k0 = 0; k0 < 1024; k0 += 32) {
    __syncthreads();
#pragma unroll
    for (int r = 0; r < 2; ++r) {
      int v = r * 256 + tid;
      int mm = v >> 3, kq = (v & 7) * 4;
      float4 a = *(const float4*)&G[(pb + mm) * 1024 + k0 + kq];
      As[kq + 0][mm] = a.x; As[kq + 1][mm] = a.y;
      As[kq + 2][mm] = a.z; As[kq + 3][mm] = a.w;
      float4 b = *(const float4*)&O[(cb + mm) * 1024 + k0 + kq];
      Bs[kq + 0][mm] = b.x; Bs[kq + 1][mm] = b.y;
      Bs[kq + 2][mm] = b.z; Bs[kq + 3][mm] = b.w;
    }
    __syncthreads();
#pragma unroll
    for (int k = 0; k < 32; ++k) {
      float4 a = *(const float4*)&As[k][ty * 4];
      float4 b = *(const float4*)&Bs[k][tx * 4];
      float av[4] = {a.x, a.y, a.z, a.w};
      float bv[4] = {b.x, b.y, b.z, b.w};
#pragma unroll
      for (int i = 0; i < 4; ++i)
#pragma unroll
        for (int j = 0; j < 4; ++j) acc[i][j] += av[i] * bv[j];
    }
  }
#pragma unroll
  for (int i = 0; i < 4; ++i) {
    float4 o4 = {acc[i][0], acc[i][1], acc[i][2], acc[i][3]};
    *(float4*)&Mo[(pb + ty * 4 + i) * 512 + cb + tx * 4] = o4;
  }
}

// ---------------- per-channel InstanceNorm + LeakyReLU(0.2) -----------------
__global__ __launch_bounds__(256) void norm_leaky(const float* __restrict__ raw,
                                                  float* __restrict__ out) {
  __shared__ float red[8];
  int c = blockIdx.x, tid = threadIdx.x;
  float v[4];
  float s = 0.f, ss = 0.f;
#pragma unroll
  for (int r = 0; r < 4; ++r) {
    v[r] = raw[c * 1024 + tid + r * 256];
    s += v[r];
    ss += v[r] * v[r];
  }
  breduce2(s, ss, red);
  float mean = s * (1.f / 1024.f);
  float var = ss * (1.f / 1024.f) - mean * mean;
  float inv = rsqrtf(var + EPSN);
#pragma unroll
  for (int r = 0; r < 4; ++r) {
    float t = (v[r] - mean) * inv;
    out[c * 1024 + tid + r * 256] = t >= 0.f ? t : 0.2f * t;
  }
}

// ---------------- transpose out_ral to spatial-major + sigmoid --------------
__global__ __launch_bounds__(256) void transpose_sig(const float* __restrict__ orl,
                                                     float* __restrict__ orl_t,
                                                     float* __restrict__ sig_t) {
  __shared__ float t[32][33];
  int bc = blockIdx.x, bn = blockIdx.y;
  int tx = threadIdx.x & 31, ty = threadIdx.x >> 5;
#pragma unroll
  for (int r0 = 0; r0 < 4; ++r0) {
    int r = ty + r0 * 8;
    t[r][tx] = orl[(bc * 32 + r) * 1024 + bn * 32 + tx];
  }
  __syncthreads();
#pragma unroll
  for (int r0 = 0; r0 < 4; ++r0) {
    int r = ty + r0 * 8;
    float v = t[tx][r];
    int o = (bn * 32 + r) * 512 + bc * 32 + tx;
    orl_t[o] = v;
    sig_t[o] = 1.f / (1.f + expf(-v));
  }
}

// ---------------- CSA attention: 9-tap correlation + softmax ----------------
__global__ __launch_bounds__(256) void csa_attn(const float* __restrict__ sig_t,
                                                float* __restrict__ a9) {
  __shared__ float red[8];
  int n = blockIdx.x, tid = threadIdx.x;
  int ny = n >> 5, nx = n & 31;
  float part[9];
#pragma unroll
  for (int t = 0; t < 9; ++t) part[t] = 0.f;
  for (int c = tid; c < 512; c += 256) {
    float ctr = sig_t[n * 512 + c];
#pragma unroll
    for (int u = 0; u < 3; ++u) {
      int yy = ny + u - 1;
#pragma unroll
      for (int v = 0; v < 3; ++v) {
        int xx = nx + v - 1;
        float nb = ((unsigned)yy < 32u && (unsigned)xx < 32u)
                       ? sig_t[(yy * 32 + xx) * 512 + c] : 0.f;
        part[u * 3 + v] += ctr * nb;
      }
    }
  }
  float a[9];
#pragma unroll
  for (int t = 0; t < 9; ++t) a[t] = breduce_sum(part[t], red) * (1.f / 512.f);
  float mx = a[0];
#pragma unroll
  for (int t = 1; t < 9; ++t) mx = fmaxf(mx, a[t]);
  float sum = 0.f;
#pragma unroll
  for (int t = 0; t < 9; ++t) { a[t] = expf(a[t] - mx); sum += a[t]; }
  float inv = 1.f / sum;
  if (tid == 0) {
#pragma unroll
    for (int t = 0; t < 9; ++t) a9[n * 9 + t] = a[t] * inv;
  }
}

// ---------------- CSA output: weighted 3x3 gather ---------------------------
__global__ void csa_out(const float* __restrict__ a9, const float* __restrict__ orl_t,
                        float* __restrict__ outc) {
  int f = blockIdx.x * 256 + threadIdx.x;
  int n = f >> 9, q = f & 511;
  int ny = n >> 5, nx = n & 31;
  float acc = 0.f;
#pragma unroll
  for (int u = 0; u < 3; ++u) {
    int yy = ny + u - 1;
#pragma unroll
    for (int v = 0; v < 3; ++v) {
      int xx = nx + v - 1;
      if ((unsigned)yy < 32u && (unsigned)xx < 32u)
        acc += a9[n * 9 + u * 3 + v] * orl_t[(yy * 32 + xx) * 512 + q];
    }
  }
  outc[f] = acc;
}

// ---------------- host launch ------------------------------------------------
extern "C" void kernel_launch(void* const* d_in, const int* in_sizes, int n_in,
                              void* d_out, int out_size, void* d_ws, size_t ws_size,
                              hipStream_t stream) {
  const float* x = (const float*)d_in[0];
  const float* gus = (const float*)d_in[1];
  const float* w3 = (const float*)d_in[2];
  const float* b3 = (const float*)d_in[3];
  const float* w5 = (const float*)d_in[4];
  const float* b5 = (const float*)d_in[5];
  const float* w7 = (const float*)d_in[6];
  const float* b7 = (const float*)d_in[7];
  const float* wfc = (const float*)d_in[8];
  const float* bfc = (const float*)d_in[9];
  const float* w0 = (const float*)d_in[10];
  const float* b0 = (const float*)d_in[11];
  const float* w1 = (const float*)d_in[12];
  const float* b1 = (const float*)d_in[13];
  const float* w2 = (const float*)d_in[14];
  const float* b2 = (const float*)d_in[15];
  const float* wdown = (const float*)d_in[16];
  const float* wfuse = (const float*)d_in[17];

  float* ws = (float*)d_ws;
  float* feas = ws;                   // 3*512*1024 (dead after blend; reused as raw)
  float* bmean = feas + 1572864;      // 1536
  float* att = bmean + 1536;          // 1536
  float* res = att + 1536;            // 524288
  float* fgs = res + 524288;          // 131072
  float* A = fgs + 131072;            // 65536
  float* attn = A + 65536;            // 65536
  float* orl = attn + 65536;          // 524288
  float* orlt = orl + 524288;         // 524288
  float* sigt = orlt + 524288;        // 524288
  float* gusout = sigt + 524288;      // 524288
  float* a9 = gusout + 524288;        // 9216
  float* outcsa = a9 + 9216;          // 524288
  float* zdown = outcsa + 524288;     // 524288
  float* raw = feas;                  // reuse (feas dead after blend)

  sk_branch<3><<<512, 256, 0, stream>>>(x, w3, b3, feas, bmean, 0);
  sk_branch<5><<<512, 256, 0, stream>>>(x, w5, b5, feas, bmean, 1);
  sk_branch<7><<<512, 256, 0, stream>>>(x, w7, b7, feas, bmean, 2);
  fc_att<<<1, 256, 0, stream>>>(bmean, wfc, bfc, w0, b0, w1, b1, w2, b2, att);
  blend<<<2048, 256, 0, stream>>>(feas, att, res);
  pool2<<<512, 256, 0, stream>>>(res, fgs);
  gram<<<256, 256, 0, stream>>>(fgs, A);
  attn_softmax<<<256, 256, 0, stream>>>(A, attn);
  tconv<<<512, 256, 0, stream>>>(res, attn, orl);
  gemm_nt<<<dim3(8, 16), 256, 0, stream>>>(gus, orl, gusout);
  transpose_sig<<<dim3(16, 32), 256, 0, stream>>>(orl, orlt, sigt);
  csa_attn<<<1024, 256, 0, stream>>>(sigt, a9);
  csa_out<<<2048, 256, 0, stream>>>(a9, orlt, outcsa);
  gemm_nn<<<dim3(16, 8), 256, 0, stream>>>(wdown, gusout, outcsa, raw);
  norm_leaky<<<512, 256, 0, stream>>>(raw, zdown);
  gemm_nn<<<dim3(16, 8), 256, 0, stream>>>(wfuse, zdown, res, raw);
  norm_leaky<<<512, 256, 0, stream>>>(raw, (float*)d_out);
}

// Round 3
// 424.941 us; speedup vs baseline: 2.1736x; 1.4932x over previous
//
#include <hip/hip_runtime.h>
#include <math.h>

#define EPSN 1e-5f

// ---------------- block-wide reductions (blockDim.x == 256, 4 waves) --------
__device__ __forceinline__ void breduce2(float& a, float& b, float* lds) {
#pragma unroll
  for (int o = 32; o > 0; o >>= 1) {
    a += __shfl_down(a, o);
    b += __shfl_down(b, o);
  }
  int lane = threadIdx.x & 63, wid = threadIdx.x >> 6;
  __syncthreads();
  if (lane == 0) { lds[wid] = a; lds[4 + wid] = b; }
  __syncthreads();
  a = lds[0] + lds[1] + lds[2] + lds[3];
  b = lds[4] + lds[5] + lds[6] + lds[7];
}

__device__ __forceinline__ float breduce_sum(float v, float* lds) {
#pragma unroll
  for (int o = 32; o > 0; o >>= 1) v += __shfl_down(v, o);
  int lane = threadIdx.x & 63, wid = threadIdx.x >> 6;
  __syncthreads();
  if (lane == 0) lds[wid] = v;
  __syncthreads();
  return lds[0] + lds[1] + lds[2] + lds[3];
}

__device__ __forceinline__ float breduce_max(float v, float* lds) {
#pragma unroll
  for (int o = 32; o > 0; o >>= 1) v = fmaxf(v, __shfl_down(v, o));
  int lane = threadIdx.x & 63, wid = threadIdx.x >> 6;
  __syncthreads();
  if (lane == 0) lds[wid] = v;
  __syncthreads();
  return fmaxf(fmaxf(lds[0], lds[1]), fmaxf(lds[2], lds[3]));
}

// ---------------- fused SKConv: all 3 branches in one pass ------------------
// block = one output channel c. Thread: row y = tid>>3, 4 consecutive x.
// chanp padded by 3 (for k=7); k=5/k=3 taps are interior-offset subsets.
__device__ __forceinline__ void finish_branch(float* acc, float bv, int m, int c,
                                              int y, int xb, float* feas,
                                              float* bmean, float* red) {
  float s = 0.f, ss = 0.f;
#pragma unroll
  for (int r = 0; r < 4; ++r) {
    acc[r] += bv;
    s += acc[r];
    ss += acc[r] * acc[r];
  }
  breduce2(s, ss, red);
  float mean = s * (1.f / 1024.f);
  float var = ss * (1.f / 1024.f) - mean * mean;
  float inv = rsqrtf(var + EPSN);
  float4 o;
  float* ov = (float*)&o;
  float rs = 0.f;
#pragma unroll
  for (int r = 0; r < 4; ++r) {
    float v = (acc[r] - mean) * inv;
    v = v > 0.f ? v : 0.f;
    ov[r] = v;
    rs += v;
  }
  *(float4*)&feas[(m * 512 + c) * 1024 + y * 32 + xb] = o;
  float tot = breduce_sum(rs, red);
  if (threadIdx.x == 0) bmean[m * 512 + c] = tot * (1.f / 1024.f);
}

__global__ __launch_bounds__(256) void sk_all(
    const float* __restrict__ x, const float* __restrict__ w3,
    const float* __restrict__ b3, const float* __restrict__ w5,
    const float* __restrict__ b5, const float* __restrict__ w7,
    const float* __restrict__ b7, float* __restrict__ feas,
    float* __restrict__ bmean) {
  __shared__ float chanp[38 * 38];
  __shared__ float ws7[784];
  __shared__ float ws5[400];
  __shared__ float ws3[144];
  __shared__ float red[8];
  int c = blockIdx.x, tid = threadIdx.x, g = c >> 4;
  for (int i = tid; i < 1444; i += 256) chanp[i] = 0.f;
  for (int i = tid; i < 784; i += 256) ws7[i] = w7[c * 784 + i];
  for (int i = tid; i < 400; i += 256) ws5[i] = w5[c * 400 + i];
  for (int i = tid; i < 144; i += 256) ws3[i] = w3[c * 144 + i];
  int y = tid >> 3, xb = (tid & 7) * 4;
  float a3[4] = {}, a5[4] = {}, a7[4] = {};
  for (int ic = 0; ic < 16; ++ic) {
    __syncthreads();
    for (int i = tid; i < 1024; i += 256)
      chanp[((i >> 5) + 3) * 38 + (i & 31) + 3] = x[(g * 16 + ic) * 1024 + i];
    __syncthreads();
    const float* W7 = ws7 + ic * 49;
    const float* W5 = ws5 + ic * 25;
    const float* W3 = ws3 + ic * 9;
#pragma unroll
    for (int dy = 0; dy < 7; ++dy) {
      float seg[10];
      const float* row = &chanp[(y + dy) * 38 + xb];
#pragma unroll
      for (int t = 0; t < 10; ++t) seg[t] = row[t];
#pragma unroll
      for (int kx = 0; kx < 7; ++kx) {
        float wv = W7[dy * 7 + kx];
#pragma unroll
        for (int px = 0; px < 4; ++px) a7[px] += seg[px + kx] * wv;
      }
      if (dy >= 1 && dy <= 5) {
#pragma unroll
        for (int kx = 0; kx < 5; ++kx) {
          float wv = W5[(dy - 1) * 5 + kx];
#pragma unroll
          for (int px = 0; px < 4; ++px) a5[px] += seg[px + kx + 1] * wv;
        }
      }
      if (dy >= 2 && dy <= 4) {
#pragma unroll
        for (int kx = 0; kx < 3; ++kx) {
          float wv = W3[(dy - 2) * 3 + kx];
#pragma unroll
          for (int px = 0; px < 4; ++px) a3[px] += seg[px + kx + 2] * wv;
        }
      }
    }
  }
  finish_branch(a3, b3[c], 0, c, y, xb, feas, bmean, red);
  finish_branch(a5, b5[c], 1, c, y, xb, feas, bmean, red);
  finish_branch(a7, b7[c], 2, c, y, xb, feas, bmean, red);
}

// ---------------- FC chain + branch softmax (one block) ---------------------
__global__ __launch_bounds__(256) void fc_att(
    const float* __restrict__ bmean, const float* __restrict__ w_fc,
    const float* __restrict__ b_fc, const float* __restrict__ w0,
    const float* __restrict__ b0, const float* __restrict__ w1,
    const float* __restrict__ b1, const float* __restrict__ w2,
    const float* __restrict__ b2, float* __restrict__ att) {
  __shared__ float sfea[512];
  __shared__ float zz[32];
  int tid = threadIdx.x;
  for (int c = tid; c < 512; c += 256)
    sfea[c] = bmean[c] + bmean[512 + c] + bmean[1024 + c];
  __syncthreads();
  if (tid < 32) {
    float d = b_fc[tid];
    for (int c = 0; c < 512; ++c) d += sfea[c] * w_fc[tid * 512 + c];
    zz[tid] = d;
  }
  __syncthreads();
  for (int c = tid; c < 512; c += 256) {
    float l0 = b0[c], l1 = b1[c], l2 = b2[c];
#pragma unroll
    for (int j = 0; j < 32; ++j) {
      float z = zz[j];
      l0 += z * w0[c * 32 + j];
      l1 += z * w1[c * 32 + j];
      l2 += z * w2[c * 32 + j];
    }
    float mx = fmaxf(l0, fmaxf(l1, l2));
    float e0 = expf(l0 - mx), e1 = expf(l1 - mx), e2 = expf(l2 - mx);
    float inv = 1.f / (e0 + e1 + e2);
    att[c] = e0 * inv;
    att[512 + c] = e1 * inv;
    att[1024 + c] = e2 * inv;
  }
}

// ---------------- attention blend -> res (ch-major) + rest (pos-major) ------
// grid = (32 pos-tiles, 16 c-tiles), 256 threads
__global__ __launch_bounds__(256) void blend_t(const float* __restrict__ feas,
                                               const float* __restrict__ att,
                                               float* __restrict__ res,
                                               float* __restrict__ rest) {
  __shared__ float t[32][33];
  int pb = blockIdx.x * 32, cb = blockIdx.y * 32;
  int tx = threadIdx.x & 31, ty = threadIdx.x >> 5;
#pragma unroll
  for (int r = 0; r < 4; ++r) {
    int cl = ty + r * 8;
    int c = cb + cl, pos = pb + tx;
    float v = feas[c * 1024 + pos] * att[c] +
              feas[(512 + c) * 1024 + pos] * att[512 + c] +
              feas[(1024 + c) * 1024 + pos] * att[1024 + c];
    res[c * 1024 + pos] = v;
    t[cl][tx] = v;
  }
  __syncthreads();
#pragma unroll
  for (int r = 0; r < 4; ++r) {
    int pl = ty + r * 8;
    rest[(pb + pl) * 512 + cb + tx] = t[tx][pl];
  }
}

// ---------------- 2x2 average pool -> fg_small (512,16,16) ------------------
__global__ void pool2(const float* __restrict__ res, float* __restrict__ fgs) {
  int idx = blockIdx.x * 256 + threadIdx.x;
  int c = idx >> 8;
  int rem = idx & 255;
  int i = rem >> 4, j = rem & 15;
  const float* base = res + c * 1024 + (2 * i) * 32 + 2 * j;
  fgs[idx] = 0.25f * (base[0] + base[1] + base[32] + base[33]);
}

// ---------------- Gram matrix of 3x3x512 neighborhoods (256x256) ------------
__global__ __launch_bounds__(256) void gram(const float* __restrict__ fgs,
                                            float* __restrict__ A) {
  __shared__ float ch[8][324];
  int p = blockIdx.x, q = threadIdx.x;
  int pi = p >> 4, pj = p & 15, qi = q >> 4, qj = q & 15;
  for (int i = threadIdx.x; i < 8 * 324; i += 256) ((float*)ch)[i] = 0.f;
  float acc = 0.f;
  for (int c0 = 0; c0 < 512; c0 += 8) {
    __syncthreads();
#pragma unroll
    for (int cc = 0; cc < 8; ++cc)
      ch[cc][((q >> 4) + 1) * 18 + (q & 15) + 1] = fgs[(c0 + cc) * 256 + q];
    __syncthreads();
#pragma unroll
    for (int cc = 0; cc < 8; ++cc) {
#pragma unroll
      for (int u = 0; u < 3; ++u)
#pragma unroll
        for (int v = 0; v < 3; ++v)
          acc += ch[cc][(pi + u) * 18 + pj + v] * ch[cc][(qi + u) * 18 + qj + v];
    }
  }
  A[p * 256 + q] = acc;
}

// ---------------- RAL attention softmax over patch axis ---------------------
__global__ __launch_bounds__(256) void attn_softmax(const float* __restrict__ A,
                                                    float* __restrict__ attn) {
  __shared__ float red[8];
  int q = blockIdx.x, t = threadIdx.x;
  float nrm = sqrtf(fmaxf(A[t * 256 + t], 0.f));
  float v = A[t * 256 + q] / fmaxf(nrm, 1e-4f) * 10.f;
  float mx = breduce_max(v, red);
  float e = expf(v - mx);
  float sm = breduce_sum(e, red);
  attn[t * 256 + q] = e / sm;
}

// ---------------- tconv as 16-batch GEMM ------------------------------------
// T[b][q][c] = sum_p attn[p,q] * rest[spos_b(p)][c]; b=(ki,kj)
// grid = (8 c-tiles, 4 q-tiles, 16 batches)
__global__ __launch_bounds__(256) void tconv_gemm(const float* __restrict__ attn,
                                                  const float* __restrict__ rest,
                                                  float* __restrict__ T) {
  __shared__ float As[32][68];
  __shared__ float Bs[32][68];
  int tid = threadIdx.x;
  int cb = blockIdx.x * 64, qb = blockIdx.y * 64;
  int b = blockIdx.z;
  int ki = b >> 2, kj = b & 3;
  int tx = tid & 15, ty = tid >> 4;
  float acc[4][4] = {};
  for (int k0 = 0; k0 < 256; k0 += 32) {
    __syncthreads();
#pragma unroll
    for (int r = 0; r < 2; ++r) {
      int v = r * 256 + tid;
      int kk = v >> 4, e4 = (v & 15) * 4;
      int p = k0 + kk;
      *(float4*)&As[kk][e4] = *(const float4*)&attn[p * 256 + qb + e4];
      int ry = 2 * (p >> 4) + ki - 1;
      int rx = 2 * (p & 15) + kj - 1;
      float4 bv = {0.f, 0.f, 0.f, 0.f};
      if ((unsigned)ry < 32u && (unsigned)rx < 32u)
        bv = *(const float4*)&rest[(ry * 32 + rx) * 512 + cb + e4];
      *(float4*)&Bs[kk][e4] = bv;
    }
    __syncthreads();
#pragma unroll
    for (int k = 0; k < 32; ++k) {
      float4 a = *(const float4*)&As[k][ty * 4];
      float4 bb = *(const float4*)&Bs[k][tx * 4];
      float av[4] = {a.x, a.y, a.z, a.w};
      float bw[4] = {bb.x, bb.y, bb.z, bb.w};
#pragma unroll
      for (int i = 0; i < 4; ++i)
#pragma unroll
        for (int j = 0; j < 4; ++j) acc[i][j] += av[i] * bw[j];
    }
  }
#pragma unroll
  for (int i = 0; i < 4; ++i) {
    float4 o4 = {acc[i][0], acc[i][1], acc[i][2], acc[i][3]};
    *(float4*)&T[(b * 256 + qb + ty * 4 + i) * 512 + cb + tx * 4] = o4;
  }
}

// ---------------- combine taps -> orlt (pos-major) + sigt -------------------
__global__ void tcomb(const float* __restrict__ T, float* __restrict__ orlt,
                      float* __restrict__ sigt) {
  int f = blockIdx.x * 256 + threadIdx.x;  // 524288
  int n = f >> 9, c = f & 511;
  int y = n >> 5, x = n & 31;
  int i0 = (y + 1) >> 1, ki0 = (y + 1) & 1;
  int j0 = (x + 1) >> 1, kj0 = (x + 1) & 1;
  float sum = 0.f;
#pragma unroll
  for (int iy = 0; iy < 2; ++iy) {
    int i = i0 - iy, ki = ki0 + 2 * iy;
    if ((unsigned)i >= 16u) continue;
#pragma unroll
    for (int ix = 0; ix < 2; ++ix) {
      int j = j0 - ix, kj = kj0 + 2 * ix;
      if ((unsigned)j >= 16u) continue;
      sum += T[((ki * 4 + kj) * 256 + i * 16 + j) * 512 + c];
    }
  }
  float v = sum * 0.25f;
  orlt[f] = v;
  sigt[f] = 1.f / (1.f + expf(-v));
}

// ---------------- gus einsum: Mo[p,c] = sum_k gus[p,k] * orlt[k,c] ----------
// grid = (8 c-tiles, 16 p-tiles)
__global__ __launch_bounds__(256) void gemm_gus(const float* __restrict__ G,
                                                const float* __restrict__ orlt,
                                                float* __restrict__ Mo) {
  __shared__ float As[32][68];
  __shared__ float Bs[32][68];
  int tid = threadIdx.x;
  int cb = blockIdx.x * 64, pb = blockIdx.y * 64;
  int tx = tid & 15, ty = tid >> 4;
  float acc[4][4] = {};
  for (int k0 = 0; k0 < 1024; k0 += 32) {
    __syncthreads();
#pragma unroll
    for (int r = 0; r < 2; ++r) {
      int v = r * 256 + tid;
      int mm = v >> 3, kq = (v & 7) * 4;
      float4 a = *(const float4*)&G[(pb + mm) * 1024 + k0 + kq];
      As[kq + 0][mm] = a.x; As[kq + 1][mm] = a.y;
      As[kq + 2][mm] = a.z; As[kq + 3][mm] = a.w;
      int kk = v >> 4, c4 = (v & 15) * 4;
      *(float4*)&Bs[kk][c4] = *(const float4*)&orlt[(k0 + kk) * 512 + cb + c4];
    }
    __syncthreads();
#pragma unroll
    for (int k = 0; k < 32; ++k) {
      float4 a = *(const float4*)&As[k][ty * 4];
      float4 bb = *(const float4*)&Bs[k][tx * 4];
      float av[4] = {a.x, a.y, a.z, a.w};
      float bw[4] = {bb.x, bb.y, bb.z, bb.w};
#pragma unroll
      for (int i = 0; i < 4; ++i)
#pragma unroll
        for (int j = 0; j < 4; ++j) acc[i][j] += av[i] * bw[j];
    }
  }
#pragma unroll
  for (int i = 0; i < 4; ++i) {
    float4 o4 = {acc[i][0], acc[i][1], acc[i][2], acc[i][3]};
    *(float4*)&Mo[(pb + ty * 4 + i) * 512 + cb + tx * 4] = o4;
  }
}

// ---------------- CSA attention: 9-tap correlation + softmax ----------------
__global__ __launch_bounds__(256) void csa_attn(const float* __restrict__ sig_t,
                                                float* __restrict__ a9) {
  __shared__ float red[8];
  int n = blockIdx.x, tid = threadIdx.x;
  int ny = n >> 5, nx = n & 31;
  float part[9];
#pragma unroll
  for (int t = 0; t < 9; ++t) part[t] = 0.f;
  for (int c = tid; c < 512; c += 256) {
    float ctr = sig_t[n * 512 + c];
#pragma unroll
    for (int u = 0; u < 3; ++u) {
      int yy = ny + u - 1;
#pragma unroll
      for (int v = 0; v < 3; ++v) {
        int xx = nx + v - 1;
        float nb = ((unsigned)yy < 32u && (unsigned)xx < 32u)
                       ? sig_t[(yy * 32 + xx) * 512 + c] : 0.f;
        part[u * 3 + v] += ctr * nb;
      }
    }
  }
  float a[9];
#pragma unroll
  for (int t = 0; t < 9; ++t) a[t] = breduce_sum(part[t], red) * (1.f / 512.f);
  float mx = a[0];
#pragma unroll
  for (int t = 1; t < 9; ++t) mx = fmaxf(mx, a[t]);
  float sum = 0.f;
#pragma unroll
  for (int t = 0; t < 9; ++t) { a[t] = expf(a[t] - mx); sum += a[t]; }
  float inv = 1.f / sum;
  if (tid == 0) {
#pragma unroll
    for (int t = 0; t < 9; ++t) a9[n * 9 + t] = a[t] * inv;
  }
}

// ---------------- CSA output: weighted 3x3 gather ---------------------------
__global__ void csa_out(const float* __restrict__ a9, const float* __restrict__ orl_t,
                        float* __restrict__ outc) {
  int f = blockIdx.x * 256 + threadIdx.x;
  int n = f >> 9, q = f & 511;
  int ny = n >> 5, nx = n & 31;
  float acc = 0.f;
#pragma unroll
  for (int u = 0; u < 3; ++u) {
    int yy = ny + u - 1;
#pragma unroll
    for (int v = 0; v < 3; ++v) {
      int xx = nx + v - 1;
      if ((unsigned)yy < 32u && (unsigned)xx < 32u)
        acc += a9[n * 9 + u * 3 + v] * orl_t[(yy * 32 + xx) * 512 + q];
    }
  }
  outc[f] = acc;
}

// ---------------- 64x64-tile GEMM for the 1x1 convs -------------------------
__global__ __launch_bounds__(256) void gemm_nn(const float* __restrict__ w,
                                               const float* __restrict__ za,
                                               const float* __restrict__ zb,
                                               float* __restrict__ raw) {
  __shared__ float As[32][68];
  __shared__ float Bs[32][68];
  int tid = threadIdx.x;
  int pb = blockIdx.x * 64, ob = blockIdx.y * 64;
  int tx = tid & 15, ty = tid >> 4;
  float acc[4][4] = {};
  for (int k0 = 0; k0 < 1024; k0 += 32) {
    const float* Bsrc =
        (k0 < 512) ? za + (size_t)k0 * 1024 : zb + (size_t)(k0 - 512) * 1024;
    __syncthreads();
#pragma unroll
    for (int r = 0; r < 2; ++r) {
      int v = r * 256 + tid;
      int mm = v >> 3, kq = (v & 7) * 4;
      float4 a = *(const float4*)&w[(ob + mm) * 1024 + k0 + kq];
      As[kq + 0][mm] = a.x; As[kq + 1][mm] = a.y;
      As[kq + 2][mm] = a.z; As[kq + 3][mm] = a.w;
      int kk = v >> 4, pq = (v & 15) * 4;
      *(float4*)&Bs[kk][pq] = *(const float4*)&Bsrc[kk * 1024 + pb + pq];
    }
    __syncthreads();
#pragma unroll
    for (int k = 0; k < 32; ++k) {
      float4 a = *(const float4*)&As[k][ty * 4];
      float4 bb = *(const float4*)&Bs[k][tx * 4];
      float av[4] = {a.x, a.y, a.z, a.w};
      float bw[4] = {bb.x, bb.y, bb.z, bb.w};
#pragma unroll
      for (int i = 0; i < 4; ++i)
#pragma unroll
        for (int j = 0; j < 4; ++j) acc[i][j] += av[i] * bw[j];
    }
  }
#pragma unroll
  for (int i = 0; i < 4; ++i) {
    float4 o4 = {acc[i][0], acc[i][1], acc[i][2], acc[i][3]};
    *(float4*)&raw[(ob + ty * 4 + i) * 1024 + pb + tx * 4] = o4;
  }
}

// ---------------- per-channel InstanceNorm + LeakyReLU(0.2) -----------------
__global__ __launch_bounds__(256) void norm_leaky(const float* __restrict__ raw,
                                                  float* __restrict__ out) {
  __shared__ float red[8];
  int c = blockIdx.x, tid = threadIdx.x;
  float v[4];
  float s = 0.f, ss = 0.f;
#pragma unroll
  for (int r = 0; r < 4; ++r) {
    v[r] = raw[c * 1024 + tid + r * 256];
    s += v[r];
    ss += v[r] * v[r];
  }
  breduce2(s, ss, red);
  float mean = s * (1.f / 1024.f);
  float var = ss * (1.f / 1024.f) - mean * mean;
  float inv = rsqrtf(var + EPSN);
#pragma unroll
  for (int r = 0; r < 4; ++r) {
    float t = (v[r] - mean) * inv;
    out[c * 1024 + tid + r * 256] = t >= 0.f ? t : 0.2f * t;
  }
}

// ---------------- host launch ------------------------------------------------
extern "C" void kernel_launch(void* const* d_in, const int* in_sizes, int n_in,
                              void* d_out, int out_size, void* d_ws, size_t ws_size,
                              hipStream_t stream) {
  const float* x = (const float*)d_in[0];
  const float* gus = (const float*)d_in[1];
  const float* w3 = (const float*)d_in[2];
  const float* b3 = (const float*)d_in[3];
  const float* w5 = (const float*)d_in[4];
  const float* b5 = (const float*)d_in[5];
  const float* w7 = (const float*)d_in[6];
  const float* b7 = (const float*)d_in[7];
  const float* wfc = (const float*)d_in[8];
  const float* bfc = (const float*)d_in[9];
  const float* w0 = (const float*)d_in[10];
  const float* b0 = (const float*)d_in[11];
  const float* w1 = (const float*)d_in[12];
  const float* b1 = (const float*)d_in[13];
  const float* w2 = (const float*)d_in[14];
  const float* b2 = (const float*)d_in[15];
  const float* wdown = (const float*)d_in[16];
  const float* wfuse = (const float*)d_in[17];

  float* ws = (float*)d_ws;
  float* feas = ws;                   // 1572864 (dead after blend_t; reused as raw)
  float* bmean = feas + 1572864;      // 1536
  float* att = bmean + 1536;          // 1536
  float* res = att + 1536;            // 524288
  float* rest = res + 524288;         // 524288 (pos-major res)
  float* fgs = rest + 524288;         // 131072
  float* A = fgs + 131072;            // 65536
  float* attn = A + 65536;            // 65536
  float* T = attn + 65536;            // 2097152 (16x256x512)
  float* orlt = T + 2097152;          // 524288
  float* sigt = orlt + 524288;        // 524288
  float* gusout = sigt + 524288;      // 524288
  float* a9 = gusout + 524288;        // 9216
  float* outcsa = a9 + 9216;          // 524288
  float* zdown = outcsa + 524288;     // 524288
  float* raw = feas;                  // reuse

  sk_all<<<512, 256, 0, stream>>>(x, w3, b3, w5, b5, w7, b7, feas, bmean);
  fc_att<<<1, 256, 0, stream>>>(bmean, wfc, bfc, w0, b0, w1, b1, w2, b2, att);
  blend_t<<<dim3(32, 16), 256, 0, stream>>>(feas, att, res, rest);
  pool2<<<512, 256, 0, stream>>>(res, fgs);
  gram<<<256, 256, 0, stream>>>(fgs, A);
  attn_softmax<<<256, 256, 0, stream>>>(A, attn);
  tconv_gemm<<<dim3(8, 4, 16), 256, 0, stream>>>(attn, rest, T);
  tcomb<<<2048, 256, 0, stream>>>(T, orlt, sigt);
  gemm_gus<<<dim3(8, 16), 256, 0, stream>>>(gus, orlt, gusout);
  csa_attn<<<1024, 256, 0, stream>>>(sigt, a9);
  csa_out<<<2048, 256, 0, stream>>>(a9, orlt, outcsa);
  gemm_nn<<<dim3(16, 8), 256, 0, stream>>>(wdown, gusout, outcsa, raw);
  norm_leaky<<<512, 256, 0, stream>>>(raw, zdown);
  gemm_nn<<<dim3(16, 8), 256, 0, stream>>>(wfuse, zdown, res, raw);
  norm_leaky<<<512, 256, 0, stream>>>(raw, (float*)d_out);
}

// Round 4
// 362.155 us; speedup vs baseline: 2.5504x; 1.1734x over previous
//
#include <hip/hip_runtime.h>
#include <math.h>

#define EPSN 1e-5f

// ---------------- block-wide reductions (blockDim.x == 256, 4 waves) --------
__device__ __forceinline__ void breduce2(float& a, float& b, float* lds) {
#pragma unroll
  for (int o = 32; o > 0; o >>= 1) {
    a += __shfl_down(a, o);
    b += __shfl_down(b, o);
  }
  int lane = threadIdx.x & 63, wid = threadIdx.x >> 6;
  __syncthreads();
  if (lane == 0) { lds[wid] = a; lds[4 + wid] = b; }
  __syncthreads();
  a = lds[0] + lds[1] + lds[2] + lds[3];
  b = lds[4] + lds[5] + lds[6] + lds[7];
}

__device__ __forceinline__ float breduce_sum(float v, float* lds) {
#pragma unroll
  for (int o = 32; o > 0; o >>= 1) v += __shfl_down(v, o);
  int lane = threadIdx.x & 63, wid = threadIdx.x >> 6;
  __syncthreads();
  if (lane == 0) lds[wid] = v;
  __syncthreads();
  return lds[0] + lds[1] + lds[2] + lds[3];
}

__device__ __forceinline__ float breduce_max(float v, float* lds) {
#pragma unroll
  for (int o = 32; o > 0; o >>= 1) v = fmaxf(v, __shfl_down(v, o));
  int lane = threadIdx.x & 63, wid = threadIdx.x >> 6;
  __syncthreads();
  if (lane == 0) lds[wid] = v;
  __syncthreads();
  return fmaxf(fmaxf(lds[0], lds[1]), fmaxf(lds[2], lds[3]));
}

// ---------------- fused SKConv: all 3 branches in one pass ------------------
__device__ __forceinline__ void finish_branch(float* acc, float bv, int m, int c,
                                              int y, int xb, float* feas,
                                              float* bmean, float* red) {
  float s = 0.f, ss = 0.f;
#pragma unroll
  for (int r = 0; r < 4; ++r) {
    acc[r] += bv;
    s += acc[r];
    ss += acc[r] * acc[r];
  }
  breduce2(s, ss, red);
  float mean = s * (1.f / 1024.f);
  float var = ss * (1.f / 1024.f) - mean * mean;
  float inv = rsqrtf(var + EPSN);
  float4 o;
  float* ov = (float*)&o;
  float rs = 0.f;
#pragma unroll
  for (int r = 0; r < 4; ++r) {
    float v = (acc[r] - mean) * inv;
    v = v > 0.f ? v : 0.f;
    ov[r] = v;
    rs += v;
  }
  *(float4*)&feas[(m * 512 + c) * 1024 + y * 32 + xb] = o;
  float tot = breduce_sum(rs, red);
  if (threadIdx.x == 0) bmean[m * 512 + c] = tot * (1.f / 1024.f);
}

__global__ __launch_bounds__(256) void sk_all(
    const float* __restrict__ x, const float* __restrict__ w3,
    const float* __restrict__ b3, const float* __restrict__ w5,
    const float* __restrict__ b5, const float* __restrict__ w7,
    const float* __restrict__ b7, float* __restrict__ feas,
    float* __restrict__ bmean) {
  __shared__ float chanp[38 * 38];
  __shared__ float ws7[784];
  __shared__ float ws5[400];
  __shared__ float ws3[144];
  __shared__ float red[8];
  int c = blockIdx.x, tid = threadIdx.x, g = c >> 4;
  for (int i = tid; i < 1444; i += 256) chanp[i] = 0.f;
  for (int i = tid; i < 784; i += 256) ws7[i] = w7[c * 784 + i];
  for (int i = tid; i < 400; i += 256) ws5[i] = w5[c * 400 + i];
  for (int i = tid; i < 144; i += 256) ws3[i] = w3[c * 144 + i];
  int y = tid >> 3, xb = (tid & 7) * 4;
  float a3[4] = {}, a5[4] = {}, a7[4] = {};
  for (int ic = 0; ic < 16; ++ic) {
    __syncthreads();
    for (int i = tid; i < 1024; i += 256)
      chanp[((i >> 5) + 3) * 38 + (i & 31) + 3] = x[(g * 16 + ic) * 1024 + i];
    __syncthreads();
    const float* W7 = ws7 + ic * 49;
    const float* W5 = ws5 + ic * 25;
    const float* W3 = ws3 + ic * 9;
#pragma unroll
    for (int dy = 0; dy < 7; ++dy) {
      float seg[10];
      const float* row = &chanp[(y + dy) * 38 + xb];
#pragma unroll
      for (int t = 0; t < 10; ++t) seg[t] = row[t];
#pragma unroll
      for (int kx = 0; kx < 7; ++kx) {
        float wv = W7[dy * 7 + kx];
#pragma unroll
        for (int px = 0; px < 4; ++px) a7[px] += seg[px + kx] * wv;
      }
      if (dy >= 1 && dy <= 5) {
#pragma unroll
        for (int kx = 0; kx < 5; ++kx) {
          float wv = W5[(dy - 1) * 5 + kx];
#pragma unroll
          for (int px = 0; px < 4; ++px) a5[px] += seg[px + kx + 1] * wv;
        }
      }
      if (dy >= 2 && dy <= 4) {
#pragma unroll
        for (int kx = 0; kx < 3; ++kx) {
          float wv = W3[(dy - 2) * 3 + kx];
#pragma unroll
          for (int px = 0; px < 4; ++px) a3[px] += seg[px + kx + 2] * wv;
        }
      }
    }
  }
  finish_branch(a3, b3[c], 0, c, y, xb, feas, bmean, red);
  finish_branch(a5, b5[c], 1, c, y, xb, feas, bmean, red);
  finish_branch(a7, b7[c], 2, c, y, xb, feas, bmean, red);
}

// ---------------- FC chain + branch softmax (one block) ---------------------
__global__ __launch_bounds__(256) void fc_att(
    const float* __restrict__ bmean, const float* __restrict__ w_fc,
    const float* __restrict__ b_fc, const float* __restrict__ w0,
    const float* __restrict__ b0, const float* __restrict__ w1,
    const float* __restrict__ b1, const float* __restrict__ w2,
    const float* __restrict__ b2, float* __restrict__ att) {
  __shared__ float sfea[512];
  __shared__ float zz[32];
  int tid = threadIdx.x;
  for (int c = tid; c < 512; c += 256)
    sfea[c] = bmean[c] + bmean[512 + c] + bmean[1024 + c];
  __syncthreads();
  if (tid < 32) {
    float d = b_fc[tid];
    for (int c = 0; c < 512; ++c) d += sfea[c] * w_fc[tid * 512 + c];
    zz[tid] = d;
  }
  __syncthreads();
  for (int c = tid; c < 512; c += 256) {
    float l0 = b0[c], l1 = b1[c], l2 = b2[c];
#pragma unroll
    for (int j = 0; j < 32; ++j) {
      float z = zz[j];
      l0 += z * w0[c * 32 + j];
      l1 += z * w1[c * 32 + j];
      l2 += z * w2[c * 32 + j];
    }
    float mx = fmaxf(l0, fmaxf(l1, l2));
    float e0 = expf(l0 - mx), e1 = expf(l1 - mx), e2 = expf(l2 - mx);
    float inv = 1.f / (e0 + e1 + e2);
    att[c] = e0 * inv;
    att[512 + c] = e1 * inv;
    att[1024 + c] = e2 * inv;
  }
}

// ---------------- attention blend -> res (ch-major) + rest (pos-major) ------
__global__ __launch_bounds__(256) void blend_t(const float* __restrict__ feas,
                                               const float* __restrict__ att,
                                               float* __restrict__ res,
                                               float* __restrict__ rest) {
  __shared__ float t[32][33];
  int pb = blockIdx.x * 32, cb = blockIdx.y * 32;
  int tx = threadIdx.x & 31, ty = threadIdx.x >> 5;
#pragma unroll
  for (int r = 0; r < 4; ++r) {
    int cl = ty + r * 8;
    int c = cb + cl, pos = pb + tx;
    float v = feas[c * 1024 + pos] * att[c] +
              feas[(512 + c) * 1024 + pos] * att[512 + c] +
              feas[(1024 + c) * 1024 + pos] * att[1024 + c];
    res[c * 1024 + pos] = v;
    t[cl][tx] = v;
  }
  __syncthreads();
#pragma unroll
  for (int r = 0; r < 4; ++r) {
    int pl = ty + r * 8;
    rest[(pb + pl) * 512 + cb + tx] = t[tx][pl];
  }
}

// ---------------- 2x2 average pool -> fg_small (512,16,16) ------------------
__global__ void pool2(const float* __restrict__ res, float* __restrict__ fgs) {
  int idx = blockIdx.x * 256 + threadIdx.x;
  int c = idx >> 8;
  int rem = idx & 255;
  int i = rem >> 4, j = rem & 15;
  const float* base = res + c * 1024 + (2 * i) * 32 + 2 * j;
  fgs[idx] = 0.25f * (base[0] + base[1] + base[32] + base[33]);
}

// ---------------- Gram split-K partials -------------------------------------
// A[p,q] = sum_c sum_{3x3} fgsp[c][p+t] * fgsp[c][q+t]
// grid (4 q-tiles, 4 p-tiles, 16 k-chunks of 32 channels); 4x4 micro-tile.
__global__ __launch_bounds__(256) void gram_part(const float* __restrict__ fgs,
                                                 float* __restrict__ Apart) {
  __shared__ float ch[4][324];  // 4 channels, 18x18 zero-padded
  int tid = threadIdx.x;
  int qb = blockIdx.x * 64, pb = blockIdx.y * 64;
  int kc = blockIdx.z;
  int tx = tid & 15, ty = tid >> 4;
  for (int i = tid; i < 4 * 324; i += 256) ((float*)ch)[i] = 0.f;
  int pi = (pb + ty * 4) >> 4, pj = (pb + ty * 4) & 15;
  int qi = (qb + tx * 4) >> 4, qj = (qb + tx * 4) & 15;
  int lane = tid & 63, wv = tid >> 6;
  int sr = lane >> 2, sc = (lane & 3) * 4;
  float acc[4][4] = {};
  for (int c0 = kc * 32; c0 < kc * 32 + 32; c0 += 4) {
    __syncthreads();
    {  // wave wv stages channel c0+wv (lane: one float4 of the 16x16 interior)
      float4 v = *(const float4*)&fgs[(c0 + wv) * 256 + lane * 4];
      float* dst = &ch[wv][(sr + 1) * 18 + sc + 1];
      dst[0] = v.x; dst[1] = v.y; dst[2] = v.z; dst[3] = v.w;
    }
    __syncthreads();
#pragma unroll
    for (int cc = 0; cc < 4; ++cc) {
      float ps[3][6], qs[3][6];
#pragma unroll
      for (int u = 0; u < 3; ++u) {
        const float* pr = &ch[cc][(pi + u) * 18 + pj];
        const float* qr = &ch[cc][(qi + u) * 18 + qj];
#pragma unroll
        for (int t = 0; t < 6; ++t) { ps[u][t] = pr[t]; qs[u][t] = qr[t]; }
      }
#pragma unroll
      for (int u = 0; u < 3; ++u)
#pragma unroll
        for (int v = 0; v < 3; ++v)
#pragma unroll
          for (int i = 0; i < 4; ++i)
#pragma unroll
            for (int j = 0; j < 4; ++j)
              acc[i][j] += ps[u][v + i] * qs[u][v + j];
    }
  }
#pragma unroll
  for (int i = 0; i < 4; ++i) {
    float4 o4 = {acc[i][0], acc[i][1], acc[i][2], acc[i][3]};
    *(float4*)&Apart[(size_t)kc * 65536 + (pb + ty * 4 + i) * 256 + qb + tx * 4] = o4;
  }
}

__global__ void gram_reduce(const float* __restrict__ Apart,
                            float* __restrict__ A) {
  int idx = blockIdx.x * 256 + threadIdx.x;  // 65536
  float s = 0.f;
#pragma unroll
  for (int k = 0; k < 16; ++k) s += Apart[(size_t)k * 65536 + idx];
  A[idx] = s;
}

// ---------------- RAL attention softmax over patch axis ---------------------
__global__ __launch_bounds__(256) void attn_softmax(const float* __restrict__ A,
                                                    float* __restrict__ attn) {
  __shared__ float red[8];
  int q = blockIdx.x, t = threadIdx.x;
  float nrm = sqrtf(fmaxf(A[t * 256 + t], 0.f));
  float v = A[t * 256 + q] / fmaxf(nrm, 1e-4f) * 10.f;
  float mx = breduce_max(v, red);
  float e = expf(v - mx);
  float sm = breduce_sum(e, red);
  attn[t * 256 + q] = e / sm;
}

// ---------------- tconv as 16-batch GEMM ------------------------------------
__global__ __launch_bounds__(256) void tconv_gemm(const float* __restrict__ attn,
                                                  const float* __restrict__ rest,
                                                  float* __restrict__ T) {
  __shared__ float As[32][68];
  __shared__ float Bs[32][68];
  int tid = threadIdx.x;
  int cb = blockIdx.x * 64, qb = blockIdx.y * 64;
  int b = blockIdx.z;
  int ki = b >> 2, kj = b & 3;
  int tx = tid & 15, ty = tid >> 4;
  float acc[4][4] = {};
  for (int k0 = 0; k0 < 256; k0 += 32) {
    __syncthreads();
#pragma unroll
    for (int r = 0; r < 2; ++r) {
      int v = r * 256 + tid;
      int kk = v >> 4, e4 = (v & 15) * 4;
      int p = k0 + kk;
      *(float4*)&As[kk][e4] = *(const float4*)&attn[p * 256 + qb + e4];
      int ry = 2 * (p >> 4) + ki - 1;
      int rx = 2 * (p & 15) + kj - 1;
      float4 bv = {0.f, 0.f, 0.f, 0.f};
      if ((unsigned)ry < 32u && (unsigned)rx < 32u)
        bv = *(const float4*)&rest[(ry * 32 + rx) * 512 + cb + e4];
      *(float4*)&Bs[kk][e4] = bv;
    }
    __syncthreads();
#pragma unroll
    for (int k = 0; k < 32; ++k) {
      float4 a = *(const float4*)&As[k][ty * 4];
      float4 bb = *(const float4*)&Bs[k][tx * 4];
      float av[4] = {a.x, a.y, a.z, a.w};
      float bw[4] = {bb.x, bb.y, bb.z, bb.w};
#pragma unroll
      for (int i = 0; i < 4; ++i)
#pragma unroll
        for (int j = 0; j < 4; ++j) acc[i][j] += av[i] * bw[j];
    }
  }
#pragma unroll
  for (int i = 0; i < 4; ++i) {
    float4 o4 = {acc[i][0], acc[i][1], acc[i][2], acc[i][3]};
    *(float4*)&T[(b * 256 + qb + ty * 4 + i) * 512 + cb + tx * 4] = o4;
  }
}

// ---------------- combine taps -> orlt (pos-major) + sigt -------------------
__global__ void tcomb(const float* __restrict__ T, float* __restrict__ orlt,
                      float* __restrict__ sigt) {
  int f = blockIdx.x * 256 + threadIdx.x;  // 524288
  int n = f >> 9, c = f & 511;
  int y = n >> 5, x = n & 31;
  int i0 = (y + 1) >> 1, ki0 = (y + 1) & 1;
  int j0 = (x + 1) >> 1, kj0 = (x + 1) & 1;
  float sum = 0.f;
#pragma unroll
  for (int iy = 0; iy < 2; ++iy) {
    int i = i0 - iy, ki = ki0 + 2 * iy;
    if ((unsigned)i >= 16u) continue;
#pragma unroll
    for (int ix = 0; ix < 2; ++ix) {
      int j = j0 - ix, kj = kj0 + 2 * ix;
      if ((unsigned)j >= 16u) continue;
      sum += T[((ki * 4 + kj) * 256 + i * 16 + j) * 512 + c];
    }
  }
  float v = sum * 0.25f;
  orlt[f] = v;
  sigt[f] = 1.f / (1.f + expf(-v));
}

// ---------------- gus einsum: Mo[p,c] = sum_k gus[p,k] * orlt[k,c] ----------
__global__ __launch_bounds__(256) void gemm_gus(const float* __restrict__ G,
                                                const float* __restrict__ orlt,
                                                float* __restrict__ Mo) {
  __shared__ float As[32][68];
  __shared__ float Bs[32][68];
  int tid = threadIdx.x;
  int cb = blockIdx.x * 64, pb = blockIdx.y * 64;
  int tx = tid & 15, ty = tid >> 4;
  float acc[4][4] = {};
  for (int k0 = 0; k0 < 1024; k0 += 32) {
    __syncthreads();
#pragma unroll
    for (int r = 0; r < 2; ++r) {
      int v = r * 256 + tid;
      int mm = v >> 3, kq = (v & 7) * 4;
      float4 a = *(const float4*)&G[(pb + mm) * 1024 + k0 + kq];
      As[kq + 0][mm] = a.x; As[kq + 1][mm] = a.y;
      As[kq + 2][mm] = a.z; As[kq + 3][mm] = a.w;
      int kk = v >> 4, c4 = (v & 15) * 4;
      *(float4*)&Bs[kk][c4] = *(const float4*)&orlt[(k0 + kk) * 512 + cb + c4];
    }
    __syncthreads();
#pragma unroll
    for (int k = 0; k < 32; ++k) {
      float4 a = *(const float4*)&As[k][ty * 4];
      float4 bb = *(const float4*)&Bs[k][tx * 4];
      float av[4] = {a.x, a.y, a.z, a.w};
      float bw[4] = {bb.x, bb.y, bb.z, bb.w};
#pragma unroll
      for (int i = 0; i < 4; ++i)
#pragma unroll
        for (int j = 0; j < 4; ++j) acc[i][j] += av[i] * bw[j];
    }
  }
#pragma unroll
  for (int i = 0; i < 4; ++i) {
    float4 o4 = {acc[i][0], acc[i][1], acc[i][2], acc[i][3]};
    *(float4*)&Mo[(pb + ty * 4 + i) * 512 + cb + tx * 4] = o4;
  }
}

// ---------------- CSA fused: 9-tap correlation + softmax + gather -----------
__global__ __launch_bounds__(256) void csa_fused(const float* __restrict__ sigt,
                                                 const float* __restrict__ orlt,
                                                 float* __restrict__ outc) {
  __shared__ float red[8];
  __shared__ float a9s[9];
  int n = blockIdx.x, tid = threadIdx.x;
  int ny = n >> 5, nx = n & 31;
  float part[9];
#pragma unroll
  for (int t = 0; t < 9; ++t) part[t] = 0.f;
  for (int c = tid; c < 512; c += 256) {
    float ctr = sigt[n * 512 + c];
#pragma unroll
    for (int u = 0; u < 3; ++u) {
      int yy = ny + u - 1;
#pragma unroll
      for (int v = 0; v < 3; ++v) {
        int xx = nx + v - 1;
        float nb = ((unsigned)yy < 32u && (unsigned)xx < 32u)
                       ? sigt[(yy * 32 + xx) * 512 + c] : 0.f;
        part[u * 3 + v] += ctr * nb;
      }
    }
  }
  float a[9];
#pragma unroll
  for (int t = 0; t < 9; ++t) a[t] = breduce_sum(part[t], red) * (1.f / 512.f);
  float mx = a[0];
#pragma unroll
  for (int t = 1; t < 9; ++t) mx = fmaxf(mx, a[t]);
  float sum = 0.f;
#pragma unroll
  for (int t = 0; t < 9; ++t) { a[t] = expf(a[t] - mx); sum += a[t]; }
  if (tid == 0) {
    float inv = 1.f / sum;
#pragma unroll
    for (int t = 0; t < 9; ++t) a9s[t] = a[t] * inv;
  }
  __syncthreads();
  float w9[9];
#pragma unroll
  for (int t = 0; t < 9; ++t) w9[t] = a9s[t];
  for (int c = tid; c < 512; c += 256) {
    float acc = 0.f;
#pragma unroll
    for (int u = 0; u < 3; ++u) {
      int yy = ny + u - 1;
#pragma unroll
      for (int v = 0; v < 3; ++v) {
        int xx = nx + v - 1;
        if ((unsigned)yy < 32u && (unsigned)xx < 32u)
          acc += w9[u * 3 + v] * orlt[(yy * 32 + xx) * 512 + c];
      }
    }
    outc[n * 512 + c] = acc;
  }
}

// ---------------- 64x64-tile GEMM for the 1x1 convs -------------------------
__global__ __launch_bounds__(256) void gemm_nn(const float* __restrict__ w,
                                               const float* __restrict__ za,
                                               const float* __restrict__ zb,
                                               float* __restrict__ raw) {
  __shared__ float As[32][68];
  __shared__ float Bs[32][68];
  int tid = threadIdx.x;
  int pb = blockIdx.x * 64, ob = blockIdx.y * 64;
  int tx = tid & 15, ty = tid >> 4;
  float acc[4][4] = {};
  for (int k0 = 0; k0 < 1024; k0 += 32) {
    const float* Bsrc =
        (k0 < 512) ? za + (size_t)k0 * 1024 : zb + (size_t)(k0 - 512) * 1024;
    __syncthreads();
#pragma unroll
    for (int r = 0; r < 2; ++r) {
      int v = r * 256 + tid;
      int mm = v >> 3, kq = (v & 7) * 4;
      float4 a = *(const float4*)&w[(ob + mm) * 1024 + k0 + kq];
      As[kq + 0][mm] = a.x; As[kq + 1][mm] = a.y;
      As[kq + 2][mm] = a.z; As[kq + 3][mm] = a.w;
      int kk = v >> 4, pq = (v & 15) * 4;
      *(float4*)&Bs[kk][pq] = *(const float4*)&Bsrc[kk * 1024 + pb + pq];
    }
    __syncthreads();
#pragma unroll
    for (int k = 0; k < 32; ++k) {
      float4 a = *(const float4*)&As[k][ty * 4];
      float4 bb = *(const float4*)&Bs[k][tx * 4];
      float av[4] = {a.x, a.y, a.z, a.w};
      float bw[4] = {bb.x, bb.y, bb.z, bb.w};
#pragma unroll
      for (int i = 0; i < 4; ++i)
#pragma unroll
        for (int j = 0; j < 4; ++j) acc[i][j] += av[i] * bw[j];
    }
  }
#pragma unroll
  for (int i = 0; i < 4; ++i) {
    float4 o4 = {acc[i][0], acc[i][1], acc[i][2], acc[i][3]};
    *(float4*)&raw[(ob + ty * 4 + i) * 1024 + pb + tx * 4] = o4;
  }
}

// ---------------- per-channel InstanceNorm + LeakyReLU(0.2) -----------------
__global__ __launch_bounds__(256) void norm_leaky(const float* __restrict__ raw,
                                                  float* __restrict__ out) {
  __shared__ float red[8];
  int c = blockIdx.x, tid = threadIdx.x;
  float v[4];
  float s = 0.f, ss = 0.f;
#pragma unroll
  for (int r = 0; r < 4; ++r) {
    v[r] = raw[c * 1024 + tid + r * 256];
    s += v[r];
    ss += v[r] * v[r];
  }
  breduce2(s, ss, red);
  float mean = s * (1.f / 1024.f);
  float var = ss * (1.f / 1024.f) - mean * mean;
  float inv = rsqrtf(var + EPSN);
#pragma unroll
  for (int r = 0; r < 4; ++r) {
    float t = (v[r] - mean) * inv;
    out[c * 1024 + tid + r * 256] = t >= 0.f ? t : 0.2f * t;
  }
}

// ---------------- host launch ------------------------------------------------
extern "C" void kernel_launch(void* const* d_in, const int* in_sizes, int n_in,
                              void* d_out, int out_size, void* d_ws, size_t ws_size,
                              hipStream_t stream) {
  const float* x = (const float*)d_in[0];
  const float* gus = (const float*)d_in[1];
  const float* w3 = (const float*)d_in[2];
  const float* b3 = (const float*)d_in[3];
  const float* w5 = (const float*)d_in[4];
  const float* b5 = (const float*)d_in[5];
  const float* w7 = (const float*)d_in[6];
  const float* b7 = (const float*)d_in[7];
  const float* wfc = (const float*)d_in[8];
  const float* bfc = (const float*)d_in[9];
  const float* w0 = (const float*)d_in[10];
  const float* b0 = (const float*)d_in[11];
  const float* w1 = (const float*)d_in[12];
  const float* b1 = (const float*)d_in[13];
  const float* w2 = (const float*)d_in[14];
  const float* b2 = (const float*)d_in[15];
  const float* wdown = (const float*)d_in[16];
  const float* wfuse = (const float*)d_in[17];

  float* ws = (float*)d_ws;
  float* feas = ws;                   // 1572864 (dead after blend_t; reused as raw)
  float* bmean = feas + 1572864;      // 1536
  float* att = bmean + 1536;          // 1536
  float* res = att + 1536;            // 524288
  float* rest = res + 524288;         // 524288 (pos-major res)
  float* fgs = rest + 524288;         // 131072
  float* A = fgs + 131072;            // 65536
  float* attn = A + 65536;            // 65536
  float* T = attn + 65536;            // 2097152 (16x256x512)
  float* orlt = T + 2097152;          // 524288
  float* sigt = orlt + 524288;        // 524288
  float* gusout = sigt + 524288;      // 524288
  float* outcsa = gusout + 524288;    // 524288
  float* zdown = outcsa + 524288;     // 524288
  float* raw = feas;                  // reuse (feas dead after blend_t)
  float* Apart = T;                   // reuse (T written later by tconv_gemm)

  sk_all<<<512, 256, 0, stream>>>(x, w3, b3, w5, b5, w7, b7, feas, bmean);
  fc_att<<<1, 256, 0, stream>>>(bmean, wfc, bfc, w0, b0, w1, b1, w2, b2, att);
  blend_t<<<dim3(32, 16), 256, 0, stream>>>(feas, att, res, rest);
  pool2<<<512, 256, 0, stream>>>(res, fgs);
  gram_part<<<dim3(4, 4, 16), 256, 0, stream>>>(fgs, Apart);
  gram_reduce<<<256, 256, 0, stream>>>(Apart, A);
  attn_softmax<<<256, 256, 0, stream>>>(A, attn);
  tconv_gemm<<<dim3(8, 4, 16), 256, 0, stream>>>(attn, rest, T);
  tcomb<<<2048, 256, 0, stream>>>(T, orlt, sigt);
  gemm_gus<<<dim3(8, 16), 256, 0, stream>>>(gus, orlt, gusout);
  csa_fused<<<1024, 256, 0, stream>>>(sigt, orlt, outcsa);
  gemm_nn<<<dim3(16, 8), 256, 0, stream>>>(wdown, gusout, outcsa, raw);
  norm_leaky<<<512, 256, 0, stream>>>(raw, zdown);
  gemm_nn<<<dim3(16, 8), 256, 0, stream>>>(wfuse, zdown, res, raw);
  norm_leaky<<<512, 256, 0, stream>>>(raw, (float*)d_out);
}

// Round 5
// 293.098 us; speedup vs baseline: 3.1513x; 1.2356x over previous
//
#include <hip/hip_runtime.h>
#include <math.h>

#define EPSN 1e-5f

typedef __attribute__((ext_vector_type(8))) short bf16x8;
typedef __attribute__((ext_vector_type(4))) float f32x4;

__device__ __forceinline__ ushort f2bf(float f) {
  unsigned u = __float_as_uint(f);
  unsigned r = (u + 0x7fff + ((u >> 16) & 1)) >> 16;
  return (ushort)r;
}

// ---------------- block-wide reductions (blockDim.x == 256, 4 waves) --------
__device__ __forceinline__ void breduce2(float& a, float& b, float* lds) {
#pragma unroll
  for (int o = 32; o > 0; o >>= 1) {
    a += __shfl_down(a, o);
    b += __shfl_down(b, o);
  }
  int lane = threadIdx.x & 63, wid = threadIdx.x >> 6;
  __syncthreads();
  if (lane == 0) { lds[wid] = a; lds[4 + wid] = b; }
  __syncthreads();
  a = lds[0] + lds[1] + lds[2] + lds[3];
  b = lds[4] + lds[5] + lds[6] + lds[7];
}

__device__ __forceinline__ float breduce_sum(float v, float* lds) {
#pragma unroll
  for (int o = 32; o > 0; o >>= 1) v += __shfl_down(v, o);
  int lane = threadIdx.x & 63, wid = threadIdx.x >> 6;
  __syncthreads();
  if (lane == 0) lds[wid] = v;
  __syncthreads();
  return lds[0] + lds[1] + lds[2] + lds[3];
}

__device__ __forceinline__ float breduce_max(float v, float* lds) {
#pragma unroll
  for (int o = 32; o > 0; o >>= 1) v = fmaxf(v, __shfl_down(v, o));
  int lane = threadIdx.x & 63, wid = threadIdx.x >> 6;
  __syncthreads();
  if (lane == 0) lds[wid] = v;
  __syncthreads();
  return fmaxf(fmaxf(lds[0], lds[1]), fmaxf(lds[2], lds[3]));
}

// ---------------- fused SKConv: all 3 branches in one pass ------------------
__device__ __forceinline__ void finish_branch(float* acc, float bv, int m, int c,
                                              int y, int xb, float* feas,
                                              float* bmean, float* red) {
  float s = 0.f, ss = 0.f;
#pragma unroll
  for (int r = 0; r < 4; ++r) {
    acc[r] += bv;
    s += acc[r];
    ss += acc[r] * acc[r];
  }
  breduce2(s, ss, red);
  float mean = s * (1.f / 1024.f);
  float var = ss * (1.f / 1024.f) - mean * mean;
  float inv = rsqrtf(var + EPSN);
  float4 o;
  float* ov = (float*)&o;
  float rs = 0.f;
#pragma unroll
  for (int r = 0; r < 4; ++r) {
    float v = (acc[r] - mean) * inv;
    v = v > 0.f ? v : 0.f;
    ov[r] = v;
    rs += v;
  }
  *(float4*)&feas[(m * 512 + c) * 1024 + y * 32 + xb] = o;
  float tot = breduce_sum(rs, red);
  if (threadIdx.x == 0) bmean[m * 512 + c] = tot * (1.f / 1024.f);
}

__global__ __launch_bounds__(256) void sk_all(
    const float* __restrict__ x, const float* __restrict__ w3,
    const float* __restrict__ b3, const float* __restrict__ w5,
    const float* __restrict__ b5, const float* __restrict__ w7,
    const float* __restrict__ b7, float* __restrict__ feas,
    float* __restrict__ bmean) {
  __shared__ float chanp[38 * 38];
  __shared__ float ws7[784];
  __shared__ float ws5[400];
  __shared__ float ws3[144];
  __shared__ float red[8];
  int c = blockIdx.x, tid = threadIdx.x, g = c >> 4;
  for (int i = tid; i < 1444; i += 256) chanp[i] = 0.f;
  for (int i = tid; i < 784; i += 256) ws7[i] = w7[c * 784 + i];
  for (int i = tid; i < 400; i += 256) ws5[i] = w5[c * 400 + i];
  for (int i = tid; i < 144; i += 256) ws3[i] = w3[c * 144 + i];
  int y = tid >> 3, xb = (tid & 7) * 4;
  float a3[4] = {}, a5[4] = {}, a7[4] = {};
  for (int ic = 0; ic < 16; ++ic) {
    __syncthreads();
    for (int i = tid; i < 1024; i += 256)
      chanp[((i >> 5) + 3) * 38 + (i & 31) + 3] = x[(g * 16 + ic) * 1024 + i];
    __syncthreads();
    const float* W7 = ws7 + ic * 49;
    const float* W5 = ws5 + ic * 25;
    const float* W3 = ws3 + ic * 9;
#pragma unroll
    for (int dy = 0; dy < 7; ++dy) {
      float seg[10];
      const float* row = &chanp[(y + dy) * 38 + xb];
#pragma unroll
      for (int t = 0; t < 10; ++t) seg[t] = row[t];
#pragma unroll
      for (int kx = 0; kx < 7; ++kx) {
        float wv = W7[dy * 7 + kx];
#pragma unroll
        for (int px = 0; px < 4; ++px) a7[px] += seg[px + kx] * wv;
      }
      if (dy >= 1 && dy <= 5) {
#pragma unroll
        for (int kx = 0; kx < 5; ++kx) {
          float wv = W5[(dy - 1) * 5 + kx];
#pragma unroll
          for (int px = 0; px < 4; ++px) a5[px] += seg[px + kx + 1] * wv;
        }
      }
      if (dy >= 2 && dy <= 4) {
#pragma unroll
        for (int kx = 0; kx < 3; ++kx) {
          float wv = W3[(dy - 2) * 3 + kx];
#pragma unroll
          for (int px = 0; px < 4; ++px) a3[px] += seg[px + kx + 2] * wv;
        }
      }
    }
  }
  finish_branch(a3, b3[c], 0, c, y, xb, feas, bmean, red);
  finish_branch(a5, b5[c], 1, c, y, xb, feas, bmean, red);
  finish_branch(a7, b7[c], 2, c, y, xb, feas, bmean, red);
}

// ---------------- FC chain + branch softmax (one block) ---------------------
__global__ __launch_bounds__(256) void fc_att(
    const float* __restrict__ bmean, const float* __restrict__ w_fc,
    const float* __restrict__ b_fc, const float* __restrict__ w0,
    const float* __restrict__ b0, const float* __restrict__ w1,
    const float* __restrict__ b1, const float* __restrict__ w2,
    const float* __restrict__ b2, float* __restrict__ att) {
  __shared__ float sfea[512];
  __shared__ float zz[32];
  int tid = threadIdx.x;
  for (int c = tid; c < 512; c += 256)
    sfea[c] = bmean[c] + bmean[512 + c] + bmean[1024 + c];
  __syncthreads();
  if (tid < 32) {
    float d = b_fc[tid];
    for (int c = 0; c < 512; ++c) d += sfea[c] * w_fc[tid * 512 + c];
    zz[tid] = d;
  }
  __syncthreads();
  for (int c = tid; c < 512; c += 256) {
    float l0 = b0[c], l1 = b1[c], l2 = b2[c];
#pragma unroll
    for (int j = 0; j < 32; ++j) {
      float z = zz[j];
      l0 += z * w0[c * 32 + j];
      l1 += z * w1[c * 32 + j];
      l2 += z * w2[c * 32 + j];
    }
    float mx = fmaxf(l0, fmaxf(l1, l2));
    float e0 = expf(l0 - mx), e1 = expf(l1 - mx), e2 = expf(l2 - mx);
    float inv = 1.f / (e0 + e1 + e2);
    att[c] = e0 * inv;
    att[512 + c] = e1 * inv;
    att[1024 + c] = e2 * inv;
  }
}

// ---------------- attention blend -> res (ch-major) + rest (pos-major) ------
__global__ __launch_bounds__(256) void blend_t(const float* __restrict__ feas,
                                               const float* __restrict__ att,
                                               float* __restrict__ res,
                                               float* __restrict__ rest) {
  __shared__ float t[32][33];
  int pb = blockIdx.x * 32, cb = blockIdx.y * 32;
  int tx = threadIdx.x & 31, ty = threadIdx.x >> 5;
#pragma unroll
  for (int r = 0; r < 4; ++r) {
    int cl = ty + r * 8;
    int c = cb + cl, pos = pb + tx;
    float v = feas[c * 1024 + pos] * att[c] +
              feas[(512 + c) * 1024 + pos] * att[512 + c] +
              feas[(1024 + c) * 1024 + pos] * att[1024 + c];
    res[c * 1024 + pos] = v;
    t[cl][tx] = v;
  }
  __syncthreads();
#pragma unroll
  for (int r = 0; r < 4; ++r) {
    int pl = ty + r * 8;
    rest[(pb + pl) * 512 + cb + tx] = t[tx][pl];
  }
}

// ---------------- 2x2 average pool -> fg_small (512,16,16) ------------------
__global__ void pool2(const float* __restrict__ res, float* __restrict__ fgs) {
  int idx = blockIdx.x * 256 + threadIdx.x;
  int c = idx >> 8;
  int rem = idx & 255;
  int i = rem >> 4, j = rem & 15;
  const float* base = res + c * 1024 + (2 * i) * 32 + 2 * j;
  fgs[idx] = 0.25f * (base[0] + base[1] + base[32] + base[33]);
}

// ---------------- Gram split-K partials -------------------------------------
__global__ __launch_bounds__(256) void gram_part(const float* __restrict__ fgs,
                                                 float* __restrict__ Apart) {
  __shared__ float ch[4][324];
  int tid = threadIdx.x;
  int qb = blockIdx.x * 64, pb = blockIdx.y * 64;
  int kc = blockIdx.z;
  int tx = tid & 15, ty = tid >> 4;
  for (int i = tid; i < 4 * 324; i += 256) ((float*)ch)[i] = 0.f;
  int pi = (pb + ty * 4) >> 4, pj = (pb + ty * 4) & 15;
  int qi = (qb + tx * 4) >> 4, qj = (qb + tx * 4) & 15;
  int lane = tid & 63, wv = tid >> 6;
  int sr = lane >> 2, sc = (lane & 3) * 4;
  float acc[4][4] = {};
  for (int c0 = kc * 32; c0 < kc * 32 + 32; c0 += 4) {
    __syncthreads();
    {
      float4 v = *(const float4*)&fgs[(c0 + wv) * 256 + lane * 4];
      float* dst = &ch[wv][(sr + 1) * 18 + sc + 1];
      dst[0] = v.x; dst[1] = v.y; dst[2] = v.z; dst[3] = v.w;
    }
    __syncthreads();
#pragma unroll
    for (int cc = 0; cc < 4; ++cc) {
      float ps[3][6], qs[3][6];
#pragma unroll
      for (int u = 0; u < 3; ++u) {
        const float* pr = &ch[cc][(pi + u) * 18 + pj];
        const float* qr = &ch[cc][(qi + u) * 18 + qj];
#pragma unroll
        for (int t = 0; t < 6; ++t) { ps[u][t] = pr[t]; qs[u][t] = qr[t]; }
      }
#pragma unroll
      for (int u = 0; u < 3; ++u)
#pragma unroll
        for (int v = 0; v < 3; ++v)
#pragma unroll
          for (int i = 0; i < 4; ++i)
#pragma unroll
            for (int j = 0; j < 4; ++j)
              acc[i][j] += ps[u][v + i] * qs[u][v + j];
    }
  }
#pragma unroll
  for (int i = 0; i < 4; ++i) {
    float4 o4 = {acc[i][0], acc[i][1], acc[i][2], acc[i][3]};
    *(float4*)&Apart[(size_t)kc * 65536 + (pb + ty * 4 + i) * 256 + qb + tx * 4] = o4;
  }
}

__global__ void gram_reduce(const float* __restrict__ Apart,
                            float* __restrict__ A) {
  int idx = blockIdx.x * 256 + threadIdx.x;
  float s = 0.f;
#pragma unroll
  for (int k = 0; k < 16; ++k) s += Apart[(size_t)k * 65536 + idx];
  A[idx] = s;
}

// ---------------- RAL attention softmax over patch axis ---------------------
__global__ __launch_bounds__(256) void attn_softmax(const float* __restrict__ A,
                                                    float* __restrict__ attn) {
  __shared__ float red[8];
  int q = blockIdx.x, t = threadIdx.x;
  float nrm = sqrtf(fmaxf(A[t * 256 + t], 0.f));
  float v = A[t * 256 + q] / fmaxf(nrm, 1e-4f) * 10.f;
  float mx = breduce_max(v, red);
  float e = expf(v - mx);
  float sm = breduce_sum(e, red);
  attn[t * 256 + q] = e / sm;
}

// ---------------- tconv as 16-batch GEMM (fp32) -----------------------------
__global__ __launch_bounds__(256) void tconv_gemm(const float* __restrict__ attn,
                                                  const float* __restrict__ rest,
                                                  float* __restrict__ T) {
  __shared__ float As[32][68];
  __shared__ float Bs[32][68];
  int tid = threadIdx.x;
  int cb = blockIdx.x * 64, qb = blockIdx.y * 64;
  int b = blockIdx.z;
  int ki = b >> 2, kj = b & 3;
  int tx = tid & 15, ty = tid >> 4;
  float acc[4][4] = {};
  for (int k0 = 0; k0 < 256; k0 += 32) {
    __syncthreads();
#pragma unroll
    for (int r = 0; r < 2; ++r) {
      int v = r * 256 + tid;
      int kk = v >> 4, e4 = (v & 15) * 4;
      int p = k0 + kk;
      *(float4*)&As[kk][e4] = *(const float4*)&attn[p * 256 + qb + e4];
      int ry = 2 * (p >> 4) + ki - 1;
      int rx = 2 * (p & 15) + kj - 1;
      float4 bv = {0.f, 0.f, 0.f, 0.f};
      if ((unsigned)ry < 32u && (unsigned)rx < 32u)
        bv = *(const float4*)&rest[(ry * 32 + rx) * 512 + cb + e4];
      *(float4*)&Bs[kk][e4] = bv;
    }
    __syncthreads();
#pragma unroll
    for (int k = 0; k < 32; ++k) {
      float4 a = *(const float4*)&As[k][ty * 4];
      float4 bb = *(const float4*)&Bs[k][tx * 4];
      float av[4] = {a.x, a.y, a.z, a.w};
      float bw[4] = {bb.x, bb.y, bb.z, bb.w};
#pragma unroll
      for (int i = 0; i < 4; ++i)
#pragma unroll
        for (int j = 0; j < 4; ++j) acc[i][j] += av[i] * bw[j];
    }
  }
#pragma unroll
  for (int i = 0; i < 4; ++i) {
    float4 o4 = {acc[i][0], acc[i][1], acc[i][2], acc[i][3]};
    *(float4*)&T[(b * 256 + qb + ty * 4 + i) * 512 + cb + tx * 4] = o4;
  }
}

// ---------------- combine taps -> orlt (pos-major) + sigt -------------------
__global__ void tcomb(const float* __restrict__ T, float* __restrict__ orlt,
                      float* __restrict__ sigt) {
  int f = blockIdx.x * 256 + threadIdx.x;
  int n = f >> 9, c = f & 511;
  int y = n >> 5, x = n & 31;
  int i0 = (y + 1) >> 1, ki0 = (y + 1) & 1;
  int j0 = (x + 1) >> 1, kj0 = (x + 1) & 1;
  float sum = 0.f;
#pragma unroll
  for (int iy = 0; iy < 2; ++iy) {
    int i = i0 - iy, ki = ki0 + 2 * iy;
    if ((unsigned)i >= 16u) continue;
#pragma unroll
    for (int ix = 0; ix < 2; ++ix) {
      int j = j0 - ix, kj = kj0 + 2 * ix;
      if ((unsigned)j >= 16u) continue;
      sum += T[((ki * 4 + kj) * 256 + i * 16 + j) * 512 + c];
    }
  }
  float v = sum * 0.25f;
  orlt[f] = v;
  sigt[f] = 1.f / (1.f + expf(-v));
}

// ---------------- fp32 -> bf16 elementwise (4/thread) -----------------------
__global__ void conv_bf(const float* __restrict__ in, ushort* __restrict__ out) {
  int i = (blockIdx.x * 256 + threadIdx.x) * 4;
  float4 v = *(const float4*)&in[i];
  ushort4 o = {f2bf(v.x), f2bf(v.y), f2bf(v.z), f2bf(v.w)};
  *(ushort4*)&out[i] = o;
}

// ---------------- transpose-pack: ch-major fp32 x2 -> pos-major bf16 --------
// za/zb: [512][1024] fp32 each (concat along channel); zt: [1024 p][1024 k] bf16
__global__ __launch_bounds__(256) void pack_zt(const float* __restrict__ za,
                                               const float* __restrict__ zb,
                                               ushort* __restrict__ zt) {
  __shared__ float t[32][33];
  int kb = blockIdx.x * 32, pb = blockIdx.y * 32;
  const float* src = (kb < 512) ? za + (size_t)kb * 1024
                                : zb + (size_t)(kb - 512) * 1024;
  int tx = threadIdx.x & 31, ty = threadIdx.x >> 5;
#pragma unroll
  for (int r = 0; r < 4; ++r) {
    int k = ty + r * 8;
    t[k][tx] = src[k * 1024 + pb + tx];
  }
  __syncthreads();
#pragma unroll
  for (int r = 0; r < 4; ++r) {
    int p = ty + r * 8;
    zt[(size_t)(pb + p) * 1024 + kb + tx] = f2bf(t[tx][p]);
  }
}

// ---------------- transpose-pack: orlt [1024 p][512 c] -> orlT [512 c][1024 p]
__global__ __launch_bounds__(256) void pack_orlT(const float* __restrict__ orlt,
                                                 ushort* __restrict__ out) {
  __shared__ float t[32][33];
  int cb = blockIdx.x * 32, pb = blockIdx.y * 32;
  int tx = threadIdx.x & 31, ty = threadIdx.x >> 5;
#pragma unroll
  for (int r = 0; r < 4; ++r) {
    int p = ty + r * 8;
    t[p][tx] = orlt[(size_t)(pb + p) * 512 + cb + tx];
  }
  __syncthreads();
#pragma unroll
  for (int r = 0; r < 4; ++r) {
    int c = ty + r * 8;
    out[(size_t)(cb + c) * 1024 + pb + tx] = f2bf(t[tx][c]);
  }
}

// ---------------- bf16 MFMA GEMM: C[M][N] = A[M][K] * Bt[N][K]^T ------------
// block 256 = 4 waves; tile 64(M) x 64(N); wave w -> M rows [mb+16w, +16).
// No LDS, no barriers: fragments load straight from global (L2-resident).
__global__ __launch_bounds__(256) void mfma_gemm(const ushort* __restrict__ A,
                                                 const ushort* __restrict__ Bt,
                                                 float* __restrict__ C, int M,
                                                 int N, int K) {
  int tid = threadIdx.x;
  int wv = tid >> 6, lane = tid & 63;
  int quad = lane >> 4, m16 = lane & 15;
  int nb = blockIdx.x * 64, mb = blockIdx.y * 64;
  const ushort* Ap = A + (size_t)(mb + wv * 16 + m16) * K + quad * 8;
  const ushort* Bp = Bt + (size_t)(nb + m16) * K + quad * 8;
  f32x4 ac0 = {0.f, 0.f, 0.f, 0.f}, ac1 = ac0, ac2 = ac0, ac3 = ac0;
#pragma unroll 2
  for (int k0 = 0; k0 < K; k0 += 32) {
    bf16x8 af = *(const bf16x8*)(Ap + k0);
    bf16x8 b0 = *(const bf16x8*)(Bp + k0);
    bf16x8 b1 = *(const bf16x8*)(Bp + (size_t)16 * K + k0);
    bf16x8 b2 = *(const bf16x8*)(Bp + (size_t)32 * K + k0);
    bf16x8 b3 = *(const bf16x8*)(Bp + (size_t)48 * K + k0);
    ac0 = __builtin_amdgcn_mfma_f32_16x16x32_bf16(af, b0, ac0, 0, 0, 0);
    ac1 = __builtin_amdgcn_mfma_f32_16x16x32_bf16(af, b1, ac1, 0, 0, 0);
    ac2 = __builtin_amdgcn_mfma_f32_16x16x32_bf16(af, b2, ac2, 0, 0, 0);
    ac3 = __builtin_amdgcn_mfma_f32_16x16x32_bf16(af, b3, ac3, 0, 0, 0);
  }
  int row = mb + wv * 16 + quad * 4;
  f32x4 accs[4] = {ac0, ac1, ac2, ac3};
#pragma unroll
  for (int nt = 0; nt < 4; ++nt)
#pragma unroll
    for (int r = 0; r < 4; ++r)
      C[(size_t)(row + r) * N + nb + nt * 16 + m16] = accs[nt][r];
}

// ---------------- CSA fused: 9-tap correlation + softmax + gather -----------
__global__ __launch_bounds__(256) void csa_fused(const float* __restrict__ sigt,
                                                 const float* __restrict__ orlt,
                                                 float* __restrict__ outc) {
  __shared__ float red[8];
  __shared__ float a9s[9];
  int n = blockIdx.x, tid = threadIdx.x;
  int ny = n >> 5, nx = n & 31;
  float part[9];
#pragma unroll
  for (int t = 0; t < 9; ++t) part[t] = 0.f;
  for (int c = tid; c < 512; c += 256) {
    float ctr = sigt[n * 512 + c];
#pragma unroll
    for (int u = 0; u < 3; ++u) {
      int yy = ny + u - 1;
#pragma unroll
      for (int v = 0; v < 3; ++v) {
        int xx = nx + v - 1;
        float nb = ((unsigned)yy < 32u && (unsigned)xx < 32u)
                       ? sigt[(yy * 32 + xx) * 512 + c] : 0.f;
        part[u * 3 + v] += ctr * nb;
      }
    }
  }
  float a[9];
#pragma unroll
  for (int t = 0; t < 9; ++t) a[t] = breduce_sum(part[t], red) * (1.f / 512.f);
  float mx = a[0];
#pragma unroll
  for (int t = 1; t < 9; ++t) mx = fmaxf(mx, a[t]);
  float sum = 0.f;
#pragma unroll
  for (int t = 0; t < 9; ++t) { a[t] = expf(a[t] - mx); sum += a[t]; }
  if (tid == 0) {
    float inv = 1.f / sum;
#pragma unroll
    for (int t = 0; t < 9; ++t) a9s[t] = a[t] * inv;
  }
  __syncthreads();
  float w9[9];
#pragma unroll
  for (int t = 0; t < 9; ++t) w9[t] = a9s[t];
  for (int c = tid; c < 512; c += 256) {
    float acc = 0.f;
#pragma unroll
    for (int u = 0; u < 3; ++u) {
      int yy = ny + u - 1;
#pragma unroll
      for (int v = 0; v < 3; ++v) {
        int xx = nx + v - 1;
        if ((unsigned)yy < 32u && (unsigned)xx < 32u)
          acc += w9[u * 3 + v] * orlt[(yy * 32 + xx) * 512 + c];
      }
    }
    outc[n * 512 + c] = acc;
  }
}

// ---------------- per-channel InstanceNorm + LeakyReLU(0.2) -----------------
__global__ __launch_bounds__(256) void norm_leaky(const float* __restrict__ raw,
                                                  float* __restrict__ out) {
  __shared__ float red[8];
  int c = blockIdx.x, tid = threadIdx.x;
  float v[4];
  float s = 0.f, ss = 0.f;
#pragma unroll
  for (int r = 0; r < 4; ++r) {
    v[r] = raw[c * 1024 + tid + r * 256];
    s += v[r];
    ss += v[r] * v[r];
  }
  breduce2(s, ss, red);
  float mean = s * (1.f / 1024.f);
  float var = ss * (1.f / 1024.f) - mean * mean;
  float inv = rsqrtf(var + EPSN);
#pragma unroll
  for (int r = 0; r < 4; ++r) {
    float t = (v[r] - mean) * inv;
    out[c * 1024 + tid + r * 256] = t >= 0.f ? t : 0.2f * t;
  }
}

// ---------------- host launch ------------------------------------------------
extern "C" void kernel_launch(void* const* d_in, const int* in_sizes, int n_in,
                              void* d_out, int out_size, void* d_ws, size_t ws_size,
                              hipStream_t stream) {
  const float* x = (const float*)d_in[0];
  const float* gus = (const float*)d_in[1];
  const float* w3 = (const float*)d_in[2];
  const float* b3 = (const float*)d_in[3];
  const float* w5 = (const float*)d_in[4];
  const float* b5 = (const float*)d_in[5];
  const float* w7 = (const float*)d_in[6];
  const float* b7 = (const float*)d_in[7];
  const float* wfc = (const float*)d_in[8];
  const float* bfc = (const float*)d_in[9];
  const float* w0 = (const float*)d_in[10];
  const float* b0 = (const float*)d_in[11];
  const float* w1 = (const float*)d_in[12];
  const float* b1 = (const float*)d_in[13];
  const float* w2 = (const float*)d_in[14];
  const float* b2 = (const float*)d_in[15];
  const float* wdown = (const float*)d_in[16];
  const float* wfuse = (const float*)d_in[17];

  float* ws = (float*)d_ws;
  float* feas = ws;                   // 1572864 (dead after blend_t; reused as raw)
  float* bmean = feas + 1572864;      // 1536
  float* att = bmean + 1536;          // 1536
  float* res = att + 1536;            // 524288
  float* rest = res + 524288;         // 524288 (pos-major res)
  float* fgs = rest + 524288;         // 131072
  float* A = fgs + 131072;            // 65536
  float* attn = A + 65536;            // 65536
  float* T = attn + 65536;            // 2097152 (16x256x512); bf16 bufs after tcomb
  float* orlt = T + 2097152;          // 524288
  float* sigt = orlt + 524288;        // 524288
  float* gusout = sigt + 524288;      // 524288
  float* outcsa = gusout + 524288;    // 524288
  float* zdown = outcsa + 524288;     // 524288
  float* raw = feas;                  // reuse (feas dead after blend_t)
  float* Apart = T;                   // reuse (T written later by tconv_gemm)
  // bf16 buffers overlaid on T (T dead after tcomb):
  ushort* gus_bf = (ushort*)T;                  // 1048576 ush
  ushort* orlT = (ushort*)(T + 524288);         // 524288 ush
  ushort* wdown_bf = (ushort*)(T + 786432);     // 524288 ush
  ushort* wfuse_bf = (ushort*)(T + 1048576);    // 524288 ush
  ushort* Zt = (ushort*)(T + 1310720);          // 1048576 ush (ends at 1835008 fl)

  sk_all<<<512, 256, 0, stream>>>(x, w3, b3, w5, b5, w7, b7, feas, bmean);
  fc_att<<<1, 256, 0, stream>>>(bmean, wfc, bfc, w0, b0, w1, b1, w2, b2, att);
  blend_t<<<dim3(32, 16), 256, 0, stream>>>(feas, att, res, rest);
  pool2<<<512, 256, 0, stream>>>(res, fgs);
  gram_part<<<dim3(4, 4, 16), 256, 0, stream>>>(fgs, Apart);
  gram_reduce<<<256, 256, 0, stream>>>(Apart, A);
  attn_softmax<<<256, 256, 0, stream>>>(A, attn);
  tconv_gemm<<<dim3(8, 4, 16), 256, 0, stream>>>(attn, rest, T);
  tcomb<<<2048, 256, 0, stream>>>(T, orlt, sigt);
  // ---- bf16 conversions (T region now dead) ----
  conv_bf<<<1024, 256, 0, stream>>>(gus, gus_bf);
  conv_bf<<<512, 256, 0, stream>>>(wdown, wdown_bf);
  conv_bf<<<512, 256, 0, stream>>>(wfuse, wfuse_bf);
  pack_orlT<<<dim3(16, 32), 256, 0, stream>>>(orlt, orlT);
  // gus einsum: M=1024(p), N=512(c), K=1024(pos)
  mfma_gemm<<<dim3(8, 16), 256, 0, stream>>>(gus_bf, orlT, gusout, 1024, 512, 1024);
  csa_fused<<<1024, 256, 0, stream>>>(sigt, orlt, outcsa);
  // down conv: M=512(o), N=1024(p), K=1024
  pack_zt<<<dim3(32, 32), 256, 0, stream>>>(gusout, outcsa, Zt);
  mfma_gemm<<<dim3(16, 8), 256, 0, stream>>>(wdown_bf, Zt, raw, 512, 1024, 1024);
  norm_leaky<<<512, 256, 0, stream>>>(raw, zdown);
  // fuse conv
  pack_zt<<<dim3(32, 32), 256, 0, stream>>>(zdown, res, Zt);
  mfma_gemm<<<dim3(16, 8), 256, 0, stream>>>(wfuse_bf, Zt, raw, 512, 1024, 1024);
  norm_leaky<<<512, 256, 0, stream>>>(raw, (float*)d_out);
}

// Round 6
// 291.985 us; speedup vs baseline: 3.1633x; 1.0038x over previous
//
#include <hip/hip_runtime.h>
#include <math.h>

#define EPSN 1e-5f

typedef __attribute__((ext_vector_type(8))) short bf16x8;
typedef __attribute__((ext_vector_type(4))) float f32x4;

__device__ __forceinline__ ushort f2bf(float f) {
  unsigned u = __float_as_uint(f);
  unsigned r = (u + 0x7fff + ((u >> 16) & 1)) >> 16;
  return (ushort)r;
}

// ---------------- block-wide reductions (blockDim.x == 256, 4 waves) --------
__device__ __forceinline__ void breduce2(float& a, float& b, float* lds) {
#pragma unroll
  for (int o = 32; o > 0; o >>= 1) {
    a += __shfl_down(a, o);
    b += __shfl_down(b, o);
  }
  int lane = threadIdx.x & 63, wid = threadIdx.x >> 6;
  __syncthreads();
  if (lane == 0) { lds[wid] = a; lds[4 + wid] = b; }
  __syncthreads();
  a = lds[0] + lds[1] + lds[2] + lds[3];
  b = lds[4] + lds[5] + lds[6] + lds[7];
}

__device__ __forceinline__ float breduce_sum(float v, float* lds) {
#pragma unroll
  for (int o = 32; o > 0; o >>= 1) v += __shfl_down(v, o);
  int lane = threadIdx.x & 63, wid = threadIdx.x >> 6;
  __syncthreads();
  if (lane == 0) lds[wid] = v;
  __syncthreads();
  return lds[0] + lds[1] + lds[2] + lds[3];
}

__device__ __forceinline__ float breduce_max(float v, float* lds) {
#pragma unroll
  for (int o = 32; o > 0; o >>= 1) v = fmaxf(v, __shfl_down(v, o));
  int lane = threadIdx.x & 63, wid = threadIdx.x >> 6;
  __syncthreads();
  if (lane == 0) lds[wid] = v;
  __syncthreads();
  return fmaxf(fmaxf(lds[0], lds[1]), fmaxf(lds[2], lds[3]));
}

// ---------------- fused SKConv: all 3 branches, vectorized LDS --------------
__device__ __forceinline__ void finish_branch(float* acc, float bv, int m, int c,
                                              int y, int xb, float* feas,
                                              float* bmean, float* red) {
  float s = 0.f, ss = 0.f;
#pragma unroll
  for (int r = 0; r < 4; ++r) {
    acc[r] += bv;
    s += acc[r];
    ss += acc[r] * acc[r];
  }
  breduce2(s, ss, red);
  float mean = s * (1.f / 1024.f);
  float var = ss * (1.f / 1024.f) - mean * mean;
  float inv = rsqrtf(var + EPSN);
  float4 o;
  float* ov = (float*)&o;
  float rs = 0.f;
#pragma unroll
  for (int r = 0; r < 4; ++r) {
    float v = (acc[r] - mean) * inv;
    v = v > 0.f ? v : 0.f;
    ov[r] = v;
    rs += v;
  }
  *(float4*)&feas[(m * 512 + c) * 1024 + y * 32 + xb] = o;
  float tot = breduce_sum(rs, red);
  if (threadIdx.x == 0) bmean[m * 512 + c] = tot * (1.f / 1024.f);
}

__global__ __launch_bounds__(256) void sk_all(
    const float* __restrict__ x, const float* __restrict__ w3,
    const float* __restrict__ b3, const float* __restrict__ w5,
    const float* __restrict__ b5, const float* __restrict__ w7,
    const float* __restrict__ b7, float* __restrict__ feas,
    float* __restrict__ bmean) {
  __shared__ float chanp[38 * 40];   // row stride 40 -> 16B-aligned rows
  __shared__ float ws7p[16 * 56];    // 7 rows x 8 (pad) per ic
  __shared__ float ws5p[16 * 40];    // 5 rows x 8
  __shared__ float ws3p[16 * 12];    // 3 rows x 4
  __shared__ float red[8];
  int c = blockIdx.x, tid = threadIdx.x, g = c >> 4;
  for (int i = tid; i < 1520; i += 256) chanp[i] = 0.f;
  for (int i = tid; i < 896; i += 256) {
    int ic = i / 56, t = i - ic * 56, r = t >> 3, k = t & 7;
    ws7p[i] = (r < 7 && k < 7) ? w7[c * 784 + ic * 49 + r * 7 + k] : 0.f;
  }
  for (int i = tid; i < 640; i += 256) {
    int ic = i / 40, t = i - ic * 40, r = t >> 3, k = t & 7;
    ws5p[i] = (r < 5 && k < 5) ? w5[c * 400 + ic * 25 + r * 5 + k] : 0.f;
  }
  for (int i = tid; i < 192; i += 256) {
    int ic = i / 12, t = i - ic * 12, r = t >> 2, k = t & 3;
    ws3p[i] = (k < 3) ? w3[c * 144 + ic * 9 + r * 3 + k] : 0.f;
  }
  int y = tid >> 3, xb = (tid & 7) * 4;
  float a3[4] = {}, a5[4] = {}, a7[4] = {};
  int xr = tid >> 3, xc = (tid & 7) * 4;  // staging coords (4 px/thread)
  for (int ic = 0; ic < 16; ++ic) {
    __syncthreads();
    {
      float4 xv = *(const float4*)&x[(g * 16 + ic) * 1024 + tid * 4];
      float* dst = &chanp[(xr + 3) * 40 + xc + 3];
      dst[0] = xv.x; dst[1] = xv.y; dst[2] = xv.z; dst[3] = xv.w;
    }
    __syncthreads();
#pragma unroll
    for (int dy = 0; dy < 7; ++dy) {
      const float* row = &chanp[(y + dy) * 40 + xb];
      float4 s0 = *(const float4*)row;
      float4 s1 = *(const float4*)(row + 4);
      float2 s2 = *(const float2*)(row + 8);
      float seg[10] = {s0.x, s0.y, s0.z, s0.w, s1.x, s1.y, s1.z, s1.w, s2.x, s2.y};
      const float* w7r = &ws7p[ic * 56 + dy * 8];
      float4 wa = *(const float4*)w7r;
      float4 wb = *(const float4*)(w7r + 4);
      float w7v[7] = {wa.x, wa.y, wa.z, wa.w, wb.x, wb.y, wb.z};
#pragma unroll
      for (int kx = 0; kx < 7; ++kx)
#pragma unroll
        for (int px = 0; px < 4; ++px) a7[px] += seg[px + kx] * w7v[kx];
      if (dy >= 1 && dy <= 5) {
        const float* w5r = &ws5p[ic * 40 + (dy - 1) * 8];
        float4 va = *(const float4*)w5r;
        float4 vb = *(const float4*)(w5r + 4);
        float w5v[5] = {va.x, va.y, va.z, va.w, vb.x};
#pragma unroll
        for (int kx = 0; kx < 5; ++kx)
#pragma unroll
          for (int px = 0; px < 4; ++px) a5[px] += seg[px + kx + 1] * w5v[kx];
      }
      if (dy >= 2 && dy <= 4) {
        float4 ta = *(const float4*)&ws3p[ic * 12 + (dy - 2) * 4];
        float w3v[3] = {ta.x, ta.y, ta.z};
#pragma unroll
        for (int kx = 0; kx < 3; ++kx)
#pragma unroll
          for (int px = 0; px < 4; ++px) a3[px] += seg[px + kx + 2] * w3v[kx];
      }
    }
  }
  finish_branch(a3, b3[c], 0, c, y, xb, feas, bmean, red);
  finish_branch(a5, b5[c], 1, c, y, xb, feas, bmean, red);
  finish_branch(a7, b7[c], 2, c, y, xb, feas, bmean, red);
}

// ---------------- FC chain + branch softmax (one block) ---------------------
__global__ __launch_bounds__(256) void fc_att(
    const float* __restrict__ bmean, const float* __restrict__ w_fc,
    const float* __restrict__ b_fc, const float* __restrict__ w0,
    const float* __restrict__ b0, const float* __restrict__ w1,
    const float* __restrict__ b1, const float* __restrict__ w2,
    const float* __restrict__ b2, float* __restrict__ att) {
  __shared__ float sfea[512];
  __shared__ float zz[32];
  int tid = threadIdx.x;
  for (int c = tid; c < 512; c += 256)
    sfea[c] = bmean[c] + bmean[512 + c] + bmean[1024 + c];
  __syncthreads();
  if (tid < 32) {
    float d = b_fc[tid];
    for (int c = 0; c < 512; ++c) d += sfea[c] * w_fc[tid * 512 + c];
    zz[tid] = d;
  }
  __syncthreads();
  for (int c = tid; c < 512; c += 256) {
    float l0 = b0[c], l1 = b1[c], l2 = b2[c];
#pragma unroll
    for (int j = 0; j < 32; ++j) {
      float z = zz[j];
      l0 += z * w0[c * 32 + j];
      l1 += z * w1[c * 32 + j];
      l2 += z * w2[c * 32 + j];
    }
    float mx = fmaxf(l0, fmaxf(l1, l2));
    float e0 = expf(l0 - mx), e1 = expf(l1 - mx), e2 = expf(l2 - mx);
    float inv = 1.f / (e0 + e1 + e2);
    att[c] = e0 * inv;
    att[512 + c] = e1 * inv;
    att[1024 + c] = e2 * inv;
  }
}

// ---------------- attention blend -> res (ch-major) + rest (pos-major) ------
__global__ __launch_bounds__(256) void blend_t(const float* __restrict__ feas,
                                               const float* __restrict__ att,
                                               float* __restrict__ res,
                                               float* __restrict__ rest) {
  __shared__ float t[32][33];
  int pb = blockIdx.x * 32, cb = blockIdx.y * 32;
  int tx = threadIdx.x & 31, ty = threadIdx.x >> 5;
#pragma unroll
  for (int r = 0; r < 4; ++r) {
    int cl = ty + r * 8;
    int c = cb + cl, pos = pb + tx;
    float v = feas[c * 1024 + pos] * att[c] +
              feas[(512 + c) * 1024 + pos] * att[512 + c] +
              feas[(1024 + c) * 1024 + pos] * att[1024 + c];
    res[c * 1024 + pos] = v;
    t[cl][tx] = v;
  }
  __syncthreads();
#pragma unroll
  for (int r = 0; r < 4; ++r) {
    int pl = ty + r * 8;
    rest[(pb + pl) * 512 + cb + tx] = t[tx][pl];
  }
}

// ---------------- 2x2 average pool -> fg_small (512,16,16) ------------------
__global__ void pool2(const float* __restrict__ res, float* __restrict__ fgs) {
  int idx = blockIdx.x * 256 + threadIdx.x;
  int c = idx >> 8;
  int rem = idx & 255;
  int i = rem >> 4, j = rem & 15;
  const float* base = res + c * 1024 + (2 * i) * 32 + 2 * j;
  fgs[idx] = 0.25f * (base[0] + base[1] + base[32] + base[33]);
}

// ---------------- Gram split-K partials -------------------------------------
__global__ __launch_bounds__(256) void gram_part(const float* __restrict__ fgs,
                                                 float* __restrict__ Apart) {
  __shared__ float ch[4][324];
  int tid = threadIdx.x;
  int qb = blockIdx.x * 64, pb = blockIdx.y * 64;
  int kc = blockIdx.z;
  int tx = tid & 15, ty = tid >> 4;
  for (int i = tid; i < 4 * 324; i += 256) ((float*)ch)[i] = 0.f;
  int pi = (pb + ty * 4) >> 4, pj = (pb + ty * 4) & 15;
  int qi = (qb + tx * 4) >> 4, qj = (qb + tx * 4) & 15;
  int lane = tid & 63, wv = tid >> 6;
  int sr = lane >> 2, sc = (lane & 3) * 4;
  float acc[4][4] = {};
  for (int c0 = kc * 32; c0 < kc * 32 + 32; c0 += 4) {
    __syncthreads();
    {
      float4 v = *(const float4*)&fgs[(c0 + wv) * 256 + lane * 4];
      float* dst = &ch[wv][(sr + 1) * 18 + sc + 1];
      dst[0] = v.x; dst[1] = v.y; dst[2] = v.z; dst[3] = v.w;
    }
    __syncthreads();
#pragma unroll
    for (int cc = 0; cc < 4; ++cc) {
      float ps[3][6], qs[3][6];
#pragma unroll
      for (int u = 0; u < 3; ++u) {
        const float* pr = &ch[cc][(pi + u) * 18 + pj];
        const float* qr = &ch[cc][(qi + u) * 18 + qj];
#pragma unroll
        for (int t = 0; t < 6; ++t) { ps[u][t] = pr[t]; qs[u][t] = qr[t]; }
      }
#pragma unroll
      for (int u = 0; u < 3; ++u)
#pragma unroll
        for (int v = 0; v < 3; ++v)
#pragma unroll
          for (int i = 0; i < 4; ++i)
#pragma unroll
            for (int j = 0; j < 4; ++j)
              acc[i][j] += ps[u][v + i] * qs[u][v + j];
    }
  }
#pragma unroll
  for (int i = 0; i < 4; ++i) {
    float4 o4 = {acc[i][0], acc[i][1], acc[i][2], acc[i][3]};
    *(float4*)&Apart[(size_t)kc * 65536 + (pb + ty * 4 + i) * 256 + qb + tx * 4] = o4;
  }
}

__global__ void gram_reduce(const float* __restrict__ Apart,
                            float* __restrict__ A) {
  int idx = blockIdx.x * 256 + threadIdx.x;
  float s = 0.f;
#pragma unroll
  for (int k = 0; k < 16; ++k) s += Apart[(size_t)k * 65536 + idx];
  A[idx] = s;
}

// ---------------- RAL attention softmax over patch axis ---------------------
__global__ __launch_bounds__(256) void attn_softmax(const float* __restrict__ A,
                                                    float* __restrict__ attn) {
  __shared__ float red[8];
  int q = blockIdx.x, t = threadIdx.x;
  float nrm = sqrtf(fmaxf(A[t * 256 + t], 0.f));
  float v = A[t * 256 + q] / fmaxf(nrm, 1e-4f) * 10.f;
  float mx = breduce_max(v, red);
  float e = expf(v - mx);
  float sm = breduce_sum(e, red);
  attn[t * 256 + q] = e / sm;
}

// ---------------- pack attn [p][q] -> attnT [q][p] bf16 ---------------------
__global__ __launch_bounds__(256) void pack_attnT(const float* __restrict__ attn,
                                                  ushort* __restrict__ attnT) {
  __shared__ float t[32][33];
  int pb = blockIdx.x * 32, qb = blockIdx.y * 32;
  int tx = threadIdx.x & 31, ty = threadIdx.x >> 5;
#pragma unroll
  for (int r = 0; r < 4; ++r) {
    int p = ty + r * 8;
    t[p][tx] = attn[(pb + p) * 256 + qb + tx];
  }
  __syncthreads();
#pragma unroll
  for (int r = 0; r < 4; ++r) {
    int q = ty + r * 8;
    attnT[(qb + q) * 256 + pb + tx] = f2bf(t[tx][q]);
  }
}

// ---------------- pack dilated res gather -> resd[b][c][p] bf16 -------------
__global__ void pack_resd(const float* __restrict__ res,
                          ushort* __restrict__ resd) {
  int idx = blockIdx.x * 256 + threadIdx.x;  // 2,097,152
  int b = idx >> 17;
  int rem = idx & 131071;
  int c = rem >> 8, p = rem & 255;
  int ki = b >> 2, kj = b & 3;
  int ry = 2 * (p >> 4) + ki - 1;
  int rx = 2 * (p & 15) + kj - 1;
  float v = ((unsigned)ry < 32u && (unsigned)rx < 32u)
                ? res[c * 1024 + ry * 32 + rx] : 0.f;
  resd[idx] = f2bf(v);
}

// ---------------- tconv: 16-batch bf16 MFMA GEMM ----------------------------
// T[b][q][c] = sum_p attnT[q][p] * resd[b][c][p]; M=256(q) N=512(c) K=256(p)
__global__ __launch_bounds__(256) void mfma_tconv(const ushort* __restrict__ attnT,
                                                  const ushort* __restrict__ resd,
                                                  float* __restrict__ T) {
  int tid = threadIdx.x;
  int wv = tid >> 6, lane = tid & 63;
  int quad = lane >> 4, m16 = lane & 15;
  int nb = blockIdx.x * 64, qb = blockIdx.y * 64;
  int b = blockIdx.z;
  const ushort* Ap = attnT + (size_t)(qb + wv * 16 + m16) * 256 + quad * 8;
  const ushort* Bp = resd + (size_t)b * 131072 + (size_t)(nb + m16) * 256 + quad * 8;
  f32x4 ac0 = {0.f, 0.f, 0.f, 0.f}, ac1 = ac0, ac2 = ac0, ac3 = ac0;
#pragma unroll 2
  for (int k0 = 0; k0 < 256; k0 += 32) {
    bf16x8 af = *(const bf16x8*)(Ap + k0);
    bf16x8 b0 = *(const bf16x8*)(Bp + k0);
    bf16x8 b1 = *(const bf16x8*)(Bp + 16 * 256 + k0);
    bf16x8 b2 = *(const bf16x8*)(Bp + 32 * 256 + k0);
    bf16x8 b3 = *(const bf16x8*)(Bp + 48 * 256 + k0);
    ac0 = __builtin_amdgcn_mfma_f32_16x16x32_bf16(af, b0, ac0, 0, 0, 0);
    ac1 = __builtin_amdgcn_mfma_f32_16x16x32_bf16(af, b1, ac1, 0, 0, 0);
    ac2 = __builtin_amdgcn_mfma_f32_16x16x32_bf16(af, b2, ac2, 0, 0, 0);
    ac3 = __builtin_amdgcn_mfma_f32_16x16x32_bf16(af, b3, ac3, 0, 0, 0);
  }
  int row = qb + wv * 16 + quad * 4;
  float* Cb = T + (size_t)b * 131072;
  f32x4 accs[4] = {ac0, ac1, ac2, ac3};
#pragma unroll
  for (int nt = 0; nt < 4; ++nt)
#pragma unroll
    for (int r = 0; r < 4; ++r)
      Cb[(size_t)(row + r) * 512 + nb + nt * 16 + m16] = accs[nt][r];
}

// ---------------- combine taps -> orlt (pos-major) + sigt -------------------
__global__ void tcomb(const float* __restrict__ T, float* __restrict__ orlt,
                      float* __restrict__ sigt) {
  int f = blockIdx.x * 256 + threadIdx.x;
  int n = f >> 9, c = f & 511;
  int y = n >> 5, x = n & 31;
  int i0 = (y + 1) >> 1, ki0 = (y + 1) & 1;
  int j0 = (x + 1) >> 1, kj0 = (x + 1) & 1;
  float sum = 0.f;
#pragma unroll
  for (int iy = 0; iy < 2; ++iy) {
    int i = i0 - iy, ki = ki0 + 2 * iy;
    if ((unsigned)i >= 16u) continue;
#pragma unroll
    for (int ix = 0; ix < 2; ++ix) {
      int j = j0 - ix, kj = kj0 + 2 * ix;
      if ((unsigned)j >= 16u) continue;
      sum += T[((ki * 4 + kj) * 256 + i * 16 + j) * 512 + c];
    }
  }
  float v = sum * 0.25f;
  orlt[f] = v;
  sigt[f] = 1.f / (1.f + expf(-v));
}

// ---------------- fp32 -> bf16 elementwise (4/thread) -----------------------
__global__ void conv_bf(const float* __restrict__ in, ushort* __restrict__ out) {
  int i = (blockIdx.x * 256 + threadIdx.x) * 4;
  float4 v = *(const float4*)&in[i];
  ushort4 o = {f2bf(v.x), f2bf(v.y), f2bf(v.z), f2bf(v.w)};
  *(ushort4*)&out[i] = o;
}

// ---------------- transpose-pack: ch-major fp32 x2 -> pos-major bf16 --------
__global__ __launch_bounds__(256) void pack_zt(const float* __restrict__ za,
                                               const float* __restrict__ zb,
                                               ushort* __restrict__ zt) {
  __shared__ float t[32][33];
  int kb = blockIdx.x * 32, pb = blockIdx.y * 32;
  const float* src = (kb < 512) ? za + (size_t)kb * 1024
                                : zb + (size_t)(kb - 512) * 1024;
  int tx = threadIdx.x & 31, ty = threadIdx.x >> 5;
#pragma unroll
  for (int r = 0; r < 4; ++r) {
    int k = ty + r * 8;
    t[k][tx] = src[k * 1024 + pb + tx];
  }
  __syncthreads();
#pragma unroll
  for (int r = 0; r < 4; ++r) {
    int p = ty + r * 8;
    zt[(size_t)(pb + p) * 1024 + kb + tx] = f2bf(t[tx][p]);
  }
}

// ---------------- transpose-pack: orlt [1024 p][512 c] -> orlT [512][1024] --
__global__ __launch_bounds__(256) void pack_orlT(const float* __restrict__ orlt,
                                                 ushort* __restrict__ out) {
  __shared__ float t[32][33];
  int cb = blockIdx.x * 32, pb = blockIdx.y * 32;
  int tx = threadIdx.x & 31, ty = threadIdx.x >> 5;
#pragma unroll
  for (int r = 0; r < 4; ++r) {
    int p = ty + r * 8;
    t[p][tx] = orlt[(size_t)(pb + p) * 512 + cb + tx];
  }
  __syncthreads();
#pragma unroll
  for (int r = 0; r < 4; ++r) {
    int c = ty + r * 8;
    out[(size_t)(cb + c) * 1024 + pb + tx] = f2bf(t[tx][c]);
  }
}

// ---------------- bf16 MFMA GEMM: C[M][N] = A[M][K] * Bt[N][K]^T ------------
__global__ __launch_bounds__(256) void mfma_gemm(const ushort* __restrict__ A,
                                                 const ushort* __restrict__ Bt,
                                                 float* __restrict__ C, int M,
                                                 int N, int K) {
  int tid = threadIdx.x;
  int wv = tid >> 6, lane = tid & 63;
  int quad = lane >> 4, m16 = lane & 15;
  int nb = blockIdx.x * 64, mb = blockIdx.y * 64;
  const ushort* Ap = A + (size_t)(mb + wv * 16 + m16) * K + quad * 8;
  const ushort* Bp = Bt + (size_t)(nb + m16) * K + quad * 8;
  f32x4 ac0 = {0.f, 0.f, 0.f, 0.f}, ac1 = ac0, ac2 = ac0, ac3 = ac0;
#pragma unroll 2
  for (int k0 = 0; k0 < K; k0 += 32) {
    bf16x8 af = *(const bf16x8*)(Ap + k0);
    bf16x8 b0 = *(const bf16x8*)(Bp + k0);
    bf16x8 b1 = *(const bf16x8*)(Bp + (size_t)16 * K + k0);
    bf16x8 b2 = *(const bf16x8*)(Bp + (size_t)32 * K + k0);
    bf16x8 b3 = *(const bf16x8*)(Bp + (size_t)48 * K + k0);
    ac0 = __builtin_amdgcn_mfma_f32_16x16x32_bf16(af, b0, ac0, 0, 0, 0);
    ac1 = __builtin_amdgcn_mfma_f32_16x16x32_bf16(af, b1, ac1, 0, 0, 0);
    ac2 = __builtin_amdgcn_mfma_f32_16x16x32_bf16(af, b2, ac2, 0, 0, 0);
    ac3 = __builtin_amdgcn_mfma_f32_16x16x32_bf16(af, b3, ac3, 0, 0, 0);
  }
  int row = mb + wv * 16 + quad * 4;
  f32x4 accs[4] = {ac0, ac1, ac2, ac3};
#pragma unroll
  for (int nt = 0; nt < 4; ++nt)
#pragma unroll
    for (int r = 0; r < 4; ++r)
      C[(size_t)(row + r) * N + nb + nt * 16 + m16] = accs[nt][r];
}

// ---------------- CSA fused (float2): correlation + softmax + gather --------
__global__ __launch_bounds__(256) void csa_fused(const float* __restrict__ sigt,
                                                 const float* __restrict__ orlt,
                                                 float* __restrict__ outc) {
  __shared__ float red[8];
  __shared__ float a9s[9];
  int n = blockIdx.x, tid = threadIdx.x;
  int ny = n >> 5, nx = n & 31;
  int c2 = tid * 2;
  float2 ctr = *(const float2*)&sigt[n * 512 + c2];
  float part[9];
#pragma unroll
  for (int u = 0; u < 3; ++u) {
    int yy = ny + u - 1;
#pragma unroll
    for (int v = 0; v < 3; ++v) {
      int xx = nx + v - 1;
      float2 nb = {0.f, 0.f};
      if ((unsigned)yy < 32u && (unsigned)xx < 32u)
        nb = *(const float2*)&sigt[(yy * 32 + xx) * 512 + c2];
      part[u * 3 + v] = ctr.x * nb.x + ctr.y * nb.y;
    }
  }
  float a[9];
#pragma unroll
  for (int t = 0; t < 9; ++t) a[t] = breduce_sum(part[t], red) * (1.f / 512.f);
  float mx = a[0];
#pragma unroll
  for (int t = 1; t < 9; ++t) mx = fmaxf(mx, a[t]);
  float sum = 0.f;
#pragma unroll
  for (int t = 0; t < 9; ++t) { a[t] = expf(a[t] - mx); sum += a[t]; }
  if (tid == 0) {
    float inv = 1.f / sum;
#pragma unroll
    for (int t = 0; t < 9; ++t) a9s[t] = a[t] * inv;
  }
  __syncthreads();
  float2 acc = {0.f, 0.f};
#pragma unroll
  for (int u = 0; u < 3; ++u) {
    int yy = ny + u - 1;
#pragma unroll
    for (int v = 0; v < 3; ++v) {
      int xx = nx + v - 1;
      if ((unsigned)yy < 32u && (unsigned)xx < 32u) {
        float w = a9s[u * 3 + v];
        float2 ov = *(const float2*)&orlt[(yy * 32 + xx) * 512 + c2];
        acc.x += w * ov.x;
        acc.y += w * ov.y;
      }
    }
  }
  *(float2*)&outc[n * 512 + c2] = acc;
}

// ---------------- per-channel InstanceNorm + LeakyReLU(0.2) -----------------
__global__ __launch_bounds__(256) void norm_leaky(const float* __restrict__ raw,
                                                  float* __restrict__ out) {
  __shared__ float red[8];
  int c = blockIdx.x, tid = threadIdx.x;
  float v[4];
  float s = 0.f, ss = 0.f;
#pragma unroll
  for (int r = 0; r < 4; ++r) {
    v[r] = raw[c * 1024 + tid + r * 256];
    s += v[r];
    ss += v[r] * v[r];
  }
  breduce2(s, ss, red);
  float mean = s * (1.f / 1024.f);
  float var = ss * (1.f / 1024.f) - mean * mean;
  float inv = rsqrtf(var + EPSN);
#pragma unroll
  for (int r = 0; r < 4; ++r) {
    float t = (v[r] - mean) * inv;
    out[c * 1024 + tid + r * 256] = t >= 0.f ? t : 0.2f * t;
  }
}

// ---------------- host launch ------------------------------------------------
extern "C" void kernel_launch(void* const* d_in, const int* in_sizes, int n_in,
                              void* d_out, int out_size, void* d_ws, size_t ws_size,
                              hipStream_t stream) {
  const float* x = (const float*)d_in[0];
  const float* gus = (const float*)d_in[1];
  const float* w3 = (const float*)d_in[2];
  const float* b3 = (const float*)d_in[3];
  const float* w5 = (const float*)d_in[4];
  const float* b5 = (const float*)d_in[5];
  const float* w7 = (const float*)d_in[6];
  const float* b7 = (const float*)d_in[7];
  const float* wfc = (const float*)d_in[8];
  const float* bfc = (const float*)d_in[9];
  const float* w0 = (const float*)d_in[10];
  const float* b0 = (const float*)d_in[11];
  const float* w1 = (const float*)d_in[12];
  const float* b1 = (const float*)d_in[13];
  const float* w2 = (const float*)d_in[14];
  const float* b2 = (const float*)d_in[15];
  const float* wdown = (const float*)d_in[16];
  const float* wfuse = (const float*)d_in[17];

  float* ws = (float*)d_ws;
  float* feas = ws;                   // 1572864 (dead after blend_t)
  float* bmean = feas + 1572864;      // 1536
  float* att = bmean + 1536;          // 1536
  float* res = att + 1536;            // 524288
  float* rest = res + 524288;         // 524288 (pos-major res)
  float* fgs = rest + 524288;         // 131072
  float* A = fgs + 131072;            // 65536
  float* attn = A + 65536;            // 65536
  float* T = attn + 65536;            // 2097152 (16x256x512)
  float* orlt = T + 2097152;          // 524288
  float* sigt = orlt + 524288;        // 524288
  float* gusout = sigt + 524288;      // 524288
  float* outcsa = gusout + 524288;    // 524288
  float* zdown = outcsa + 524288;     // 524288
  float* raw = feas;                  // reuse (feas dead after blend_t)
  float* Apart = T;                   // reuse (T written later by mfma_tconv)
  // tconv bf16 inputs overlaid on dead feas region (raw not written until later)
  ushort* resd = (ushort*)feas;                 // 2097152 ush = 1048576 fl
  ushort* attnT = (ushort*)(feas + 1048576);    // 65536 ush
  // bf16 GEMM buffers overlaid on T (T dead after tcomb):
  ushort* gus_bf = (ushort*)T;                  // 1048576 ush
  ushort* orlT = (ushort*)(T + 524288);         // 524288 ush
  ushort* wdown_bf = (ushort*)(T + 786432);     // 524288 ush
  ushort* wfuse_bf = (ushort*)(T + 1048576);    // 524288 ush
  ushort* Zt = (ushort*)(T + 1310720);          // 1048576 ush

  sk_all<<<512, 256, 0, stream>>>(x, w3, b3, w5, b5, w7, b7, feas, bmean);
  fc_att<<<1, 256, 0, stream>>>(bmean, wfc, bfc, w0, b0, w1, b1, w2, b2, att);
  blend_t<<<dim3(32, 16), 256, 0, stream>>>(feas, att, res, rest);
  pool2<<<512, 256, 0, stream>>>(res, fgs);
  gram_part<<<dim3(4, 4, 16), 256, 0, stream>>>(fgs, Apart);
  gram_reduce<<<256, 256, 0, stream>>>(Apart, A);
  attn_softmax<<<256, 256, 0, stream>>>(A, attn);
  pack_attnT<<<dim3(8, 8), 256, 0, stream>>>(attn, attnT);
  pack_resd<<<8192, 256, 0, stream>>>(res, resd);
  mfma_tconv<<<dim3(8, 4, 16), 256, 0, stream>>>(attnT, resd, T);
  tcomb<<<2048, 256, 0, stream>>>(T, orlt, sigt);
  // ---- bf16 conversions (T region now dead) ----
  conv_bf<<<1024, 256, 0, stream>>>(gus, gus_bf);
  conv_bf<<<512, 256, 0, stream>>>(wdown, wdown_bf);
  conv_bf<<<512, 256, 0, stream>>>(wfuse, wfuse_bf);
  pack_orlT<<<dim3(16, 32), 256, 0, stream>>>(orlt, orlT);
  mfma_gemm<<<dim3(8, 16), 256, 0, stream>>>(gus_bf, orlT, gusout, 1024, 512, 1024);
  csa_fused<<<1024, 256, 0, stream>>>(sigt, orlt, outcsa);
  pack_zt<<<dim3(32, 32), 256, 0, stream>>>(gusout, outcsa, Zt);
  mfma_gemm<<<dim3(16, 8), 256, 0, stream>>>(wdown_bf, Zt, raw, 512, 1024, 1024);
  norm_leaky<<<512, 256, 0, stream>>>(raw, zdown);
  pack_zt<<<dim3(32, 32), 256, 0, stream>>>(zdown, res, Zt);
  mfma_gemm<<<dim3(16, 8), 256, 0, stream>>>(wfuse_bf, Zt, raw, 512, 1024, 1024);
  norm_leaky<<<512, 256, 0, stream>>>(raw, (float*)d_out);
}

// Round 8
// 279.977 us; speedup vs baseline: 3.2990x; 1.0429x over previous
//
#include <hip/hip_runtime.h>
#include <math.h>

#define EPSN 1e-5f

typedef __attribute__((ext_vector_type(8))) short bf16x8;
typedef __attribute__((ext_vector_type(4))) float f32x4;

__device__ __forceinline__ ushort f2bf(float f) {
  unsigned u = __float_as_uint(f);
  unsigned r = (u + 0x7fff + ((u >> 16) & 1)) >> 16;
  return (ushort)r;
}

// ---------------- block-wide reductions (blockDim.x == 256, 4 waves) --------
__device__ __forceinline__ void breduce2(float& a, float& b, float* lds) {
#pragma unroll
  for (int o = 32; o > 0; o >>= 1) {
    a += __shfl_down(a, o);
    b += __shfl_down(b, o);
  }
  int lane = threadIdx.x & 63, wid = threadIdx.x >> 6;
  __syncthreads();
  if (lane == 0) { lds[wid] = a; lds[4 + wid] = b; }
  __syncthreads();
  a = lds[0] + lds[1] + lds[2] + lds[3];
  b = lds[4] + lds[5] + lds[6] + lds[7];
}

__device__ __forceinline__ float breduce_sum(float v, float* lds) {
#pragma unroll
  for (int o = 32; o > 0; o >>= 1) v += __shfl_down(v, o);
  int lane = threadIdx.x & 63, wid = threadIdx.x >> 6;
  __syncthreads();
  if (lane == 0) lds[wid] = v;
  __syncthreads();
  return lds[0] + lds[1] + lds[2] + lds[3];
}

__device__ __forceinline__ float breduce_max(float v, float* lds) {
#pragma unroll
  for (int o = 32; o > 0; o >>= 1) v = fmaxf(v, __shfl_down(v, o));
  int lane = threadIdx.x & 63, wid = threadIdx.x >> 6;
  __syncthreads();
  if (lane == 0) lds[wid] = v;
  __syncthreads();
  return fmaxf(fmaxf(lds[0], lds[1]), fmaxf(lds[2], lds[3]));
}

// ---------------- SKConv: 2 output channels/block, shared staged x ----------
__device__ __forceinline__ void finish_branch(float* acc, float bv, int m, int c,
                                              int y, int xb, float* feas,
                                              float* bmean, float* red) {
  float s = 0.f, ss = 0.f;
#pragma unroll
  for (int r = 0; r < 4; ++r) {
    acc[r] += bv;
    s += acc[r];
    ss += acc[r] * acc[r];
  }
  breduce2(s, ss, red);
  float mean = s * (1.f / 1024.f);
  float var = ss * (1.f / 1024.f) - mean * mean;
  float inv = rsqrtf(var + EPSN);
  float4 o;
  float* ov = (float*)&o;
  float rs = 0.f;
#pragma unroll
  for (int r = 0; r < 4; ++r) {
    float v = (acc[r] - mean) * inv;
    v = v > 0.f ? v : 0.f;
    ov[r] = v;
    rs += v;
  }
  *(float4*)&feas[(m * 512 + c) * 1024 + y * 32 + xb] = o;
  float tot = breduce_sum(rs, red);
  if (threadIdx.x == 0) bmean[m * 512 + c] = tot * (1.f / 1024.f);
}

__global__ __launch_bounds__(256) void sk_all2(
    const float* __restrict__ x, const float* __restrict__ w3,
    const float* __restrict__ b3, const float* __restrict__ w5,
    const float* __restrict__ b5, const float* __restrict__ w7,
    const float* __restrict__ b7, float* __restrict__ feas,
    float* __restrict__ bmean) {
  __shared__ float chanp[38 * 40];     // stride 40 -> aligned float4 rows
  __shared__ float ws7p[2 * 16 * 56];  // [ch][ic][7 rows x 8]
  __shared__ float ws5p[2 * 16 * 40];  // [ch][ic][5 rows x 8]
  __shared__ float ws3p[2 * 16 * 12];  // [ch][ic][3 rows x 4]
  __shared__ float red[8];
  int c0 = blockIdx.x * 2, tid = threadIdx.x, g = c0 >> 4;
  for (int i = tid; i < 1520; i += 256) chanp[i] = 0.f;
  for (int i = tid; i < 1792; i += 256) {
    int ch = i / 896, rem = i - ch * 896;
    int ic = rem / 56, t = rem - ic * 56, r = t >> 3, k = t & 7;
    ws7p[i] = (r < 7 && k < 7) ? w7[(c0 + ch) * 784 + ic * 49 + r * 7 + k] : 0.f;
  }
  for (int i = tid; i < 1280; i += 256) {
    int ch = i / 640, rem = i - ch * 640;
    int ic = rem / 40, t = rem - ic * 40, r = t >> 3, k = t & 7;
    ws5p[i] = (r < 5 && k < 5) ? w5[(c0 + ch) * 400 + ic * 25 + r * 5 + k] : 0.f;
  }
  for (int i = tid; i < 384; i += 256) {
    int ch = i / 192, rem = i - ch * 192;
    int ic = rem / 12, t = rem - ic * 12, r = t >> 2, k = t & 3;
    ws3p[i] = (k < 3) ? w3[(c0 + ch) * 144 + ic * 9 + r * 3 + k] : 0.f;
  }
  int y = tid >> 3, xb = (tid & 7) * 4;
  float a3[2][4] = {}, a5[2][4] = {}, a7[2][4] = {};
  float4 xv = *(const float4*)&x[(size_t)(g * 16) * 1024 + tid * 4];  // prefetch ic=0
  for (int ic = 0; ic < 16; ++ic) {
    __syncthreads();
    {
      float* dst = &chanp[((tid >> 3) + 3) * 40 + (tid & 7) * 4 + 3];
      dst[0] = xv.x; dst[1] = xv.y; dst[2] = xv.z; dst[3] = xv.w;
    }
    __syncthreads();
    if (ic < 15)  // prefetch next channel; latency hidden behind compute
      xv = *(const float4*)&x[(size_t)(g * 16 + ic + 1) * 1024 + tid * 4];
#pragma unroll
    for (int dy = 0; dy < 7; ++dy) {
      const float* row = &chanp[(y + dy) * 40 + xb];
      float4 s0 = *(const float4*)row;
      float4 s1 = *(const float4*)(row + 4);
      float2 s2 = *(const float2*)(row + 8);
      float seg[10] = {s0.x, s0.y, s0.z, s0.w, s1.x, s1.y, s1.z, s1.w, s2.x, s2.y};
#pragma unroll
      for (int ch = 0; ch < 2; ++ch) {
        const float* w7r = &ws7p[ch * 896 + ic * 56 + dy * 8];
        float4 wa = *(const float4*)w7r;
        float4 wb = *(const float4*)(w7r + 4);
        float w7v[7] = {wa.x, wa.y, wa.z, wa.w, wb.x, wb.y, wb.z};
#pragma unroll
        for (int kx = 0; kx < 7; ++kx)
#pragma unroll
          for (int px = 0; px < 4; ++px) a7[ch][px] += seg[px + kx] * w7v[kx];
        if (dy >= 1 && dy <= 5) {
          const float* w5r = &ws5p[ch * 640 + ic * 40 + (dy - 1) * 8];
          float4 va = *(const float4*)w5r;
          float4 vb = *(const float4*)(w5r + 4);
          float w5v[5] = {va.x, va.y, va.z, va.w, vb.x};
#pragma unroll
          for (int kx = 0; kx < 5; ++kx)
#pragma unroll
            for (int px = 0; px < 4; ++px) a5[ch][px] += seg[px + kx + 1] * w5v[kx];
        }
        if (dy >= 2 && dy <= 4) {
          float4 ta = *(const float4*)&ws3p[ch * 192 + ic * 12 + (dy - 2) * 4];
          float w3v[3] = {ta.x, ta.y, ta.z};
#pragma unroll
          for (int kx = 0; kx < 3; ++kx)
#pragma unroll
            for (int px = 0; px < 4; ++px) a3[ch][px] += seg[px + kx + 2] * w3v[kx];
        }
      }
    }
  }
#pragma unroll
  for (int ch = 0; ch < 2; ++ch) {
    finish_branch(a3[ch], b3[c0 + ch], 0, c0 + ch, y, xb, feas, bmean, red);
    finish_branch(a5[ch], b5[c0 + ch], 1, c0 + ch, y, xb, feas, bmean, red);
    finish_branch(a7[ch], b7[c0 + ch], 2, c0 + ch, y, xb, feas, bmean, red);
  }
}

// ---------------- blend + fused FC-attention; writes res + Zt2 res-half -----
__global__ __launch_bounds__(256) void blend_fc(
    const float* __restrict__ feas, const float* __restrict__ bmean,
    const float* __restrict__ wfc, const float* __restrict__ bfc,
    const float* __restrict__ w0, const float* __restrict__ b0,
    const float* __restrict__ w1, const float* __restrict__ b1,
    const float* __restrict__ w2, const float* __restrict__ b2,
    float* __restrict__ res, ushort* __restrict__ Zt2) {
  __shared__ float sfea[512];
  __shared__ float zpart[8][32];
  __shared__ float zz[32];
  __shared__ float lv[3][32];
  __shared__ float attb[3][32];
  __shared__ float tile[32][33];
  int tid = threadIdx.x;
  int pb = blockIdx.x * 32, cb = blockIdx.y * 32;
  for (int c = tid; c < 512; c += 256)
    sfea[c] = bmean[c] + bmean[512 + c] + bmean[1024 + c];
  __syncthreads();
  {
    int j = tid & 31, seg = tid >> 5;
    float p = 0.f;
    for (int c = seg * 64; c < seg * 64 + 64; ++c) p += sfea[c] * wfc[j * 512 + c];
    zpart[seg][j] = p;
  }
  __syncthreads();
  if (tid < 32) {
    float d = bfc[tid];
#pragma unroll
    for (int s = 0; s < 8; ++s) d += zpart[s][tid];
    zz[tid] = d;
  }
  __syncthreads();
  if (tid < 96) {
    int m = tid >> 5, cl = tid & 31;
    const float* wm = (m == 0) ? w0 : (m == 1) ? w1 : w2;
    const float* bm = (m == 0) ? b0 : (m == 1) ? b1 : b2;
    float l = bm[cb + cl];
#pragma unroll
    for (int j = 0; j < 32; ++j) l += zz[j] * wm[(cb + cl) * 32 + j];
    lv[m][cl] = l;
  }
  __syncthreads();
  if (tid < 32) {
    float l0 = lv[0][tid], l1 = lv[1][tid], l2 = lv[2][tid];
    float mx = fmaxf(l0, fmaxf(l1, l2));
    float e0 = expf(l0 - mx), e1 = expf(l1 - mx), e2 = expf(l2 - mx);
    float inv = 1.f / (e0 + e1 + e2);
    attb[0][tid] = e0 * inv; attb[1][tid] = e1 * inv; attb[2][tid] = e2 * inv;
  }
  __syncthreads();
  int tx = tid & 31, ty = tid >> 5;
#pragma unroll
  for (int r = 0; r < 4; ++r) {
    int cl = ty + r * 8;
    int c = cb + cl, pos = pb + tx;
    float v = feas[c * 1024 + pos] * attb[0][cl] +
              feas[(512 + c) * 1024 + pos] * attb[1][cl] +
              feas[(1024 + c) * 1024 + pos] * attb[2][cl];
    res[c * 1024 + pos] = v;
    tile[cl][tx] = v;
  }
  __syncthreads();
#pragma unroll
  for (int r = 0; r < 4; ++r) {
    int pl = ty + r * 8;
    Zt2[(size_t)(pb + pl) * 1024 + 512 + cb + tx] = f2bf(tile[tx][pl]);
  }
}

// ---------------- Gram split-K partials with fused 2x2 pooling --------------
__global__ __launch_bounds__(256) void gram_part2(const float* __restrict__ res,
                                                  float* __restrict__ Apart) {
  __shared__ float ch[4][324];
  int tid = threadIdx.x;
  int qb = blockIdx.x * 64, pb = blockIdx.y * 64;
  int kc = blockIdx.z;
  int tx = tid & 15, ty = tid >> 4;
  for (int i = tid; i < 4 * 324; i += 256) ((float*)ch)[i] = 0.f;
  int pi = (pb + ty * 4) >> 4, pj = (pb + ty * 4) & 15;
  int qi = (qb + tx * 4) >> 4, qj = (qb + tx * 4) & 15;
  int lane = tid & 63, wv = tid >> 6;
  int sr = lane >> 2, sc = (lane & 3) * 4;
  float acc[4][4] = {};
  for (int c0 = kc * 32; c0 < kc * 32 + 32; c0 += 4) {
    __syncthreads();
    {  // wave wv stages channel c0+wv, pooling 2x2 from res on the fly
      const float* src = res + (size_t)(c0 + wv) * 1024 + (2 * sr) * 32 + 2 * sc;
      float4 r0a = *(const float4*)src;
      float4 r0b = *(const float4*)(src + 4);
      float4 r1a = *(const float4*)(src + 32);
      float4 r1b = *(const float4*)(src + 36);
      float* dst = &ch[wv][(sr + 1) * 18 + sc + 1];
      dst[0] = 0.25f * (r0a.x + r0a.y + r1a.x + r1a.y);
      dst[1] = 0.25f * (r0a.z + r0a.w + r1a.z + r1a.w);
      dst[2] = 0.25f * (r0b.x + r0b.y + r1b.x + r1b.y);
      dst[3] = 0.25f * (r0b.z + r0b.w + r1b.z + r1b.w);
    }
    __syncthreads();
#pragma unroll
    for (int cc = 0; cc < 4; ++cc) {
      float ps[3][6], qs[3][6];
#pragma unroll
      for (int u = 0; u < 3; ++u) {
        const float* pr = &ch[cc][(pi + u) * 18 + pj];
        const float* qr = &ch[cc][(qi + u) * 18 + qj];
#pragma unroll
        for (int t = 0; t < 6; ++t) { ps[u][t] = pr[t]; qs[u][t] = qr[t]; }
      }
#pragma unroll
      for (int u = 0; u < 3; ++u)
#pragma unroll
        for (int v = 0; v < 3; ++v)
#pragma unroll
          for (int i = 0; i < 4; ++i)
#pragma unroll
            for (int j = 0; j < 4; ++j)
              acc[i][j] += ps[u][v + i] * qs[u][v + j];
    }
  }
#pragma unroll
  for (int i = 0; i < 4; ++i) {
    float4 o4 = {acc[i][0], acc[i][1], acc[i][2], acc[i][3]};
    *(float4*)&Apart[(size_t)kc * 65536 + (pb + ty * 4 + i) * 256 + qb + tx * 4] = o4;
  }
}

// ---------------- diagonal norms (one block) --------------------------------
__global__ void diag_norm(const float* __restrict__ Apart, float* __restrict__ invn) {
  int t = threadIdx.x;
  float d = 0.f;
#pragma unroll
  for (int k = 0; k < 16; ++k) d += Apart[(size_t)k * 65536 + t * 257];
  float nrm = sqrtf(fmaxf(d, 0.f));
  invn[t] = 10.f / fmaxf(nrm, 1e-4f);
}

// ---------------- softmax (+16-way reduce, via Gram symmetry) -> attnT bf16 -
__global__ __launch_bounds__(256) void attn_soft2(const float* __restrict__ Apart,
                                                  const float* __restrict__ invn,
                                                  ushort* __restrict__ attnT) {
  __shared__ float red[8];
  int q = blockIdx.x, t = threadIdx.x;
  float s = 0.f;
#pragma unroll
  for (int k = 0; k < 16; ++k) s += Apart[(size_t)k * 65536 + q * 256 + t];  // A[q][t] == A[t][q]
  float v = s * invn[t];
  float mx = breduce_max(v, red);
  float e = expf(v - mx);
  float sm = breduce_sum(e, red);
  attnT[q * 256 + t] = f2bf(e / sm);
}

// ---------------- pack dilated res gather -> resd[b][c][p] bf16 -------------
__global__ void pack_resd(const float* __restrict__ res,
                          ushort* __restrict__ resd) {
  int idx = blockIdx.x * 256 + threadIdx.x;
  int b = idx >> 17;
  int rem = idx & 131071;
  int c = rem >> 8, p = rem & 255;
  int ki = b >> 2, kj = b & 3;
  int ry = 2 * (p >> 4) + ki - 1;
  int rx = 2 * (p & 15) + kj - 1;
  float v = ((unsigned)ry < 32u && (unsigned)rx < 32u)
                ? res[c * 1024 + ry * 32 + rx] : 0.f;
  resd[idx] = f2bf(v);
}

// ---------------- tconv: 16-batch bf16 MFMA GEMM ----------------------------
__global__ __launch_bounds__(256) void mfma_tconv(const ushort* __restrict__ attnT,
                                                  const ushort* __restrict__ resd,
                                                  float* __restrict__ T) {
  int tid = threadIdx.x;
  int wv = tid >> 6, lane = tid & 63;
  int quad = lane >> 4, m16 = lane & 15;
  int nb = blockIdx.x * 64, qb = blockIdx.y * 64;
  int b = blockIdx.z;
  const ushort* Ap = attnT + (size_t)(qb + wv * 16 + m16) * 256 + quad * 8;
  const ushort* Bp = resd + (size_t)b * 131072 + (size_t)(nb + m16) * 256 + quad * 8;
  f32x4 ac0 = {0.f, 0.f, 0.f, 0.f}, ac1 = ac0, ac2 = ac0, ac3 = ac0;
#pragma unroll 2
  for (int k0 = 0; k0 < 256; k0 += 32) {
    bf16x8 af = *(const bf16x8*)(Ap + k0);
    bf16x8 b0 = *(const bf16x8*)(Bp + k0);
    bf16x8 b1 = *(const bf16x8*)(Bp + 16 * 256 + k0);
    bf16x8 b2 = *(const bf16x8*)(Bp + 32 * 256 + k0);
    bf16x8 b3 = *(const bf16x8*)(Bp + 48 * 256 + k0);
    ac0 = __builtin_amdgcn_mfma_f32_16x16x32_bf16(af, b0, ac0, 0, 0, 0);
    ac1 = __builtin_amdgcn_mfma_f32_16x16x32_bf16(af, b1, ac1, 0, 0, 0);
    ac2 = __builtin_amdgcn_mfma_f32_16x16x32_bf16(af, b2, ac2, 0, 0, 0);
    ac3 = __builtin_amdgcn_mfma_f32_16x16x32_bf16(af, b3, ac3, 0, 0, 0);
  }
  int row = qb + wv * 16 + quad * 4;
  float* Cb = T + (size_t)b * 131072;
  f32x4 accs[4] = {ac0, ac1, ac2, ac3};
#pragma unroll
  for (int nt = 0; nt < 4; ++nt)
#pragma unroll
    for (int r = 0; r < 4; ++r)
      Cb[(size_t)(row + r) * 512 + nb + nt * 16 + m16] = accs[nt][r];
}

// ---------------- combine taps -> orlt, sigt, orlT bf16 (tiled) -------------
__global__ __launch_bounds__(256) void tcomb2(const float* __restrict__ T,
                                              float* __restrict__ orlt,
                                              float* __restrict__ sigt,
                                              ushort* __restrict__ orlT) {
  __shared__ float tl[32][33];
  int nb = blockIdx.x * 32, cb = blockIdx.y * 32;
  int tx = threadIdx.x & 31, ty = threadIdx.x >> 5;
#pragma unroll
  for (int r = 0; r < 4; ++r) {
    int nl = ty + r * 8;
    int n = nb + nl, c = cb + tx;
    int y = n >> 5, x = n & 31;
    int i0 = (y + 1) >> 1, ki0 = (y + 1) & 1;
    int j0 = (x + 1) >> 1, kj0 = (x + 1) & 1;
    float sum = 0.f;
#pragma unroll
    for (int iy = 0; iy < 2; ++iy) {
      int i = i0 - iy, ki = ki0 + 2 * iy;
      if ((unsigned)i >= 16u) continue;
#pragma unroll
      for (int ix = 0; ix < 2; ++ix) {
        int j = j0 - ix, kj = kj0 + 2 * ix;
        if ((unsigned)j >= 16u) continue;
        sum += T[((ki * 4 + kj) * 256 + i * 16 + j) * 512 + c];
      }
    }
    float v = sum * 0.25f;
    orlt[n * 512 + c] = v;
    sigt[n * 512 + c] = 1.f / (1.f + expf(-v));
    tl[nl][tx] = v;
  }
  __syncthreads();
#pragma unroll
  for (int r = 0; r < 4; ++r) {
    int cl = ty + r * 8;
    orlT[(size_t)(cb + cl) * 1024 + nb + tx] = f2bf(tl[tx][cl]);
  }
}

// ---------------- fp32 -> bf16 for gus + both weights (one kernel) ----------
__global__ void conv_bf3(const float* __restrict__ gus,
                         const float* __restrict__ wdown,
                         const float* __restrict__ wfuse,
                         ushort* __restrict__ gus_bf,
                         ushort* __restrict__ wdown_bf,
                         ushort* __restrict__ wfuse_bf) {
  int i = (blockIdx.x * 256 + threadIdx.x) * 4;
  const float* src; ushort* dst; int off;
  if (i < 1048576) { src = gus; dst = gus_bf; off = i; }
  else if (i < 1572864) { src = wdown; dst = wdown_bf; off = i - 1048576; }
  else { src = wfuse; dst = wfuse_bf; off = i - 1572864; }
  float4 v = *(const float4*)&src[off];
  ushort4 o = {f2bf(v.x), f2bf(v.y), f2bf(v.z), f2bf(v.w)};
  *(ushort4*)&dst[off] = o;
}

// ---------------- bf16 MFMA GEMM, fp32 C: C[M][N] = A[M][K] * Bt[N][K]^T ----
__global__ __launch_bounds__(256) void mfma_gemm(const ushort* __restrict__ A,
                                                 const ushort* __restrict__ Bt,
                                                 float* __restrict__ C, int N,
                                                 int K) {
  int tid = threadIdx.x;
  int wv = tid >> 6, lane = tid & 63;
  int quad = lane >> 4, m16 = lane & 15;
  int nb = blockIdx.x * 64, mb = blockIdx.y * 64;
  const ushort* Ap = A + (size_t)(mb + wv * 16 + m16) * K + quad * 8;
  const ushort* Bp = Bt + (size_t)(nb + m16) * K + quad * 8;
  f32x4 ac0 = {0.f, 0.f, 0.f, 0.f}, ac1 = ac0, ac2 = ac0, ac3 = ac0;
#pragma unroll 2
  for (int k0 = 0; k0 < K; k0 += 32) {
    bf16x8 af = *(const bf16x8*)(Ap + k0);
    bf16x8 b0 = *(const bf16x8*)(Bp + k0);
    bf16x8 b1 = *(const bf16x8*)(Bp + (size_t)16 * K + k0);
    bf16x8 b2 = *(const bf16x8*)(Bp + (size_t)32 * K + k0);
    bf16x8 b3 = *(const bf16x8*)(Bp + (size_t)48 * K + k0);
    ac0 = __builtin_amdgcn_mfma_f32_16x16x32_bf16(af, b0, ac0, 0, 0, 0);
    ac1 = __builtin_amdgcn_mfma_f32_16x16x32_bf16(af, b1, ac1, 0, 0, 0);
    ac2 = __builtin_amdgcn_mfma_f32_16x16x32_bf16(af, b2, ac2, 0, 0, 0);
    ac3 = __builtin_amdgcn_mfma_f32_16x16x32_bf16(af, b3, ac3, 0, 0, 0);
  }
  int row = mb + wv * 16 + quad * 4;
  f32x4 accs[4] = {ac0, ac1, ac2, ac3};
#pragma unroll
  for (int nt = 0; nt < 4; ++nt)
#pragma unroll
    for (int r = 0; r < 4; ++r)
      C[(size_t)(row + r) * N + nb + nt * 16 + m16] = accs[nt][r];
}

// ---------------- gus GEMM -> Zt with raw-reshape scatter -------------------
// E[p][c] (p=0..1024, c=0..512); flat f = p*512+c maps to channel k=f>>10,
// pos=f&1023 (reference's .reshape). Zt[pos][k] = bf16(E[p][c]).
__global__ __launch_bounds__(256) void mfma_gus(const ushort* __restrict__ A,
                                                const ushort* __restrict__ Bt,
                                                ushort* __restrict__ Zt) {
  const int K = 1024;
  int tid = threadIdx.x;
  int wv = tid >> 6, lane = tid & 63;
  int quad = lane >> 4, m16 = lane & 15;
  int nb = blockIdx.x * 64, mb = blockIdx.y * 64;
  const ushort* Ap = A + (size_t)(mb + wv * 16 + m16) * K + quad * 8;
  const ushort* Bp = Bt + (size_t)(nb + m16) * K + quad * 8;
  f32x4 ac0 = {0.f, 0.f, 0.f, 0.f}, ac1 = ac0, ac2 = ac0, ac3 = ac0;
#pragma unroll 2
  for (int k0 = 0; k0 < K; k0 += 32) {
    bf16x8 af = *(const bf16x8*)(Ap + k0);
    bf16x8 b0 = *(const bf16x8*)(Bp + k0);
    bf16x8 b1 = *(const bf16x8*)(Bp + (size_t)16 * K + k0);
    bf16x8 b2 = *(const bf16x8*)(Bp + (size_t)32 * K + k0);
    bf16x8 b3 = *(const bf16x8*)(Bp + (size_t)48 * K + k0);
    ac0 = __builtin_amdgcn_mfma_f32_16x16x32_bf16(af, b0, ac0, 0, 0, 0);
    ac1 = __builtin_amdgcn_mfma_f32_16x16x32_bf16(af, b1, ac1, 0, 0, 0);
    ac2 = __builtin_amdgcn_mfma_f32_16x16x32_bf16(af, b2, ac2, 0, 0, 0);
    ac3 = __builtin_amdgcn_mfma_f32_16x16x32_bf16(af, b3, ac3, 0, 0, 0);
  }
  int row = mb + wv * 16 + quad * 4;
  f32x4 accs[4] = {ac0, ac1, ac2, ac3};
#pragma unroll
  for (int nt = 0; nt < 4; ++nt) {
    int c = nb + nt * 16 + m16;
#pragma unroll
    for (int r = 0; r < 4; ++r) {
      int p = row + r;
      int pos = ((p & 1) << 9) + c;   // (p*512+c) & 1023
      int kk = p >> 1;                // (p*512+c) >> 10
      Zt[(size_t)pos * 1024 + kk] = f2bf(accs[nt][r]);
    }
  }
}

// ---------------- CSA fused -> Zt second half (raw-reshape scatter) ---------
__global__ __launch_bounds__(256) void csa_fused2(const float* __restrict__ sigt,
                                                  const float* __restrict__ orlt,
                                                  ushort* __restrict__ Zt) {
  __shared__ float red[8];
  __shared__ float a9s[9];
  int n = blockIdx.x, tid = threadIdx.x;
  int ny = n >> 5, nx = n & 31;
  int c2 = tid * 2;
  float2 ctr = *(const float2*)&sigt[n * 512 + c2];
  float part[9];
#pragma unroll
  for (int u = 0; u < 3; ++u) {
    int yy = ny + u - 1;
#pragma unroll
    for (int v = 0; v < 3; ++v) {
      int xx = nx + v - 1;
      float2 nb = {0.f, 0.f};
      if ((unsigned)yy < 32u && (unsigned)xx < 32u)
        nb = *(const float2*)&sigt[(yy * 32 + xx) * 512 + c2];
      part[u * 3 + v] = ctr.x * nb.x + ctr.y * nb.y;
    }
  }
  float a[9];
#pragma unroll
  for (int t = 0; t < 9; ++t) a[t] = breduce_sum(part[t], red) * (1.f / 512.f);
  float mx = a[0];
#pragma unroll
  for (int t = 1; t < 9; ++t) mx = fmaxf(mx, a[t]);
  float sum = 0.f;
#pragma unroll
  for (int t = 0; t < 9; ++t) { a[t] = expf(a[t] - mx); sum += a[t]; }
  if (tid == 0) {
    float inv = 1.f / sum;
#pragma unroll
    for (int t = 0; t < 9; ++t) a9s[t] = a[t] * inv;
  }
  __syncthreads();
  float2 acc = {0.f, 0.f};
#pragma unroll
  for (int u = 0; u < 3; ++u) {
    int yy = ny + u - 1;
#pragma unroll
    for (int v = 0; v < 3; ++v) {
      int xx = nx + v - 1;
      if ((unsigned)yy < 32u && (unsigned)xx < 32u) {
        float w = a9s[u * 3 + v];
        float2 ov = *(const float2*)&orlt[(yy * 32 + xx) * 512 + c2];
        acc.x += w * ov.x;
        acc.y += w * ov.y;
      }
    }
  }
  // outc[n][c]: flat f = n*512+c -> Z channel 512 + (f>>10), pos f&1023
  int kk = 512 + (n >> 1);
  int pos0 = ((n & 1) << 9) + c2;
  Zt[(size_t)pos0 * 1024 + kk] = f2bf(acc.x);
  Zt[(size_t)(pos0 + 1) * 1024 + kk] = f2bf(acc.y);
}

// ---------------- InstanceNorm + LeakyReLU -> transposed bf16 into Zt2 ------
__global__ __launch_bounds__(256) void norm_down(const float* __restrict__ raw,
                                                 ushort* __restrict__ Zt2) {
  __shared__ float red[8];
  int c = blockIdx.x, tid = threadIdx.x;
  float v[4];
  float s = 0.f, ss = 0.f;
#pragma unroll
  for (int r = 0; r < 4; ++r) {
    v[r] = raw[c * 1024 + tid + r * 256];
    s += v[r];
    ss += v[r] * v[r];
  }
  breduce2(s, ss, red);
  float mean = s * (1.f / 1024.f);
  float var = ss * (1.f / 1024.f) - mean * mean;
  float inv = rsqrtf(var + EPSN);
#pragma unroll
  for (int r = 0; r < 4; ++r) {
    float t = (v[r] - mean) * inv;
    t = t >= 0.f ? t : 0.2f * t;
    Zt2[(size_t)(tid + r * 256) * 1024 + c] = f2bf(t);
  }
}

// ---------------- final InstanceNorm + LeakyReLU (fp32 out) -----------------
__global__ __launch_bounds__(256) void norm_leaky(const float* __restrict__ raw,
                                                  float* __restrict__ out) {
  __shared__ float red[8];
  int c = blockIdx.x, tid = threadIdx.x;
  float v[4];
  float s = 0.f, ss = 0.f;
#pragma unroll
  for (int r = 0; r < 4; ++r) {
    v[r] = raw[c * 1024 + tid + r * 256];
    s += v[r];
    ss += v[r] * v[r];
  }
  breduce2(s, ss, red);
  float mean = s * (1.f / 1024.f);
  float var = ss * (1.f / 1024.f) - mean * mean;
  float inv = rsqrtf(var + EPSN);
#pragma unroll
  for (int r = 0; r < 4; ++r) {
    float t = (v[r] - mean) * inv;
    out[c * 1024 + tid + r * 256] = t >= 0.f ? t : 0.2f * t;
  }
}

// ---------------- host launch ------------------------------------------------
extern "C" void kernel_launch(void* const* d_in, const int* in_sizes, int n_in,
                              void* d_out, int out_size, void* d_ws, size_t ws_size,
                              hipStream_t stream) {
  const float* x = (const float*)d_in[0];
  const float* gus = (const float*)d_in[1];
  const float* w3 = (const float*)d_in[2];
  const float* b3 = (const float*)d_in[3];
  const float* w5 = (const float*)d_in[4];
  const float* b5 = (const float*)d_in[5];
  const float* w7 = (const float*)d_in[6];
  const float* b7 = (const float*)d_in[7];
  const float* wfc = (const float*)d_in[8];
  const float* bfc = (const float*)d_in[9];
  const float* w0 = (const float*)d_in[10];
  const float* b0 = (const float*)d_in[11];
  const float* w1 = (const float*)d_in[12];
  const float* b1 = (const float*)d_in[13];
  const float* w2 = (const float*)d_in[14];
  const float* b2 = (const float*)d_in[15];
  const float* wdown = (const float*)d_in[16];
  const float* wfuse = (const float*)d_in[17];

  float* ws = (float*)d_ws;
  float* feas = ws;                      // 1572864 (dead after blend_fc)
  ushort* resd = (ushort*)feas;          // 1048576 fl (written after blend)
  float* raw = feas + 1048576;           // 524288 fl (GEMM fp32 outputs)
  float* bmean = ws + 1572864;           // 1536
  float* invn = bmean + 1536;            // 256
  float* res = invn + 256;               // 524288
  float* Zt2f = res + 524288;            // 524288 fl (fuse GEMM input, bf16)
  ushort* Zt2 = (ushort*)Zt2f;
  float* T = Zt2f + 524288;              // 2097152
  float* Apart = T;                      // 1048576 fl (dead before T written)
  ushort* Zt = (ushort*)T;               // 524288 fl (written after tcomb2)
  float* orlt = T + 2097152;             // 524288
  float* sigt = orlt + 524288;           // 524288
  ushort* orlT = (ushort*)(sigt + 524288);        // 262144 fl
  ushort* attnT = (ushort*)(sigt + 786432);       // 32768 fl
  ushort* gus_bf = (ushort*)(sigt + 819200);      // 524288 fl
  ushort* wdown_bf = (ushort*)(sigt + 1343488);   // 262144 fl
  ushort* wfuse_bf = (ushort*)(sigt + 1605632);   // 262144 fl

  conv_bf3<<<2048, 256, 0, stream>>>(gus, wdown, wfuse, gus_bf, wdown_bf, wfuse_bf);
  sk_all2<<<256, 256, 0, stream>>>(x, w3, b3, w5, b5, w7, b7, feas, bmean);
  blend_fc<<<dim3(32, 16), 256, 0, stream>>>(feas, bmean, wfc, bfc, w0, b0, w1,
                                             b1, w2, b2, res, Zt2);
  pack_resd<<<8192, 256, 0, stream>>>(res, resd);
  gram_part2<<<dim3(4, 4, 16), 256, 0, stream>>>(res, Apart);
  diag_norm<<<1, 256, 0, stream>>>(Apart, invn);
  attn_soft2<<<256, 256, 0, stream>>>(Apart, invn, attnT);
  mfma_tconv<<<dim3(8, 4, 16), 256, 0, stream>>>(attnT, resd, T);
  tcomb2<<<dim3(32, 16), 256, 0, stream>>>(T, orlt, sigt, orlT);
  // gus einsum -> Zt[:, 0:512] bf16 via raw-reshape scatter
  mfma_gus<<<dim3(8, 16), 256, 0, stream>>>(gus_bf, orlT, Zt);
  csa_fused2<<<1024, 256, 0, stream>>>(sigt, orlt, Zt);  // -> Zt[:, 512:1024]
  // down conv: M=512(o), N=1024(p), K=1024
  mfma_gemm<<<dim3(16, 8), 256, 0, stream>>>(wdown_bf, Zt, raw, 1024, 1024);
  norm_down<<<512, 256, 0, stream>>>(raw, Zt2);          // -> Zt2[:, 0:512]
  mfma_gemm<<<dim3(16, 8), 256, 0, stream>>>(wfuse_bf, Zt2, raw, 1024, 1024);
  norm_leaky<<<512, 256, 0, stream>>>(raw, (float*)d_out);
}

// Round 9
// 274.292 us; speedup vs baseline: 3.3674x; 1.0207x over previous
//
#include <hip/hip_runtime.h>
#include <math.h>

#define EPSN 1e-5f

typedef __attribute__((ext_vector_type(8))) short bf16x8;
typedef __attribute__((ext_vector_type(4))) float f32x4;

__device__ __forceinline__ ushort f2bf(float f) {
  unsigned u = __float_as_uint(f);
  unsigned r = (u + 0x7fff + ((u >> 16) & 1)) >> 16;
  return (ushort)r;
}

// ---------------- block-wide reductions (blockDim.x == 256, 4 waves) --------
__device__ __forceinline__ void breduce2(float& a, float& b, float* lds) {
#pragma unroll
  for (int o = 32; o > 0; o >>= 1) {
    a += __shfl_down(a, o);
    b += __shfl_down(b, o);
  }
  int lane = threadIdx.x & 63, wid = threadIdx.x >> 6;
  __syncthreads();
  if (lane == 0) { lds[wid] = a; lds[4 + wid] = b; }
  __syncthreads();
  a = lds[0] + lds[1] + lds[2] + lds[3];
  b = lds[4] + lds[5] + lds[6] + lds[7];
}

__device__ __forceinline__ float breduce_sum(float v, float* lds) {
#pragma unroll
  for (int o = 32; o > 0; o >>= 1) v += __shfl_down(v, o);
  int lane = threadIdx.x & 63, wid = threadIdx.x >> 6;
  __syncthreads();
  if (lane == 0) lds[wid] = v;
  __syncthreads();
  return lds[0] + lds[1] + lds[2] + lds[3];
}

__device__ __forceinline__ float breduce_max(float v, float* lds) {
#pragma unroll
  for (int o = 32; o > 0; o >>= 1) v = fmaxf(v, __shfl_down(v, o));
  int lane = threadIdx.x & 63, wid = threadIdx.x >> 6;
  __syncthreads();
  if (lane == 0) lds[wid] = v;
  __syncthreads();
  return fmaxf(fmaxf(lds[0], lds[1]), fmaxf(lds[2], lds[3]));
}

// ---------------- SKConv v3: 8-ch staging, wave-specialized, 4 barriers -----
// 256 blocks (2 out-ch each). Waves 0-1 -> ch0, waves 2-3 -> ch1.
// Thread tile: 2 rows x 4 cols. Per ic: 24 LDS seg reads feed 664 FMAs.
__device__ __forceinline__ void finish3(float a[2][4], float bv, int m, int c,
                                        int y0, int xb, float* feas,
                                        float* bmean, float* red) {
  int tid = threadIdx.x, lane = tid & 63, wid = tid >> 6, pr = wid >> 1;
  float s = 0.f, ss = 0.f;
#pragma unroll
  for (int rr = 0; rr < 2; ++rr)
#pragma unroll
    for (int px = 0; px < 4; ++px) {
      a[rr][px] += bv;
      s += a[rr][px];
      ss += a[rr][px] * a[rr][px];
    }
#pragma unroll
  for (int o = 32; o > 0; o >>= 1) {
    s += __shfl_down(s, o);
    ss += __shfl_down(ss, o);
  }
  __syncthreads();
  if (lane == 0) { red[wid] = s; red[4 + wid] = ss; }
  __syncthreads();
  s = red[2 * pr] + red[2 * pr + 1];
  ss = red[4 + 2 * pr] + red[4 + 2 * pr + 1];
  float mean = s * (1.f / 1024.f);
  float var = ss * (1.f / 1024.f) - mean * mean;
  float inv = rsqrtf(var + EPSN);
  float rs = 0.f;
#pragma unroll
  for (int rr = 0; rr < 2; ++rr) {
    float4 o4;
    float* ov = (float*)&o4;
#pragma unroll
    for (int px = 0; px < 4; ++px) {
      float v = (a[rr][px] - mean) * inv;
      v = v > 0.f ? v : 0.f;
      ov[px] = v;
      rs += v;
    }
    *(float4*)&feas[(size_t)(m * 512 + c) * 1024 + (y0 + rr) * 32 + xb] = o4;
  }
#pragma unroll
  for (int o = 32; o > 0; o >>= 1) rs += __shfl_down(rs, o);
  __syncthreads();
  if (lane == 0) red[wid] = rs;
  __syncthreads();
  if ((tid & 127) == 0)
    bmean[m * 512 + c] = (red[2 * pr] + red[2 * pr + 1]) * (1.f / 1024.f);
}

__global__ __launch_bounds__(256) void sk_all3(
    const float* __restrict__ x, const float* __restrict__ w3,
    const float* __restrict__ b3, const float* __restrict__ w5,
    const float* __restrict__ b5, const float* __restrict__ w7,
    const float* __restrict__ b7, float* __restrict__ feas,
    float* __restrict__ bmean) {
  __shared__ float chanp[8][1408];     // 8 ch x (32 rows x stride 44); x at cols 3..34
  __shared__ float ws7p[2 * 16 * 56];  // [ch][ic][7 rows x 8]
  __shared__ float ws5p[2 * 16 * 40];  // [ch][ic][5 rows x 8]
  __shared__ float ws3p[2 * 16 * 12];  // [ch][ic][3 rows x 4]
  __shared__ float red[8];
  int c0 = blockIdx.x * 2, tid = threadIdx.x, g = c0 >> 4;
  for (int i = tid; i < 8 * 1408; i += 256) ((float*)chanp)[i] = 0.f;
  for (int i = tid; i < 1792; i += 256) {
    int cw = i / 896, rem = i - cw * 896;
    int ic = rem / 56, t = rem - ic * 56, r = t >> 3, k = t & 7;
    ws7p[i] = (r < 7 && k < 7) ? w7[(c0 + cw) * 784 + ic * 49 + r * 7 + k] : 0.f;
  }
  for (int i = tid; i < 1280; i += 256) {
    int cw = i / 640, rem = i - cw * 640;
    int ic = rem / 40, t = rem - ic * 40, r = t >> 3, k = t & 7;
    ws5p[i] = (r < 5 && k < 5) ? w5[(c0 + cw) * 400 + ic * 25 + r * 5 + k] : 0.f;
  }
  for (int i = tid; i < 384; i += 256) {
    int cw = i / 192, rem = i - cw * 192;
    int ic = rem / 12, t = rem - ic * 12, r = t >> 2, k = t & 3;
    ws3p[i] = (k < 3) ? w3[(c0 + cw) * 144 + ic * 9 + r * 3 + k] : 0.f;
  }
  int ch = tid >> 7;            // wave pair -> output channel
  int idx = tid & 127;
  int y0 = (idx >> 3) * 2, xb = (idx & 7) * 4;
  float a7[2][4] = {}, a5[2][4] = {}, a3[2][4] = {};
  int srow = tid >> 3, scol = (tid & 7) * 4;
  for (int half = 0; half < 2; ++half) {
    __syncthreads();  // protects chanp reuse (and covers init/weight loads)
#pragma unroll
    for (int j = 0; j < 8; ++j) {
      float4 xv = *(const float4*)&x[(size_t)(g * 16 + half * 8 + j) * 1024 + tid * 4];
      float* d = &chanp[j][srow * 44 + 3 + scol];
      d[0] = xv.x; d[1] = xv.y; d[2] = xv.z; d[3] = xv.w;
    }
    __syncthreads();
    for (int cc = 0; cc < 8; ++cc) {
      int ic = half * 8 + cc;
      float sg[8][10];
#pragma unroll
      for (int s = 0; s < 8; ++s) {
        int r = y0 - 3 + s;
        if ((unsigned)r < 32u) {
          const float* rp = &chanp[cc][r * 44 + xb];
          float4 q0 = *(const float4*)rp;
          float4 q1 = *(const float4*)(rp + 4);
          float2 q2 = *(const float2*)(rp + 8);
          sg[s][0] = q0.x; sg[s][1] = q0.y; sg[s][2] = q0.z; sg[s][3] = q0.w;
          sg[s][4] = q1.x; sg[s][5] = q1.y; sg[s][6] = q1.z; sg[s][7] = q1.w;
          sg[s][8] = q2.x; sg[s][9] = q2.y;
        } else {
#pragma unroll
          for (int t = 0; t < 10; ++t) sg[s][t] = 0.f;
        }
      }
      const float* W7 = &ws7p[ch * 896 + ic * 56];
      const float* W5 = &ws5p[ch * 640 + ic * 40];
      const float* W3 = &ws3p[ch * 192 + ic * 12];
#pragma unroll
      for (int dy = 0; dy < 7; ++dy) {
        float4 wa = *(const float4*)(W7 + dy * 8);
        float4 wb = *(const float4*)(W7 + dy * 8 + 4);
        float wv[7] = {wa.x, wa.y, wa.z, wa.w, wb.x, wb.y, wb.z};
#pragma unroll
        for (int kx = 0; kx < 7; ++kx)
#pragma unroll
          for (int px = 0; px < 4; ++px) {
            a7[0][px] += sg[dy][px + kx] * wv[kx];
            a7[1][px] += sg[dy + 1][px + kx] * wv[kx];
          }
      }
#pragma unroll
      for (int d5 = 0; d5 < 5; ++d5) {
        float4 va = *(const float4*)(W5 + d5 * 8);
        float wv[5] = {va.x, va.y, va.z, va.w, W5[d5 * 8 + 4]};
#pragma unroll
        for (int kx = 0; kx < 5; ++kx)
#pragma unroll
          for (int px = 0; px < 4; ++px) {
            a5[0][px] += sg[d5 + 1][px + kx + 1] * wv[kx];
            a5[1][px] += sg[d5 + 2][px + kx + 1] * wv[kx];
          }
      }
#pragma unroll
      for (int d3 = 0; d3 < 3; ++d3) {
        float4 ta = *(const float4*)(W3 + d3 * 4);
        float wv[3] = {ta.x, ta.y, ta.z};
#pragma unroll
        for (int kx = 0; kx < 3; ++kx)
#pragma unroll
          for (int px = 0; px < 4; ++px) {
            a3[0][px] += sg[d3 + 2][px + kx + 2] * wv[kx];
            a3[1][px] += sg[d3 + 3][px + kx + 2] * wv[kx];
          }
      }
    }
  }
  int c = c0 + ch;
  finish3(a3, b3[c], 0, c, y0, xb, feas, bmean, red);
  finish3(a5, b5[c], 1, c, y0, xb, feas, bmean, red);
  finish3(a7, b7[c], 2, c, y0, xb, feas, bmean, red);
}

// ---------------- blend + FC-attention; writes res, Zt2 res-half, resd ------
__global__ __launch_bounds__(256) void blend_fc(
    const float* __restrict__ feas, const float* __restrict__ bmean,
    const float* __restrict__ wfc, const float* __restrict__ bfc,
    const float* __restrict__ w0, const float* __restrict__ b0,
    const float* __restrict__ w1, const float* __restrict__ b1,
    const float* __restrict__ w2, const float* __restrict__ b2,
    float* __restrict__ res, ushort* __restrict__ Zt2,
    ushort* __restrict__ resd) {
  __shared__ float sfea[512];
  __shared__ float zpart[8][32];
  __shared__ float zz[32];
  __shared__ float lv[3][32];
  __shared__ float attb[3][32];
  __shared__ float tile[32][33];
  int tid = threadIdx.x;
  int pb = blockIdx.x * 32, cb = blockIdx.y * 32;
  for (int c = tid; c < 512; c += 256)
    sfea[c] = bmean[c] + bmean[512 + c] + bmean[1024 + c];
  __syncthreads();
  {
    int j = tid & 31, seg = tid >> 5;
    float p = 0.f;
    for (int c = seg * 64; c < seg * 64 + 64; ++c) p += sfea[c] * wfc[j * 512 + c];
    zpart[seg][j] = p;
  }
  __syncthreads();
  if (tid < 32) {
    float d = bfc[tid];
#pragma unroll
    for (int s = 0; s < 8; ++s) d += zpart[s][tid];
    zz[tid] = d;
  }
  __syncthreads();
  if (tid < 96) {
    int m = tid >> 5, cl = tid & 31;
    const float* wm = (m == 0) ? w0 : (m == 1) ? w1 : w2;
    const float* bm = (m == 0) ? b0 : (m == 1) ? b1 : b2;
    float l = bm[cb + cl];
#pragma unroll
    for (int j = 0; j < 32; ++j) l += zz[j] * wm[(cb + cl) * 32 + j];
    lv[m][cl] = l;
  }
  __syncthreads();
  if (tid < 32) {
    float l0 = lv[0][tid], l1 = lv[1][tid], l2 = lv[2][tid];
    float mx = fmaxf(l0, fmaxf(l1, l2));
    float e0 = expf(l0 - mx), e1 = expf(l1 - mx), e2 = expf(l2 - mx);
    float inv = 1.f / (e0 + e1 + e2);
    attb[0][tid] = e0 * inv; attb[1][tid] = e1 * inv; attb[2][tid] = e2 * inv;
  }
  __syncthreads();
  int tx = tid & 31, ty = tid >> 5;
  int pos = pb + tx;
  int yy = pos >> 5, xx = pos & 31;
  int ki0 = (yy + 1) & 1, pi0 = (yy + 1 - ki0) >> 1;
  int kj0 = (xx + 1) & 1, pj0 = (xx + 1 - kj0) >> 1;
#pragma unroll
  for (int r = 0; r < 4; ++r) {
    int cl = ty + r * 8;
    int c = cb + cl;
    float v = feas[c * 1024 + pos] * attb[0][cl] +
              feas[(512 + c) * 1024 + pos] * attb[1][cl] +
              feas[(1024 + c) * 1024 + pos] * attb[2][cl];
    res[c * 1024 + pos] = v;
    tile[cl][tx] = v;
    ushort bv16 = f2bf(v);
#pragma unroll
    for (int ai = 0; ai < 2; ++ai) {
      int ki = ki0 + 2 * ai, pi = pi0 - ai;
      if ((unsigned)pi >= 16u) continue;
#pragma unroll
      for (int aj = 0; aj < 2; ++aj) {
        int kj = kj0 + 2 * aj, pj = pj0 - aj;
        if ((unsigned)pj >= 16u) continue;
        resd[((size_t)(ki * 4 + kj) << 17) + (size_t)c * 256 + pi * 16 + pj] = bv16;
      }
    }
  }
  __syncthreads();
#pragma unroll
  for (int r = 0; r < 4; ++r) {
    int pl = ty + r * 8;
    Zt2[(size_t)(pb + pl) * 1024 + 512 + cb + tx] = f2bf(tile[tx][pl]);
  }
}

// ---------------- Gram split-K partials with fused 2x2 pooling --------------
__global__ __launch_bounds__(256) void gram_part2(const float* __restrict__ res,
                                                  float* __restrict__ Apart) {
  __shared__ float ch[4][324];
  int tid = threadIdx.x;
  int qb = blockIdx.x * 64, pb = blockIdx.y * 64;
  int kc = blockIdx.z;
  int tx = tid & 15, ty = tid >> 4;
  for (int i = tid; i < 4 * 324; i += 256) ((float*)ch)[i] = 0.f;
  int pi = (pb + ty * 4) >> 4, pj = (pb + ty * 4) & 15;
  int qi = (qb + tx * 4) >> 4, qj = (qb + tx * 4) & 15;
  int lane = tid & 63, wv = tid >> 6;
  int sr = lane >> 2, sc = (lane & 3) * 4;
  float acc[4][4] = {};
  for (int c0 = kc * 32; c0 < kc * 32 + 32; c0 += 4) {
    __syncthreads();
    {
      const float* src = res + (size_t)(c0 + wv) * 1024 + (2 * sr) * 32 + 2 * sc;
      float4 r0a = *(const float4*)src;
      float4 r0b = *(const float4*)(src + 4);
      float4 r1a = *(const float4*)(src + 32);
      float4 r1b = *(const float4*)(src + 36);
      float* dst = &ch[wv][(sr + 1) * 18 + sc + 1];
      dst[0] = 0.25f * (r0a.x + r0a.y + r1a.x + r1a.y);
      dst[1] = 0.25f * (r0a.z + r0a.w + r1a.z + r1a.w);
      dst[2] = 0.25f * (r0b.x + r0b.y + r1b.x + r1b.y);
      dst[3] = 0.25f * (r0b.z + r0b.w + r1b.z + r1b.w);
    }
    __syncthreads();
#pragma unroll
    for (int cc = 0; cc < 4; ++cc) {
      float ps[3][6], qs[3][6];
#pragma unroll
      for (int u = 0; u < 3; ++u) {
        const float* pr = &ch[cc][(pi + u) * 18 + pj];
        const float* qr = &ch[cc][(qi + u) * 18 + qj];
#pragma unroll
        for (int t = 0; t < 6; ++t) { ps[u][t] = pr[t]; qs[u][t] = qr[t]; }
      }
#pragma unroll
      for (int u = 0; u < 3; ++u)
#pragma unroll
        for (int v = 0; v < 3; ++v)
#pragma unroll
          for (int i = 0; i < 4; ++i)
#pragma unroll
            for (int j = 0; j < 4; ++j)
              acc[i][j] += ps[u][v + i] * qs[u][v + j];
    }
  }
#pragma unroll
  for (int i = 0; i < 4; ++i) {
    float4 o4 = {acc[i][0], acc[i][1], acc[i][2], acc[i][3]};
    *(float4*)&Apart[(size_t)kc * 65536 + (pb + ty * 4 + i) * 256 + qb + tx * 4] = o4;
  }
}

// ---------------- diagonal norms (one block) --------------------------------
__global__ void diag_norm(const float* __restrict__ Apart, float* __restrict__ invn) {
  int t = threadIdx.x;
  float d = 0.f;
#pragma unroll
  for (int k = 0; k < 16; ++k) d += Apart[(size_t)k * 65536 + t * 257];
  float nrm = sqrtf(fmaxf(d, 0.f));
  invn[t] = 10.f / fmaxf(nrm, 1e-4f);
}

// ---------------- softmax (+16-way reduce, via Gram symmetry) -> attnT bf16 -
__global__ __launch_bounds__(256) void attn_soft2(const float* __restrict__ Apart,
                                                  const float* __restrict__ invn,
                                                  ushort* __restrict__ attnT) {
  __shared__ float red[8];
  int q = blockIdx.x, t = threadIdx.x;
  float s = 0.f;
#pragma unroll
  for (int k = 0; k < 16; ++k) s += Apart[(size_t)k * 65536 + q * 256 + t];
  float v = s * invn[t];
  float mx = breduce_max(v, red);
  float e = expf(v - mx);
  float sm = breduce_sum(e, red);
  attnT[q * 256 + t] = f2bf(e / sm);
}

// ---------------- tconv: 16-batch bf16 MFMA GEMM ----------------------------
__global__ __launch_bounds__(256) void mfma_tconv(const ushort* __restrict__ attnT,
                                                  const ushort* __restrict__ resd,
                                                  float* __restrict__ T) {
  int tid = threadIdx.x;
  int wv = tid >> 6, lane = tid & 63;
  int quad = lane >> 4, m16 = lane & 15;
  int nb = blockIdx.x * 64, qb = blockIdx.y * 64;
  int b = blockIdx.z;
  const ushort* Ap = attnT + (size_t)(qb + wv * 16 + m16) * 256 + quad * 8;
  const ushort* Bp = resd + (size_t)b * 131072 + (size_t)(nb + m16) * 256 + quad * 8;
  f32x4 ac0 = {0.f, 0.f, 0.f, 0.f}, ac1 = ac0, ac2 = ac0, ac3 = ac0;
#pragma unroll 2
  for (int k0 = 0; k0 < 256; k0 += 32) {
    bf16x8 af = *(const bf16x8*)(Ap + k0);
    bf16x8 b0 = *(const bf16x8*)(Bp + k0);
    bf16x8 b1 = *(const bf16x8*)(Bp + 16 * 256 + k0);
    bf16x8 b2 = *(const bf16x8*)(Bp + 32 * 256 + k0);
    bf16x8 b3 = *(const bf16x8*)(Bp + 48 * 256 + k0);
    ac0 = __builtin_amdgcn_mfma_f32_16x16x32_bf16(af, b0, ac0, 0, 0, 0);
    ac1 = __builtin_amdgcn_mfma_f32_16x16x32_bf16(af, b1, ac1, 0, 0, 0);
    ac2 = __builtin_amdgcn_mfma_f32_16x16x32_bf16(af, b2, ac2, 0, 0, 0);
    ac3 = __builtin_amdgcn_mfma_f32_16x16x32_bf16(af, b3, ac3, 0, 0, 0);
  }
  int row = qb + wv * 16 + quad * 4;
  float* Cb = T + (size_t)b * 131072;
  f32x4 accs[4] = {ac0, ac1, ac2, ac3};
#pragma unroll
  for (int nt = 0; nt < 4; ++nt)
#pragma unroll
    for (int r = 0; r < 4; ++r)
      Cb[(size_t)(row + r) * 512 + nb + nt * 16 + m16] = accs[nt][r];
}

// ---------------- combine taps -> orlt, sigt, orlT bf16 (tiled) -------------
__global__ __launch_bounds__(256) void tcomb2(const float* __restrict__ T,
                                              float* __restrict__ orlt,
                                              float* __restrict__ sigt,
                                              ushort* __restrict__ orlT) {
  __shared__ float tl[32][33];
  int nb = blockIdx.x * 32, cb = blockIdx.y * 32;
  int tx = threadIdx.x & 31, ty = threadIdx.x >> 5;
#pragma unroll
  for (int r = 0; r < 4; ++r) {
    int nl = ty + r * 8;
    int n = nb + nl, c = cb + tx;
    int y = n >> 5, x = n & 31;
    int i0 = (y + 1) >> 1, ki0 = (y + 1) & 1;
    int j0 = (x + 1) >> 1, kj0 = (x + 1) & 1;
    float sum = 0.f;
#pragma unroll
    for (int iy = 0; iy < 2; ++iy) {
      int i = i0 - iy, ki = ki0 + 2 * iy;
      if ((unsigned)i >= 16u) continue;
#pragma unroll
      for (int ix = 0; ix < 2; ++ix) {
        int j = j0 - ix, kj = kj0 + 2 * ix;
        if ((unsigned)j >= 16u) continue;
        sum += T[((ki * 4 + kj) * 256 + i * 16 + j) * 512 + c];
      }
    }
    float v = sum * 0.25f;
    orlt[n * 512 + c] = v;
    sigt[n * 512 + c] = 1.f / (1.f + expf(-v));
    tl[nl][tx] = v;
  }
  __syncthreads();
#pragma unroll
  for (int r = 0; r < 4; ++r) {
    int cl = ty + r * 8;
    orlT[(size_t)(cb + cl) * 1024 + nb + tx] = f2bf(tl[tx][cl]);
  }
}

// ---------------- fp32 -> bf16 for gus + both weights (one kernel) ----------
__global__ void conv_bf3(const float* __restrict__ gus,
                         const float* __restrict__ wdown,
                         const float* __restrict__ wfuse,
                         ushort* __restrict__ gus_bf,
                         ushort* __restrict__ wdown_bf,
                         ushort* __restrict__ wfuse_bf) {
  int i = (blockIdx.x * 256 + threadIdx.x) * 4;
  const float* src; ushort* dst; int off;
  if (i < 1048576) { src = gus; dst = gus_bf; off = i; }
  else if (i < 1572864) { src = wdown; dst = wdown_bf; off = i - 1048576; }
  else { src = wfuse; dst = wfuse_bf; off = i - 1572864; }
  float4 v = *(const float4*)&src[off];
  ushort4 o = {f2bf(v.x), f2bf(v.y), f2bf(v.z), f2bf(v.w)};
  *(ushort4*)&dst[off] = o;
}

// ---------------- bf16 MFMA GEMM, fp32 C: C[M][N] = A[M][K] * Bt[N][K]^T ----
__global__ __launch_bounds__(256) void mfma_gemm(const ushort* __restrict__ A,
                                                 const ushort* __restrict__ Bt,
                                                 float* __restrict__ C, int N,
                                                 int K) {
  int tid = threadIdx.x;
  int wv = tid >> 6, lane = tid & 63;
  int quad = lane >> 4, m16 = lane & 15;
  int nb = blockIdx.x * 64, mb = blockIdx.y * 64;
  const ushort* Ap = A + (size_t)(mb + wv * 16 + m16) * K + quad * 8;
  const ushort* Bp = Bt + (size_t)(nb + m16) * K + quad * 8;
  f32x4 ac0 = {0.f, 0.f, 0.f, 0.f}, ac1 = ac0, ac2 = ac0, ac3 = ac0;
#pragma unroll 2
  for (int k0 = 0; k0 < K; k0 += 32) {
    bf16x8 af = *(const bf16x8*)(Ap + k0);
    bf16x8 b0 = *(const bf16x8*)(Bp + k0);
    bf16x8 b1 = *(const bf16x8*)(Bp + (size_t)16 * K + k0);
    bf16x8 b2 = *(const bf16x8*)(Bp + (size_t)32 * K + k0);
    bf16x8 b3 = *(const bf16x8*)(Bp + (size_t)48 * K + k0);
    ac0 = __builtin_amdgcn_mfma_f32_16x16x32_bf16(af, b0, ac0, 0, 0, 0);
    ac1 = __builtin_amdgcn_mfma_f32_16x16x32_bf16(af, b1, ac1, 0, 0, 0);
    ac2 = __builtin_amdgcn_mfma_f32_16x16x32_bf16(af, b2, ac2, 0, 0, 0);
    ac3 = __builtin_amdgcn_mfma_f32_16x16x32_bf16(af, b3, ac3, 0, 0, 0);
  }
  int row = mb + wv * 16 + quad * 4;
  f32x4 accs[4] = {ac0, ac1, ac2, ac3};
#pragma unroll
  for (int nt = 0; nt < 4; ++nt)
#pragma unroll
    for (int r = 0; r < 4; ++r)
      C[(size_t)(row + r) * N + nb + nt * 16 + m16] = accs[nt][r];
}

// ---------------- gus GEMM -> Zt with raw-reshape scatter -------------------
__global__ __launch_bounds__(256) void mfma_gus(const ushort* __restrict__ A,
                                                const ushort* __restrict__ Bt,
                                                ushort* __restrict__ Zt) {
  const int K = 1024;
  int tid = threadIdx.x;
  int wv = tid >> 6, lane = tid & 63;
  int quad = lane >> 4, m16 = lane & 15;
  int nb = blockIdx.x * 64, mb = blockIdx.y * 64;
  const ushort* Ap = A + (size_t)(mb + wv * 16 + m16) * K + quad * 8;
  const ushort* Bp = Bt + (size_t)(nb + m16) * K + quad * 8;
  f32x4 ac0 = {0.f, 0.f, 0.f, 0.f}, ac1 = ac0, ac2 = ac0, ac3 = ac0;
#pragma unroll 2
  for (int k0 = 0; k0 < K; k0 += 32) {
    bf16x8 af = *(const bf16x8*)(Ap + k0);
    bf16x8 b0 = *(const bf16x8*)(Bp + k0);
    bf16x8 b1 = *(const bf16x8*)(Bp + (size_t)16 * K + k0);
    bf16x8 b2 = *(const bf16x8*)(Bp + (size_t)32 * K + k0);
    bf16x8 b3 = *(const bf16x8*)(Bp + (size_t)48 * K + k0);
    ac0 = __builtin_amdgcn_mfma_f32_16x16x32_bf16(af, b0, ac0, 0, 0, 0);
    ac1 = __builtin_amdgcn_mfma_f32_16x16x32_bf16(af, b1, ac1, 0, 0, 0);
    ac2 = __builtin_amdgcn_mfma_f32_16x16x32_bf16(af, b2, ac2, 0, 0, 0);
    ac3 = __builtin_amdgcn_mfma_f32_16x16x32_bf16(af, b3, ac3, 0, 0, 0);
  }
  int row = mb + wv * 16 + quad * 4;
  f32x4 accs[4] = {ac0, ac1, ac2, ac3};
#pragma unroll
  for (int nt = 0; nt < 4; ++nt) {
    int c = nb + nt * 16 + m16;
#pragma unroll
    for (int r = 0; r < 4; ++r) {
      int p = row + r;
      int pos = ((p & 1) << 9) + c;
      int kk = p >> 1;
      Zt[(size_t)pos * 1024 + kk] = f2bf(accs[nt][r]);
    }
  }
}

// ---------------- CSA fused -> Zt second half (raw-reshape scatter) ---------
__global__ __launch_bounds__(256) void csa_fused2(const float* __restrict__ sigt,
                                                  const float* __restrict__ orlt,
                                                  ushort* __restrict__ Zt) {
  __shared__ float red[8];
  __shared__ float a9s[9];
  int n = blockIdx.x, tid = threadIdx.x;
  int ny = n >> 5, nx = n & 31;
  int c2 = tid * 2;
  float2 ctr = *(const float2*)&sigt[n * 512 + c2];
  float part[9];
#pragma unroll
  for (int u = 0; u < 3; ++u) {
    int yy = ny + u - 1;
#pragma unroll
    for (int v = 0; v < 3; ++v) {
      int xx = nx + v - 1;
      float2 nb = {0.f, 0.f};
      if ((unsigned)yy < 32u && (unsigned)xx < 32u)
        nb = *(const float2*)&sigt[(yy * 32 + xx) * 512 + c2];
      part[u * 3 + v] = ctr.x * nb.x + ctr.y * nb.y;
    }
  }
  float a[9];
#pragma unroll
  for (int t = 0; t < 9; ++t) a[t] = breduce_sum(part[t], red) * (1.f / 512.f);
  float mx = a[0];
#pragma unroll
  for (int t = 1; t < 9; ++t) mx = fmaxf(mx, a[t]);
  float sum = 0.f;
#pragma unroll
  for (int t = 0; t < 9; ++t) { a[t] = expf(a[t] - mx); sum += a[t]; }
  if (tid == 0) {
    float inv = 1.f / sum;
#pragma unroll
    for (int t = 0; t < 9; ++t) a9s[t] = a[t] * inv;
  }
  __syncthreads();
  float2 acc = {0.f, 0.f};
#pragma unroll
  for (int u = 0; u < 3; ++u) {
    int yy = ny + u - 1;
#pragma unroll
    for (int v = 0; v < 3; ++v) {
      int xx = nx + v - 1;
      if ((unsigned)yy < 32u && (unsigned)xx < 32u) {
        float w = a9s[u * 3 + v];
        float2 ov = *(const float2*)&orlt[(yy * 32 + xx) * 512 + c2];
        acc.x += w * ov.x;
        acc.y += w * ov.y;
      }
    }
  }
  int kk = 512 + (n >> 1);
  int pos0 = ((n & 1) << 9) + c2;
  Zt[(size_t)pos0 * 1024 + kk] = f2bf(acc.x);
  Zt[(size_t)(pos0 + 1) * 1024 + kk] = f2bf(acc.y);
}

// ---------------- InstanceNorm + LeakyReLU -> transposed bf16 into Zt2 ------
__global__ __launch_bounds__(256) void norm_down(const float* __restrict__ raw,
                                                 ushort* __restrict__ Zt2) {
  __shared__ float red[8];
  int c = blockIdx.x, tid = threadIdx.x;
  float v[4];
  float s = 0.f, ss = 0.f;
#pragma unroll
  for (int r = 0; r < 4; ++r) {
    v[r] = raw[c * 1024 + tid + r * 256];
    s += v[r];
    ss += v[r] * v[r];
  }
  breduce2(s, ss, red);
  float mean = s * (1.f / 1024.f);
  float var = ss * (1.f / 1024.f) - mean * mean;
  float inv = rsqrtf(var + EPSN);
#pragma unroll
  for (int r = 0; r < 4; ++r) {
    float t = (v[r] - mean) * inv;
    t = t >= 0.f ? t : 0.2f * t;
    Zt2[(size_t)(tid + r * 256) * 1024 + c] = f2bf(t);
  }
}

// ---------------- final InstanceNorm + LeakyReLU (fp32 out) -----------------
__global__ __launch_bounds__(256) void norm_leaky(const float* __restrict__ raw,
                                                  float* __restrict__ out) {
  __shared__ float red[8];
  int c = blockIdx.x, tid = threadIdx.x;
  float v[4];
  float s = 0.f, ss = 0.f;
#pragma unroll
  for (int r = 0; r < 4; ++r) {
    v[r] = raw[c * 1024 + tid + r * 256];
    s += v[r];
    ss += v[r] * v[r];
  }
  breduce2(s, ss, red);
  float mean = s * (1.f / 1024.f);
  float var = ss * (1.f / 1024.f) - mean * mean;
  float inv = rsqrtf(var + EPSN);
#pragma unroll
  for (int r = 0; r < 4; ++r) {
    float t = (v[r] - mean) * inv;
    out[c * 1024 + tid + r * 256] = t >= 0.f ? t : 0.2f * t;
  }
}

// ---------------- host launch ------------------------------------------------
extern "C" void kernel_launch(void* const* d_in, const int* in_sizes, int n_in,
                              void* d_out, int out_size, void* d_ws, size_t ws_size,
                              hipStream_t stream) {
  const float* x = (const float*)d_in[0];
  const float* gus = (const float*)d_in[1];
  const float* w3 = (const float*)d_in[2];
  const float* b3 = (const float*)d_in[3];
  const float* w5 = (const float*)d_in[4];
  const float* b5 = (const float*)d_in[5];
  const float* w7 = (const float*)d_in[6];
  const float* b7 = (const float*)d_in[7];
  const float* wfc = (const float*)d_in[8];
  const float* bfc = (const float*)d_in[9];
  const float* w0 = (const float*)d_in[10];
  const float* b0 = (const float*)d_in[11];
  const float* w1 = (const float*)d_in[12];
  const float* b1 = (const float*)d_in[13];
  const float* w2 = (const float*)d_in[14];
  const float* b2 = (const float*)d_in[15];
  const float* wdown = (const float*)d_in[16];
  const float* wfuse = (const float*)d_in[17];

  float* ws = (float*)d_ws;
  float* feas = ws;                      // 1572864 (dead after blend_fc)
  float* raw = feas + 1048576;           // 524288 fl (GEMM fp32 outputs)
  float* bmean = ws + 1572864;           // 1536
  float* invn = bmean + 1536;            // 256
  float* res = invn + 256;               // 524288
  float* Zt2f = res + 524288;            // 524288 fl
  ushort* Zt2 = (ushort*)Zt2f;
  float* T = Zt2f + 524288;              // 2097152
  float* Apart = T;                      // (dead before T written)
  ushort* Zt = (ushort*)T;               // (written after tcomb2)
  float* orlt = T + 2097152;             // 524288
  float* sigt = orlt + 524288;           // 524288
  ushort* orlT = (ushort*)(sigt + 524288);        // 262144 fl
  ushort* attnT = (ushort*)(sigt + 786432);       // 32768 fl
  ushort* gus_bf = (ushort*)(sigt + 819200);      // 524288 fl
  ushort* wdown_bf = (ushort*)(sigt + 1343488);   // 262144 fl
  ushort* wfuse_bf = (ushort*)(sigt + 1605632);   // 262144 fl
  ushort* resd = (ushort*)(sigt + 1867776);       // 1048576 fl = 4 MB bf16

  conv_bf3<<<2048, 256, 0, stream>>>(gus, wdown, wfuse, gus_bf, wdown_bf, wfuse_bf);
  hipMemsetAsync(resd, 0, 16u * 512u * 256u * sizeof(ushort), stream);
  sk_all3<<<256, 256, 0, stream>>>(x, w3, b3, w5, b5, w7, b7, feas, bmean);
  blend_fc<<<dim3(32, 16), 256, 0, stream>>>(feas, bmean, wfc, bfc, w0, b0, w1,
                                             b1, w2, b2, res, Zt2, resd);
  gram_part2<<<dim3(4, 4, 16), 256, 0, stream>>>(res, Apart);
  diag_norm<<<1, 256, 0, stream>>>(Apart, invn);
  attn_soft2<<<256, 256, 0, stream>>>(Apart, invn, attnT);
  mfma_tconv<<<dim3(8, 4, 16), 256, 0, stream>>>(attnT, resd, T);
  tcomb2<<<dim3(32, 16), 256, 0, stream>>>(T, orlt, sigt, orlT);
  mfma_gus<<<dim3(8, 16), 256, 0, stream>>>(gus_bf, orlT, Zt);
  csa_fused2<<<1024, 256, 0, stream>>>(sigt, orlt, Zt);
  mfma_gemm<<<dim3(16, 8), 256, 0, stream>>>(wdown_bf, Zt, raw, 1024, 1024);
  norm_down<<<512, 256, 0, stream>>>(raw, Zt2);
  mfma_gemm<<<dim3(16, 8), 256, 0, stream>>>(wfuse_bf, Zt2, raw, 1024, 1024);
  norm_leaky<<<512, 256, 0, stream>>>(raw, (float*)d_out);
}